// Round 3
// baseline (4996.476 us; speedup 1.0000x reference)
//
#include <hip/hip_runtime.h>
#include <hip/hip_bf16.h>
#include <math.h>

typedef __hip_bfloat16 bf16;

#define LN_EPS 1e-5f

__device__ __forceinline__ float b2f(bf16 x){ return __bfloat162float(x); }
__device__ __forceinline__ float sanit(float s){ return fminf(fmaxf(s, -80.f), 80.f); }

__device__ __forceinline__ void stc(float* p, float v){ *p = v; }
__device__ __forceinline__ void stc(bf16* p, float v){ *p = __float2bfloat16(v); }

// ---------------- LayerNorm over D=256, one token per 256-thread block ----
__global__ void ln256_kernel(const float* __restrict__ in, const float* __restrict__ g,
                             const float* __restrict__ bb, float* __restrict__ out, int addTo)
{
    int token = blockIdx.x; int d = threadIdx.x;
    __shared__ float red[256];
    float v = in[(size_t)token*256 + d];
    red[d] = v; __syncthreads();
    for (int s=128; s>0; s>>=1){ if (d<s) red[d]+=red[d+s]; __syncthreads(); }
    float mean = red[0]*(1.f/256.f);
    __syncthreads();
    float dev = v - mean;
    red[d] = dev*dev; __syncthreads();
    for (int s=128; s>0; s>>=1){ if (d<s) red[d]+=red[d+s]; __syncthreads(); }
    float var = red[0]*(1.f/256.f);
    float r = dev*rsqrtf(var+LN_EPS)*g[d] + bb[d];
    size_t o = (size_t)token*256+d;
    if (addTo) out[o] += r; else out[o] = r;
}

// ---------------- Tiled GEMM: C[M,N] = act(A[M,K] @ W[N,K]^T + bias) + resid
template<typename TC>
__global__ void gemm16(const float* __restrict__ A, const float* __restrict__ W,
                       const float* __restrict__ bias, const float* __restrict__ resid,
                       TC* __restrict__ C, int M, int N, int K, int do_gelu)
{
    __shared__ float As[16][17];
    __shared__ float Ws[16][17];
    int tx = threadIdx.x, ty = threadIdx.y;
    int n0 = blockIdx.x*16, m0 = blockIdx.y*16;
    float acc = 0.f;
    for (int k0=0; k0<K; k0+=16){
        As[ty][tx] = A[(size_t)(m0+ty)*K + k0+tx];
        Ws[ty][tx] = W[(size_t)(n0+ty)*K + k0+tx];
        __syncthreads();
        #pragma unroll
        for (int kk=0; kk<16; kk++) acc += As[ty][kk]*Ws[tx][kk];
        __syncthreads();
    }
    int m = m0+ty, n = n0+tx;
    if (bias) acc += bias[n];
    if (do_gelu) acc = 0.5f*acc*(1.0f+erff(acc*0.70710678118654752f));
    size_t o = (size_t)m*N+n;
    if (resid) acc += resid[o];
    stc(&C[o], acc);
}

// ---------------- 3x3 stride-2 pad-1 conv, NHWC, one (b,ho,wo) per block --
__global__ void seedconv_kernel(const float* __restrict__ x, const float* __restrict__ w,
                                float* __restrict__ out)
{
    int idx = blockIdx.x;                 // b*784 + ho*28 + wo
    int wo = idx%28; int ho = (idx/28)%28; int b = idx/784;
    __shared__ float patch[2304];         // 9 pos x 256 ci
    int tid = threadIdx.x;
    for (int p = tid; p < 2304; p += 256){
        int pos = p >> 8; int ci = p & 255;
        int kh = pos/3, kw = pos%3;
        int ihh = 2*ho + kh - 1, iww = 2*wo + kw - 1;
        float v = 0.f;
        if (ihh>=0 && ihh<56 && iww>=0 && iww<56)
            v = x[(((size_t)b*56 + ihh)*56 + iww)*256 + ci];
        patch[p] = v;
    }
    __syncthreads();
    int o = tid;
    float acc = 0.f;
    for (int pos=0; pos<9; pos++){
        int kh = pos/3, kw = pos%3;
        const float* wp = w + (size_t)o*2304 + kh*3 + kw;   // stride 9 over ci
        const float* pp = patch + pos*256;
        for (int ci=0; ci<256; ci++)
            acc += pp[ci] * wp[(size_t)ci*9];
    }
    out[(size_t)idx*256 + o] = acc;
}

// ---------------- Group attention scores: softmax((k . q_nb + rpb)*scale) --
__global__ void grp_attn_kernel(const bf16* __restrict__ kproj, const float* __restrict__ qbuf,
                                const float* __restrict__ rpb, const float* __restrict__ g_tau,
                                float* __restrict__ attn)
{
    int idx = blockIdx.x;   // b*3136 + n*784 + i*28 + j
    int j = idx%28; int i = (idx/28)%28; int n = (idx/784)%4; int b = idx/3136;
    int lane = threadIdx.x; // 64
    int sh = n>>1, sw = n&1;
    const bf16* kv = kproj + ((size_t)b*3136 + (2*i+sh)*56 + (2*j+sw))*256;
    __shared__ float sc[9];
    int i0 = min(max(i-1,0),25), j0 = min(max(j-1,0),25);
    for (int l=0; l<9; l++){
        int qi = i0 + l/3, qj = j0 + l%3;
        const float* qv = qbuf + ((size_t)b*784 + qi*28+qj)*256;
        float p = 0.f;
        for (int d=lane; d<256; d+=64) p += b2f(kv[d])*qv[d];
        for (int off=32; off>0; off>>=1) p += __shfl_down(p, off, 64);
        if (lane==0) sc[l] = p;
    }
    __syncthreads();
    if (lane==0){
        float scale = expf(g_tau[0]);
        float s[9]; float m = -1e30f;
        for (int l=0; l<9; l++){ s[l] = sanit((sc[l] + rpb[n*9+l])*scale); m = fmaxf(m, s[l]); }
        float sum = 0.f;
        for (int l=0; l<9; l++){ s[l] = expf(s[l]-m); sum += s[l]; }
        float inv = 1.f/fmaxf(sum, 1e-30f);
        float* ap = attn + (size_t)idx*9;
        for (int l=0; l<9; l++) ap[l] = s[l]*inv + 1e-6f;
    }
}

__global__ void zero_kernel(float* __restrict__ p, int n)
{
    int t = blockIdx.x*256 + threadIdx.x;
    if (t < n) p[t] = 0.f;
}

__global__ void grp_scatter_kernel(const float* __restrict__ attn, float* __restrict__ col)
{
    int t = blockIdx.x*256 + threadIdx.x;   // 4*4*784*9
    if (t >= 4*4*784*9) return;
    int l = t%9; int rest = t/9;
    int j = rest%28; int i = (rest/28)%28; int b = rest/3136;
    int i0 = min(max(i-1,0),25), j0 = min(max(j-1,0),25);
    int qp = (i0 + l/3)*28 + (j0 + l%3);
    atomicAdd(&col[b*784+qp], attn[t]);
}

__global__ void grp_av_kernel(const float* __restrict__ attn, const float* __restrict__ col,
                              const bf16* __restrict__ vproj, float* __restrict__ xout)
{
    int idx = blockIdx.x;   // b*784 + i*28 + j
    int j = idx%28; int i = (idx/28)%28; int b = idx/784;
    int d = threadIdx.x;
    int i0 = min(max(i-1,0),25), j0 = min(max(j-1,0),25);
    float acc = 0.f;
    for (int n=0; n<4; n++){
        int sh = n>>1, sw = n&1;
        const float* ap = attn + ((size_t)(b*4+n)*784 + i*28+j)*9;
        for (int l=0; l<9; l++){
            int qi = i0 + l/3, qj = j0 + l%3;
            float dv = col[b*784 + qi*28+qj] + 1e-8f;
            acc += (ap[l]/dv) * b2f(vproj[((size_t)b*3136 + (2*qi+sh)*56 + (2*qj+sw))*256 + d]);
        }
    }
    xout[(size_t)idx*256 + d] += acc;
}

// ---------------- RoPE in place on q,k sections of qkv (B,784,3,8,32) -----
__global__ void rope_kernel(float* __restrict__ qkv)
{
    int idx = blockIdx.x*256 + threadIdx.x;   // B*784*2*8*16 = 802816
    int u = idx%16; int h = (idx/16)%8; int s = (idx/128)%2;
    int t = (idx/256)%784; int b = idx/(256*784);
    float f = expf(-((float)(2*u)/32.f)*logf(10000.f));
    float ang = (float)t * f;
    float c = cosf(ang), sn = sinf(ang);
    float* p = qkv + ((size_t)(b*784+t))*768 + s*256 + h*32 + 2*u;
    float x0 = p[0], x1 = p[1];
    p[0] = x0*c - x1*sn;
    p[1] = x1*c + x0*sn;
}

// ---------------- Block attention (KB=7): fused scores+softmax+AV ---------
__global__ void blk_attn_fused(const float* __restrict__ qkv, float* __restrict__ obuf)
{
    int idx = blockIdx.x;   // (b*8+h)*784 + t
    int t = idx%784; int h = (idx/784)%8; int b = idx/6272;
    int i = t/28, j = t%28;
    int lane = threadIdx.x; // 64
    __shared__ float qs[32];
    __shared__ float red[64];
    __shared__ float a[49];
    if (lane < 32) qs[lane] = qkv[((size_t)(b*784+t))*768 + h*32 + lane];
    __syncthreads();
    int i0 = min(max(i-3,0),21), j0 = min(max(j-3,0),21);
    float score = -1e30f;
    if (lane < 49){
        int ki = i0 + lane/7, kj = j0 + lane%7;
        const float* kp = qkv + ((size_t)(b*784 + ki*28+kj))*768 + 256 + h*32;
        float p = 0.f;
        #pragma unroll
        for (int d=0; d<32; d++) p += qs[d]*kp[d];
        score = sanit(p * 0.17677669529663687f);
    }
    red[lane] = score;
    __syncthreads();
    if (lane==0){
        float m = -1e30f;
        for (int l=0; l<49; l++) m = fmaxf(m, red[l]);
        float s = 0.f;
        for (int l=0; l<49; l++){ float e = expf(red[l]-m); a[l] = e; s += e; }
        float inv = 1.f/fmaxf(s, 1e-30f);
        for (int l=0; l<49; l++) a[l] *= inv;
    }
    __syncthreads();
    if (lane < 32){
        float acc = 0.f;
        for (int l=0; l<49; l++){
            int ki = i0 + l/7, kj = j0 + l%7;
            acc += a[l] * qkv[((size_t)(b*784 + ki*28+kj))*768 + 512 + h*32 + lane];
        }
        obuf[((size_t)(b*784+t))*256 + h*32 + lane] = acc;
    }
}

__global__ void copy_out_kernel(const float* __restrict__ in, float* __restrict__ out, int n)
{
    int t = blockIdx.x*256 + threadIdx.x;
    if (t < n) out[t] = in[t];
}

// ==========================================================================
extern "C" void kernel_launch(void* const* d_in, const int* in_sizes, int n_in,
                              void* d_out, int out_size, void* d_ws, size_t ws_size,
                              hipStream_t stream) {
    // ALL inputs are float32 per the reference (setup_inputs uses jnp.float32).
    const float* x         = (const float*)d_in[0];
    const float* g_seed_w  = (const float*)d_in[1];
    const float* g_q_w     = (const float*)d_in[2];
    const float* g_k_w     = (const float*)d_in[3];
    const float* g_v_w     = (const float*)d_in[4];
    const float* g_mlp_w1  = (const float*)d_in[5];
    const float* g_mlp_b1  = (const float*)d_in[6];
    const float* g_mlp_w2  = (const float*)d_in[7];
    const float* g_mlp_b2  = (const float*)d_in[8];
    const float* g_ln_in_g = (const float*)d_in[9];
    const float* g_ln_in_b = (const float*)d_in[10];
    const float* g_ln_out_g= (const float*)d_in[11];
    const float* g_ln_out_b= (const float*)d_in[12];
    const float* g_tau     = (const float*)d_in[13];
    const float* g_rpb     = (const float*)d_in[14];
    const float* blk_ln1_g = (const float*)d_in[15];
    const float* blk_ln1_b = (const float*)d_in[16];
    const float* blk_qkv_w = (const float*)d_in[17];
    const float* blk_proj_w= (const float*)d_in[18];
    const float* blk_proj_b= (const float*)d_in[19];
    const float* blk_ln2_g = (const float*)d_in[20];
    const float* blk_ln2_b = (const float*)d_in[21];
    const float* blk_mlp_w1= (const float*)d_in[22];
    const float* blk_mlp_b1= (const float*)d_in[23];
    const float* blk_mlp_w2= (const float*)d_in[24];
    const float* blk_mlp_b2= (const float*)d_in[25];

    // workspace layout — 8,144,192 floats-equivalent = 32.6 MB
    float* f     = (float*)d_ws;
    bf16*  kproj = (bf16*)d_ws;          // 3211264 bf16 (= 1605632 floats)
    bf16*  vproj = kproj + 3211264;      // 3211264 bf16
    float* xout  = f + 3211264;          // 802816
    float* tmp   = xout  + 802816;       // 802816
    float* qbuf  = tmp   + 802816;       // 802816
    float* big   = qbuf  + 802816;       // 2408448 (3136x768)
    float* attng = big   + 2408448;      // 112896  (4*4*784*9)
    float* col   = attng + 112896;       // 3136
    // xln aliases qbuf+big (exactly 3211264 floats); both dead at setup time
    float* xln   = qbuf;

    dim3 tpb16(16,16);

    // ---- setup ----
    ln256_kernel<<<12544, 256, 0, stream>>>(x, g_ln_in_g, g_ln_in_b, xln, 0);
    gemm16<bf16> <<<dim3(16,784), tpb16, 0, stream>>>(xln, g_k_w, nullptr, nullptr, kproj, 12544,256,256, 0);
    gemm16<bf16> <<<dim3(16,784), tpb16, 0, stream>>>(x,   g_v_w, nullptr, nullptr, vproj, 12544,256,256, 0);
    seedconv_kernel<<<3136, 256, 0, stream>>>(x, g_seed_w, tmp);
    ln256_kernel<<<3136, 256, 0, stream>>>(tmp, g_ln_out_g, g_ln_out_b, xout, 0);

    // ---- NUM_ITERS group-attention iterations ----
    for (int it=0; it<3; it++){
        ln256_kernel<<<3136, 256, 0, stream>>>(xout, g_ln_out_g, g_ln_out_b, tmp, 0);
        gemm16<float><<<dim3(16,196), tpb16, 0, stream>>>(tmp, g_q_w, nullptr, nullptr, qbuf, 3136,256,256, 0);
        grp_attn_kernel<<<12544, 64, 0, stream>>>(kproj, qbuf, g_rpb, g_tau, attng);
        zero_kernel<<<(3136+255)/256, 256, 0, stream>>>(col, 3136);
        grp_scatter_kernel<<<(112896+255)/256, 256, 0, stream>>>(attng, col);
        grp_av_kernel<<<3136, 256, 0, stream>>>(attng, col, vproj, xout);
        gemm16<float><<<dim3(32,196), tpb16, 0, stream>>>(xout, g_mlp_w1, g_mlp_b1, nullptr, big, 3136,512,256, 1);
        gemm16<float><<<dim3(16,196), tpb16, 0, stream>>>(big, g_mlp_w2, g_mlp_b2, nullptr, tmp, 3136,256,512, 0);
        ln256_kernel<<<3136, 256, 0, stream>>>(tmp, g_ln_out_g, g_ln_out_b, xout, 1);
    }

    // ---- DEPTH transformer blocks ----
    for (int l=0; l<2; l++){
        ln256_kernel<<<3136, 256, 0, stream>>>(xout, blk_ln1_g + l*256, blk_ln1_b + l*256, tmp, 0);
        gemm16<float><<<dim3(48,196), tpb16, 0, stream>>>(tmp, blk_qkv_w + (size_t)l*768*256, nullptr, nullptr, big, 3136,768,256, 0);
        rope_kernel<<<3136, 256, 0, stream>>>(big);
        blk_attn_fused<<<25088, 64, 0, stream>>>(big, qbuf);
        gemm16<float><<<dim3(16,196), tpb16, 0, stream>>>(qbuf, blk_proj_w + (size_t)l*256*256, blk_proj_b + l*256, xout, xout, 3136,256,256, 0);
        ln256_kernel<<<3136, 256, 0, stream>>>(xout, blk_ln2_g + l*256, blk_ln2_b + l*256, tmp, 0);
        gemm16<float><<<dim3(48,196), tpb16, 0, stream>>>(tmp, blk_mlp_w1 + (size_t)l*768*256, blk_mlp_b1 + l*768, nullptr, big, 3136,768,256, 1);
        gemm16<float><<<dim3(16,196), tpb16, 0, stream>>>(big, blk_mlp_w2 + (size_t)l*256*768, blk_mlp_b2 + l*256, xout, xout, 3136,256,768, 0);
    }

    copy_out_kernel<<<(802816+255)/256, 256, 0, stream>>>(xout, (float*)d_out, 802816);
}

// Round 4
// 1961.050 us; speedup vs baseline: 2.5479x; 2.5479x over previous
//
#include <hip/hip_runtime.h>
#include <hip/hip_bf16.h>
#include <math.h>

typedef __hip_bfloat16 bf16;

#define LN_EPS 1e-5f

__device__ __forceinline__ float b2f(bf16 x){ return __bfloat162float(x); }
__device__ __forceinline__ float sanit(float s){ return fminf(fmaxf(s, -80.f), 80.f); }

__device__ __forceinline__ void stc(float* p, float v){ *p = v; }
__device__ __forceinline__ void stc(bf16* p, float v){ *p = __float2bfloat16(v); }

// ---------------- LayerNorm over D=256, one token per 256-thread block ----
__global__ void ln256_kernel(const float* __restrict__ in, const float* __restrict__ g,
                             const float* __restrict__ bb, float* __restrict__ out, int addTo)
{
    int token = blockIdx.x; int d = threadIdx.x;
    __shared__ float red[256];
    float v = in[(size_t)token*256 + d];
    red[d] = v; __syncthreads();
    for (int s=128; s>0; s>>=1){ if (d<s) red[d]+=red[d+s]; __syncthreads(); }
    float mean = red[0]*(1.f/256.f);
    __syncthreads();
    float dev = v - mean;
    red[d] = dev*dev; __syncthreads();
    for (int s=128; s>0; s>>=1){ if (d<s) red[d]+=red[d+s]; __syncthreads(); }
    float var = red[0]*(1.f/256.f);
    float r = dev*rsqrtf(var+LN_EPS)*g[d] + bb[d];
    size_t o = (size_t)token*256+d;
    if (addTo) out[o] += r; else out[o] = r;
}

// ---------------- Tiled GEMM: C[M,N] = act(A[M,K] @ W[N,K]^T + bias) + resid
template<typename TC>
__global__ void gemm16(const float* __restrict__ A, const float* __restrict__ W,
                       const float* __restrict__ bias, const float* __restrict__ resid,
                       TC* __restrict__ C, int M, int N, int K, int do_gelu)
{
    __shared__ float As[16][17];
    __shared__ float Ws[16][17];
    int tx = threadIdx.x, ty = threadIdx.y;
    int n0 = blockIdx.x*16, m0 = blockIdx.y*16;
    float acc = 0.f;
    for (int k0=0; k0<K; k0+=16){
        As[ty][tx] = A[(size_t)(m0+ty)*K + k0+tx];
        Ws[ty][tx] = W[(size_t)(n0+ty)*K + k0+tx];
        __syncthreads();
        #pragma unroll
        for (int kk=0; kk<16; kk++) acc += As[ty][kk]*Ws[tx][kk];
        __syncthreads();
    }
    int m = m0+ty, n = n0+tx;
    if (bias) acc += bias[n];
    if (do_gelu) acc = 0.5f*acc*(1.0f+erff(acc*0.70710678118654752f));
    size_t o = (size_t)m*N+n;
    if (resid) acc += resid[o];
    stc(&C[o], acc);
}

// -------- 3x3 stride-2 pad-1 conv as GEMM (im2col on the fly) -------------
// C[m,n] = sum_k patch[m,k]*w[n*2304+k], m = b*784+ho*28+wo, k = ci*9+kh*3+kw
__global__ void seedconv_gemm(const float* __restrict__ x, const float* __restrict__ w,
                              float* __restrict__ out)
{
    __shared__ float As[16][17];
    __shared__ float Ws[16][17];
    int tx = threadIdx.x, ty = threadIdx.y;
    int n0 = blockIdx.x*16, m0 = blockIdx.y*16;
    int m = m0 + ty;
    int wo = m%28, ho = (m/28)%28, b = m/784;
    float acc = 0.f;
    for (int k0=0; k0<2304; k0+=16){
        int k = k0 + tx;
        int ci = k/9; int pos = k - ci*9;
        int kh = pos/3, kw = pos - kh*3;
        int ih = 2*ho + kh - 1, iw = 2*wo + kw - 1;
        float a = 0.f;
        if (ih>=0 && ih<56 && iw>=0 && iw<56)
            a = x[(((size_t)b*56 + ih)*56 + iw)*256 + ci];
        As[ty][tx] = a;
        Ws[ty][tx] = w[(size_t)(n0+ty)*2304 + k];
        __syncthreads();
        #pragma unroll
        for (int kk=0; kk<16; kk++) acc += As[ty][kk]*Ws[tx][kk];
        __syncthreads();
    }
    out[(size_t)m*256 + n0+tx] = acc;
}

// ---------------- Group attention scores: softmax((k . q_nb + rpb)*scale) --
__global__ void grp_attn_kernel(const bf16* __restrict__ kproj, const float* __restrict__ qbuf,
                                const float* __restrict__ rpb, const float* __restrict__ g_tau,
                                float* __restrict__ attn)
{
    int idx = blockIdx.x;   // b*3136 + n*784 + i*28 + j
    int j = idx%28; int i = (idx/28)%28; int n = (idx/784)%4; int b = idx/3136;
    int lane = threadIdx.x; // 64
    int sh = n>>1, sw = n&1;
    const bf16* kv = kproj + ((size_t)b*3136 + (2*i+sh)*56 + (2*j+sw))*256;
    __shared__ float sc[9];
    int i0 = min(max(i-1,0),25), j0 = min(max(j-1,0),25);
    for (int l=0; l<9; l++){
        int qi = i0 + l/3, qj = j0 + l%3;
        const float* qv = qbuf + ((size_t)b*784 + qi*28+qj)*256;
        float p = 0.f;
        for (int d=lane; d<256; d+=64) p += b2f(kv[d])*qv[d];
        for (int off=32; off>0; off>>=1) p += __shfl_down(p, off, 64);
        if (lane==0) sc[l] = p;
    }
    __syncthreads();
    if (lane==0){
        float scale = expf(g_tau[0]);
        float s[9]; float m = -1e30f;
        for (int l=0; l<9; l++){ s[l] = sanit((sc[l] + rpb[n*9+l])*scale); m = fmaxf(m, s[l]); }
        float sum = 0.f;
        for (int l=0; l<9; l++){ s[l] = expf(s[l]-m); sum += s[l]; }
        float inv = 1.f/fmaxf(sum, 1e-30f);
        float* ap = attn + (size_t)idx*9;
        for (int l=0; l<9; l++) ap[l] = s[l]*inv + 1e-6f;
    }
}

__global__ void zero_kernel(float* __restrict__ p, int n)
{
    int t = blockIdx.x*256 + threadIdx.x;
    if (t < n) p[t] = 0.f;
}

__global__ void grp_scatter_kernel(const float* __restrict__ attn, float* __restrict__ col)
{
    int t = blockIdx.x*256 + threadIdx.x;   // 4*4*784*9
    if (t >= 4*4*784*9) return;
    int l = t%9; int rest = t/9;
    int j = rest%28; int i = (rest/28)%28; int b = rest/3136;
    int i0 = min(max(i-1,0),25), j0 = min(max(j-1,0),25);
    int qp = (i0 + l/3)*28 + (j0 + l%3);
    atomicAdd(&col[b*784+qp], attn[t]);
}

__global__ void grp_av_kernel(const float* __restrict__ attn, const float* __restrict__ col,
                              const bf16* __restrict__ vproj, float* __restrict__ xout)
{
    int idx = blockIdx.x;   // b*784 + i*28 + j
    int j = idx%28; int i = (idx/28)%28; int b = idx/784;
    int d = threadIdx.x;
    int i0 = min(max(i-1,0),25), j0 = min(max(j-1,0),25);
    float acc = 0.f;
    for (int n=0; n<4; n++){
        int sh = n>>1, sw = n&1;
        const float* ap = attn + ((size_t)(b*4+n)*784 + i*28+j)*9;
        for (int l=0; l<9; l++){
            int qi = i0 + l/3, qj = j0 + l%3;
            float dv = col[b*784 + qi*28+qj] + 1e-8f;
            acc += (ap[l]/dv) * b2f(vproj[((size_t)b*3136 + (2*qi+sh)*56 + (2*qj+sw))*256 + d]);
        }
    }
    xout[(size_t)idx*256 + d] += acc;
}

// ---------------- RoPE in place on q,k sections of qkv (B,784,3,8,32) -----
__global__ void rope_kernel(float* __restrict__ qkv)
{
    int idx = blockIdx.x*256 + threadIdx.x;   // B*784*2*8*16 = 802816
    int u = idx%16; int h = (idx/16)%8; int s = (idx/128)%2;
    int t = (idx/256)%784; int b = idx/(256*784);
    float f = expf(-((float)(2*u)/32.f)*logf(10000.f));
    float ang = (float)t * f;
    float c = cosf(ang), sn = sinf(ang);
    float* p = qkv + ((size_t)(b*784+t))*768 + s*256 + h*32 + 2*u;
    float x0 = p[0], x1 = p[1];
    p[0] = x0*c - x1*sn;
    p[1] = x1*c + x0*sn;
}

// ---------------- Block attention (KB=7): fused scores+softmax+AV ---------
__global__ void blk_attn_fused(const float* __restrict__ qkv, float* __restrict__ obuf)
{
    int idx = blockIdx.x;   // (b*8+h)*784 + t
    int t = idx%784; int h = (idx/784)%8; int b = idx/6272;
    int i = t/28, j = t%28;
    int lane = threadIdx.x; // 64
    __shared__ float qs[32];
    __shared__ float red[64];
    __shared__ float a[49];
    if (lane < 32) qs[lane] = qkv[((size_t)(b*784+t))*768 + h*32 + lane];
    __syncthreads();
    int i0 = min(max(i-3,0),21), j0 = min(max(j-3,0),21);
    float score = -1e30f;
    if (lane < 49){
        int ki = i0 + lane/7, kj = j0 + lane%7;
        const float* kp = qkv + ((size_t)(b*784 + ki*28+kj))*768 + 256 + h*32;
        float p = 0.f;
        #pragma unroll
        for (int d=0; d<32; d++) p += qs[d]*kp[d];
        score = sanit(p * 0.17677669529663687f);
    }
    red[lane] = score;
    __syncthreads();
    if (lane==0){
        float m = -1e30f;
        for (int l=0; l<49; l++) m = fmaxf(m, red[l]);
        float s = 0.f;
        for (int l=0; l<49; l++){ float e = expf(red[l]-m); a[l] = e; s += e; }
        float inv = 1.f/fmaxf(s, 1e-30f);
        for (int l=0; l<49; l++) a[l] *= inv;
    }
    __syncthreads();
    if (lane < 32){
        float acc = 0.f;
        for (int l=0; l<49; l++){
            int ki = i0 + l/7, kj = j0 + l%7;
            acc += a[l] * qkv[((size_t)(b*784 + ki*28+kj))*768 + 512 + h*32 + lane];
        }
        obuf[((size_t)(b*784+t))*256 + h*32 + lane] = acc;
    }
}

__global__ void copy_out_kernel(const float* __restrict__ in, float* __restrict__ out, int n)
{
    int t = blockIdx.x*256 + threadIdx.x;
    if (t < n) out[t] = in[t];
}

// ==========================================================================
extern "C" void kernel_launch(void* const* d_in, const int* in_sizes, int n_in,
                              void* d_out, int out_size, void* d_ws, size_t ws_size,
                              hipStream_t stream) {
    const float* x         = (const float*)d_in[0];
    const float* g_seed_w  = (const float*)d_in[1];
    const float* g_q_w     = (const float*)d_in[2];
    const float* g_k_w     = (const float*)d_in[3];
    const float* g_v_w     = (const float*)d_in[4];
    const float* g_mlp_w1  = (const float*)d_in[5];
    const float* g_mlp_b1  = (const float*)d_in[6];
    const float* g_mlp_w2  = (const float*)d_in[7];
    const float* g_mlp_b2  = (const float*)d_in[8];
    const float* g_ln_in_g = (const float*)d_in[9];
    const float* g_ln_in_b = (const float*)d_in[10];
    const float* g_ln_out_g= (const float*)d_in[11];
    const float* g_ln_out_b= (const float*)d_in[12];
    const float* g_tau     = (const float*)d_in[13];
    const float* g_rpb     = (const float*)d_in[14];
    const float* blk_ln1_g = (const float*)d_in[15];
    const float* blk_ln1_b = (const float*)d_in[16];
    const float* blk_qkv_w = (const float*)d_in[17];
    const float* blk_proj_w= (const float*)d_in[18];
    const float* blk_proj_b= (const float*)d_in[19];
    const float* blk_ln2_g = (const float*)d_in[20];
    const float* blk_ln2_b = (const float*)d_in[21];
    const float* blk_mlp_w1= (const float*)d_in[22];
    const float* blk_mlp_b1= (const float*)d_in[23];
    const float* blk_mlp_w2= (const float*)d_in[24];
    const float* blk_mlp_b2= (const float*)d_in[25];

    // workspace layout — 8,144,192 floats-equivalent = 32.6 MB
    float* f     = (float*)d_ws;
    bf16*  kproj = (bf16*)d_ws;          // 3211264 bf16 (= 1605632 floats)
    bf16*  vproj = kproj + 3211264;      // 3211264 bf16
    float* xout  = f + 3211264;          // 802816
    float* tmp   = xout  + 802816;       // 802816
    float* qbuf  = tmp   + 802816;       // 802816
    float* big   = qbuf  + 802816;       // 2408448 (3136x768)
    float* attng = big   + 2408448;      // 112896  (4*4*784*9)
    float* col   = attng + 112896;       // 3136
    // xln aliases qbuf+big (exactly 3211264 floats); both dead at setup time
    float* xln   = qbuf;

    dim3 tpb16(16,16);

    // ---- setup ----
    ln256_kernel<<<12544, 256, 0, stream>>>(x, g_ln_in_g, g_ln_in_b, xln, 0);
    gemm16<bf16> <<<dim3(16,784), tpb16, 0, stream>>>(xln, g_k_w, nullptr, nullptr, kproj, 12544,256,256, 0);
    gemm16<bf16> <<<dim3(16,784), tpb16, 0, stream>>>(x,   g_v_w, nullptr, nullptr, vproj, 12544,256,256, 0);
    seedconv_gemm<<<dim3(16,196), tpb16, 0, stream>>>(x, g_seed_w, tmp);
    ln256_kernel<<<3136, 256, 0, stream>>>(tmp, g_ln_out_g, g_ln_out_b, xout, 0);

    // ---- NUM_ITERS group-attention iterations ----
    for (int it=0; it<3; it++){
        ln256_kernel<<<3136, 256, 0, stream>>>(xout, g_ln_out_g, g_ln_out_b, tmp, 0);
        gemm16<float><<<dim3(16,196), tpb16, 0, stream>>>(tmp, g_q_w, nullptr, nullptr, qbuf, 3136,256,256, 0);
        grp_attn_kernel<<<12544, 64, 0, stream>>>(kproj, qbuf, g_rpb, g_tau, attng);
        zero_kernel<<<(3136+255)/256, 256, 0, stream>>>(col, 3136);
        grp_scatter_kernel<<<(112896+255)/256, 256, 0, stream>>>(attng, col);
        grp_av_kernel<<<3136, 256, 0, stream>>>(attng, col, vproj, xout);
        gemm16<float><<<dim3(32,196), tpb16, 0, stream>>>(xout, g_mlp_w1, g_mlp_b1, nullptr, big, 3136,512,256, 1);
        gemm16<float><<<dim3(16,196), tpb16, 0, stream>>>(big, g_mlp_w2, g_mlp_b2, nullptr, tmp, 3136,256,512, 0);
        ln256_kernel<<<3136, 256, 0, stream>>>(tmp, g_ln_out_g, g_ln_out_b, xout, 1);
    }

    // ---- DEPTH transformer blocks ----
    for (int l=0; l<2; l++){
        ln256_kernel<<<3136, 256, 0, stream>>>(xout, blk_ln1_g + l*256, blk_ln1_b + l*256, tmp, 0);
        gemm16<float><<<dim3(48,196), tpb16, 0, stream>>>(tmp, blk_qkv_w + (size_t)l*768*256, nullptr, nullptr, big, 3136,768,256, 0);
        rope_kernel<<<3136, 256, 0, stream>>>(big);
        blk_attn_fused<<<25088, 64, 0, stream>>>(big, qbuf);
        gemm16<float><<<dim3(16,196), tpb16, 0, stream>>>(qbuf, blk_proj_w + (size_t)l*256*256, blk_proj_b + l*256, xout, xout, 3136,256,256, 0);
        ln256_kernel<<<3136, 256, 0, stream>>>(xout, blk_ln2_g + l*256, blk_ln2_b + l*256, tmp, 0);
        gemm16<float><<<dim3(48,196), tpb16, 0, stream>>>(tmp, blk_mlp_w1 + (size_t)l*768*256, blk_mlp_b1 + l*768, nullptr, big, 3136,768,256, 1);
        gemm16<float><<<dim3(16,196), tpb16, 0, stream>>>(big, blk_mlp_w2 + (size_t)l*256*768, blk_mlp_b2 + l*256, xout, xout, 3136,256,768, 0);
    }

    copy_out_kernel<<<(802816+255)/256, 256, 0, stream>>>(xout, (float*)d_out, 802816);
}

// Round 5
// 876.017 us; speedup vs baseline: 5.7036x; 2.2386x over previous
//
#include <hip/hip_runtime.h>
#include <hip/hip_bf16.h>
#include <math.h>

typedef __hip_bfloat16 bf16;

#define LN_EPS 1e-5f

__device__ __forceinline__ float b2f(bf16 x){ return __bfloat162float(x); }
__device__ __forceinline__ float sanit(float s){ return fminf(fmaxf(s, -80.f), 80.f); }

__device__ __forceinline__ void stc(float* p, float v){ *p = v; }
__device__ __forceinline__ void stc(bf16* p, float v){ *p = __float2bfloat16(v); }

__device__ __forceinline__ short f2s(float f){
    union { __hip_bfloat16 h; short s; } u; u.h = __float2bfloat16(f); return u.s;
}

using short8  = __attribute__((ext_vector_type(8))) short;
using floatx4 = __attribute__((ext_vector_type(4))) float;

// ---------------- LayerNorm over D=256, one token per 256-thread block ----
__global__ void ln256_kernel(const float* __restrict__ in, const float* __restrict__ g,
                             const float* __restrict__ bb, float* __restrict__ out, int addTo)
{
    int token = blockIdx.x; int d = threadIdx.x;
    __shared__ float red[256];
    float v = in[(size_t)token*256 + d];
    red[d] = v; __syncthreads();
    for (int s=128; s>0; s>>=1){ if (d<s) red[d]+=red[d+s]; __syncthreads(); }
    float mean = red[0]*(1.f/256.f);
    __syncthreads();
    float dev = v - mean;
    red[d] = dev*dev; __syncthreads();
    for (int s=128; s>0; s>>=1){ if (d<s) red[d]+=red[d+s]; __syncthreads(); }
    float var = red[0]*(1.f/256.f);
    float r = dev*rsqrtf(var+LN_EPS)*g[d] + bb[d];
    size_t o = (size_t)token*256+d;
    if (addTo) out[o] += r; else out[o] = r;
}

// ---------------- MFMA GEMM: C[M,N] = act(A[M,K] @ W[N,K]^T + bias) + resid
// 64x64 block tile, 4 waves (wave w = rows w*16..w*16+15 x all 64 cols),
// BK=32 staged via LDS with fp32->bf16 conversion. Rows padded to 40 shorts
// (80 B) so ds_read_b128 fragments are <=2-way on banks (free, m136).
// Requires: M%64==0, N%64==0, K%32==0 (true for all call sites).
template<typename TC>
__global__ __launch_bounds__(256) void gemm_mfma(const float* __restrict__ A,
                       const float* __restrict__ W,
                       const float* __restrict__ bias, const float* __restrict__ resid,
                       TC* __restrict__ C, int M, int N, int K, int do_gelu)
{
    __shared__ __align__(16) short As[64*40];
    __shared__ __align__(16) short Ws[64*40];
    int t = threadIdx.x;
    int n0 = blockIdx.x*64, m0 = blockIdx.y*64;
    int lane = t & 63, w = t >> 6;
    int quad = lane >> 4, mrow = lane & 15;
    floatx4 acc[4] = {{0,0,0,0},{0,0,0,0},{0,0,0,0},{0,0,0,0}};
    int r  = t >> 2;          // 0..63: staging row
    int kq = (t & 3) * 8;     // 0,8,16,24: k-offset within BK
    const float* Arow = A + (size_t)(m0 + r)*K + kq;
    const float* Wrow = W + (size_t)(n0 + r)*K + kq;
    for (int k0 = 0; k0 < K; k0 += 32){
        float4 a1 = *(const float4*)(Arow + k0);
        float4 a2 = *(const float4*)(Arow + k0 + 4);
        float4 w1 = *(const float4*)(Wrow + k0);
        float4 w2 = *(const float4*)(Wrow + k0 + 4);
        short8 av = { f2s(a1.x), f2s(a1.y), f2s(a1.z), f2s(a1.w),
                      f2s(a2.x), f2s(a2.y), f2s(a2.z), f2s(a2.w) };
        short8 wv = { f2s(w1.x), f2s(w1.y), f2s(w1.z), f2s(w1.w),
                      f2s(w2.x), f2s(w2.y), f2s(w2.z), f2s(w2.w) };
        __syncthreads();
        *(short8*)&As[r*40 + kq] = av;
        *(short8*)&Ws[r*40 + kq] = wv;
        __syncthreads();
        short8 af = *(short8*)&As[(w*16 + mrow)*40 + quad*8];
        #pragma unroll
        for (int nt=0; nt<4; nt++){
            short8 bfv = *(short8*)&Ws[(nt*16 + mrow)*40 + quad*8];
            acc[nt] = __builtin_amdgcn_mfma_f32_16x16x32_bf16(af, bfv, acc[nt], 0, 0, 0);
        }
    }
    #pragma unroll
    for (int nt=0; nt<4; nt++){
        int col = n0 + nt*16 + mrow;
        float bv = bias ? bias[col] : 0.f;
        #pragma unroll
        for (int rr=0; rr<4; rr++){
            int row = m0 + w*16 + quad*4 + rr;
            float v = acc[nt][rr] + bv;
            if (do_gelu) v = 0.5f*v*(1.0f+erff(v*0.70710678118654752f));
            size_t o = (size_t)row*N + col;
            if (resid) v += resid[o];
            stc(&C[o], v);
        }
    }
}

// -------- 3x3 stride-2 pad-1 conv as MFMA GEMM (im2col in the A-stager) ---
// M=3136, N=256, K=2304; k = ci*9 + kh*3 + kw
__global__ __launch_bounds__(256) void conv_mfma(const float* __restrict__ x,
                       const float* __restrict__ wgt, float* __restrict__ C)
{
    const int K = 2304, N = 256;
    __shared__ __align__(16) short As[64*40];
    __shared__ __align__(16) short Ws[64*40];
    int t = threadIdx.x;
    int n0 = blockIdx.x*64, m0 = blockIdx.y*64;
    int lane = t & 63, w = t >> 6;
    int quad = lane >> 4, mrow = lane & 15;
    floatx4 acc[4] = {{0,0,0,0},{0,0,0,0},{0,0,0,0},{0,0,0,0}};
    int r  = t >> 2;
    int kq = (t & 3) * 8;
    int m = m0 + r;
    int wo = m%28, ho = (m/28)%28, b = m/784;
    const float* Wrow = wgt + (size_t)(n0 + r)*K + kq;
    for (int k0 = 0; k0 < K; k0 += 32){
        short av[8];
        #pragma unroll
        for (int jj=0; jj<8; jj++){
            int k = k0 + kq + jj;
            int ci = k/9; int pos = k - ci*9;
            int kh = pos/3, kw = pos - kh*3;
            int ih = 2*ho + kh - 1, iw = 2*wo + kw - 1;
            float a = 0.f;
            if (ih>=0 && ih<56 && iw>=0 && iw<56)
                a = x[(((size_t)b*56 + ih)*56 + iw)*256 + ci];
            av[jj] = f2s(a);
        }
        float4 w1 = *(const float4*)(Wrow + k0);
        float4 w2 = *(const float4*)(Wrow + k0 + 4);
        short8 wv = { f2s(w1.x), f2s(w1.y), f2s(w1.z), f2s(w1.w),
                      f2s(w2.x), f2s(w2.y), f2s(w2.z), f2s(w2.w) };
        __syncthreads();
        *(short8*)&As[r*40 + kq] = *(short8*)av;
        *(short8*)&Ws[r*40 + kq] = wv;
        __syncthreads();
        short8 af = *(short8*)&As[(w*16 + mrow)*40 + quad*8];
        #pragma unroll
        for (int nt=0; nt<4; nt++){
            short8 bfv = *(short8*)&Ws[(nt*16 + mrow)*40 + quad*8];
            acc[nt] = __builtin_amdgcn_mfma_f32_16x16x32_bf16(af, bfv, acc[nt], 0, 0, 0);
        }
    }
    #pragma unroll
    for (int nt=0; nt<4; nt++){
        int col = n0 + nt*16 + mrow;
        #pragma unroll
        for (int rr=0; rr<4; rr++){
            int row = m0 + w*16 + quad*4 + rr;
            C[(size_t)row*N + col] = acc[nt][rr];
        }
    }
}

// ---------------- Group attention scores: softmax((k . q_nb + rpb)*scale) --
__global__ void grp_attn_kernel(const bf16* __restrict__ kproj, const float* __restrict__ qbuf,
                                const float* __restrict__ rpb, const float* __restrict__ g_tau,
                                float* __restrict__ attn)
{
    int idx = blockIdx.x;   // b*3136 + n*784 + i*28 + j
    int j = idx%28; int i = (idx/28)%28; int n = (idx/784)%4; int b = idx/3136;
    int lane = threadIdx.x; // 64
    int sh = n>>1, sw = n&1;
    const bf16* kv = kproj + ((size_t)b*3136 + (2*i+sh)*56 + (2*j+sw))*256;
    __shared__ float sc[9];
    int i0 = min(max(i-1,0),25), j0 = min(max(j-1,0),25);
    for (int l=0; l<9; l++){
        int qi = i0 + l/3, qj = j0 + l%3;
        const float* qv = qbuf + ((size_t)b*784 + qi*28+qj)*256;
        float p = 0.f;
        for (int d=lane; d<256; d+=64) p += b2f(kv[d])*qv[d];
        for (int off=32; off>0; off>>=1) p += __shfl_down(p, off, 64);
        if (lane==0) sc[l] = p;
    }
    __syncthreads();
    if (lane==0){
        float scale = expf(g_tau[0]);
        float s[9]; float m = -1e30f;
        for (int l=0; l<9; l++){ s[l] = sanit((sc[l] + rpb[n*9+l])*scale); m = fmaxf(m, s[l]); }
        float sum = 0.f;
        for (int l=0; l<9; l++){ s[l] = expf(s[l]-m); sum += s[l]; }
        float inv = 1.f/fmaxf(sum, 1e-30f);
        float* ap = attn + (size_t)idx*9;
        for (int l=0; l<9; l++) ap[l] = s[l]*inv + 1e-6f;
    }
}

__global__ void zero_kernel(float* __restrict__ p, int n)
{
    int t = blockIdx.x*256 + threadIdx.x;
    if (t < n) p[t] = 0.f;
}

__global__ void grp_scatter_kernel(const float* __restrict__ attn, float* __restrict__ col)
{
    int t = blockIdx.x*256 + threadIdx.x;   // 4*4*784*9
    if (t >= 4*4*784*9) return;
    int l = t%9; int rest = t/9;
    int j = rest%28; int i = (rest/28)%28; int b = rest/3136;
    int i0 = min(max(i-1,0),25), j0 = min(max(j-1,0),25);
    int qp = (i0 + l/3)*28 + (j0 + l%3);
    atomicAdd(&col[b*784+qp], attn[t]);
}

__global__ void grp_av_kernel(const float* __restrict__ attn, const float* __restrict__ col,
                              const bf16* __restrict__ vproj, float* __restrict__ xout)
{
    int idx = blockIdx.x;   // b*784 + i*28 + j
    int j = idx%28; int i = (idx/28)%28; int b = idx/784;
    int d = threadIdx.x;
    int i0 = min(max(i-1,0),25), j0 = min(max(j-1,0),25);
    float acc = 0.f;
    for (int n=0; n<4; n++){
        int sh = n>>1, sw = n&1;
        const float* ap = attn + ((size_t)(b*4+n)*784 + i*28+j)*9;
        for (int l=0; l<9; l++){
            int qi = i0 + l/3, qj = j0 + l%3;
            float dv = col[b*784 + qi*28+qj] + 1e-8f;
            acc += (ap[l]/dv) * b2f(vproj[((size_t)b*3136 + (2*qi+sh)*56 + (2*qj+sw))*256 + d]);
        }
    }
    xout[(size_t)idx*256 + d] += acc;
}

// ---------------- RoPE in place on q,k sections of qkv (B,784,3,8,32) -----
__global__ void rope_kernel(float* __restrict__ qkv)
{
    int idx = blockIdx.x*256 + threadIdx.x;   // B*784*2*8*16 = 802816
    int u = idx%16; int h = (idx/16)%8; int s = (idx/128)%2;
    int t = (idx/256)%784; int b = idx/(256*784);
    float f = expf(-((float)(2*u)/32.f)*logf(10000.f));
    float ang = (float)t * f;
    float c = cosf(ang), sn = sinf(ang);
    float* p = qkv + ((size_t)(b*784+t))*768 + s*256 + h*32 + 2*u;
    float x0 = p[0], x1 = p[1];
    p[0] = x0*c - x1*sn;
    p[1] = x1*c + x0*sn;
}

// ---------------- Block attention (KB=7): fused scores+softmax+AV ---------
__global__ void blk_attn_fused(const float* __restrict__ qkv, float* __restrict__ obuf)
{
    int idx = blockIdx.x;   // (b*8+h)*784 + t
    int t = idx%784; int h = (idx/784)%8; int b = idx/6272;
    int i = t/28, j = t%28;
    int lane = threadIdx.x; // 64
    __shared__ float qs[32];
    __shared__ float red[64];
    __shared__ float a[49];
    if (lane < 32) qs[lane] = qkv[((size_t)(b*784+t))*768 + h*32 + lane];
    __syncthreads();
    int i0 = min(max(i-3,0),21), j0 = min(max(j-3,0),21);
    float score = -1e30f;
    if (lane < 49){
        int ki = i0 + lane/7, kj = j0 + lane%7;
        const float* kp = qkv + ((size_t)(b*784 + ki*28+kj))*768 + 256 + h*32;
        float p = 0.f;
        #pragma unroll
        for (int d=0; d<32; d++) p += qs[d]*kp[d];
        score = sanit(p * 0.17677669529663687f);
    }
    red[lane] = score;
    __syncthreads();
    if (lane==0){
        float m = -1e30f;
        for (int l=0; l<49; l++) m = fmaxf(m, red[l]);
        float s = 0.f;
        for (int l=0; l<49; l++){ float e = expf(red[l]-m); a[l] = e; s += e; }
        float inv = 1.f/fmaxf(s, 1e-30f);
        for (int l=0; l<49; l++) a[l] *= inv;
    }
    __syncthreads();
    if (lane < 32){
        float acc = 0.f;
        for (int l=0; l<49; l++){
            int ki = i0 + l/7, kj = j0 + l%7;
            acc += a[l] * qkv[((size_t)(b*784 + ki*28+kj))*768 + 512 + h*32 + lane];
        }
        obuf[((size_t)(b*784+t))*256 + h*32 + lane] = acc;
    }
}

__global__ void copy_out_kernel(const float* __restrict__ in, float* __restrict__ out, int n)
{
    int t = blockIdx.x*256 + threadIdx.x;
    if (t < n) out[t] = in[t];
}

// ==========================================================================
extern "C" void kernel_launch(void* const* d_in, const int* in_sizes, int n_in,
                              void* d_out, int out_size, void* d_ws, size_t ws_size,
                              hipStream_t stream) {
    const float* x         = (const float*)d_in[0];
    const float* g_seed_w  = (const float*)d_in[1];
    const float* g_q_w     = (const float*)d_in[2];
    const float* g_k_w     = (const float*)d_in[3];
    const float* g_v_w     = (const float*)d_in[4];
    const float* g_mlp_w1  = (const float*)d_in[5];
    const float* g_mlp_b1  = (const float*)d_in[6];
    const float* g_mlp_w2  = (const float*)d_in[7];
    const float* g_mlp_b2  = (const float*)d_in[8];
    const float* g_ln_in_g = (const float*)d_in[9];
    const float* g_ln_in_b = (const float*)d_in[10];
    const float* g_ln_out_g= (const float*)d_in[11];
    const float* g_ln_out_b= (const float*)d_in[12];
    const float* g_tau     = (const float*)d_in[13];
    const float* g_rpb     = (const float*)d_in[14];
    const float* blk_ln1_g = (const float*)d_in[15];
    const float* blk_ln1_b = (const float*)d_in[16];
    const float* blk_qkv_w = (const float*)d_in[17];
    const float* blk_proj_w= (const float*)d_in[18];
    const float* blk_proj_b= (const float*)d_in[19];
    const float* blk_ln2_g = (const float*)d_in[20];
    const float* blk_ln2_b = (const float*)d_in[21];
    const float* blk_mlp_w1= (const float*)d_in[22];
    const float* blk_mlp_b1= (const float*)d_in[23];
    const float* blk_mlp_w2= (const float*)d_in[24];
    const float* blk_mlp_b2= (const float*)d_in[25];

    // workspace layout — 8,144,192 floats-equivalent = 32.6 MB
    float* f     = (float*)d_ws;
    bf16*  kproj = (bf16*)d_ws;          // 3211264 bf16 (= 1605632 floats)
    bf16*  vproj = kproj + 3211264;      // 3211264 bf16
    float* xout  = f + 3211264;          // 802816
    float* tmp   = xout  + 802816;       // 802816
    float* qbuf  = tmp   + 802816;       // 802816
    float* big   = qbuf  + 802816;       // 2408448 (3136x768)
    float* attng = big   + 2408448;      // 112896  (4*4*784*9)
    float* col   = attng + 112896;       // 3136
    // xln aliases qbuf+big (exactly 3211264 floats); both dead at setup time
    float* xln   = qbuf;

    // ---- setup ----
    ln256_kernel<<<12544, 256, 0, stream>>>(x, g_ln_in_g, g_ln_in_b, xln, 0);
    gemm_mfma<bf16><<<dim3(4,196), 256, 0, stream>>>(xln, g_k_w, nullptr, nullptr, kproj, 12544,256,256, 0);
    gemm_mfma<bf16><<<dim3(4,196), 256, 0, stream>>>(x,   g_v_w, nullptr, nullptr, vproj, 12544,256,256, 0);
    conv_mfma<<<dim3(4,49), 256, 0, stream>>>(x, g_seed_w, tmp);
    ln256_kernel<<<3136, 256, 0, stream>>>(tmp, g_ln_out_g, g_ln_out_b, xout, 0);

    // ---- NUM_ITERS group-attention iterations ----
    for (int it=0; it<3; it++){
        ln256_kernel<<<3136, 256, 0, stream>>>(xout, g_ln_out_g, g_ln_out_b, tmp, 0);
        gemm_mfma<float><<<dim3(4,49), 256, 0, stream>>>(tmp, g_q_w, nullptr, nullptr, qbuf, 3136,256,256, 0);
        grp_attn_kernel<<<12544, 64, 0, stream>>>(kproj, qbuf, g_rpb, g_tau, attng);
        zero_kernel<<<(3136+255)/256, 256, 0, stream>>>(col, 3136);
        grp_scatter_kernel<<<(112896+255)/256, 256, 0, stream>>>(attng, col);
        grp_av_kernel<<<3136, 256, 0, stream>>>(attng, col, vproj, xout);
        gemm_mfma<float><<<dim3(8,49), 256, 0, stream>>>(xout, g_mlp_w1, g_mlp_b1, nullptr, big, 3136,512,256, 1);
        gemm_mfma<float><<<dim3(4,49), 256, 0, stream>>>(big, g_mlp_w2, g_mlp_b2, nullptr, tmp, 3136,256,512, 0);
        ln256_kernel<<<3136, 256, 0, stream>>>(tmp, g_ln_out_g, g_ln_out_b, xout, 1);
    }

    // ---- DEPTH transformer blocks ----
    for (int l=0; l<2; l++){
        ln256_kernel<<<3136, 256, 0, stream>>>(xout, blk_ln1_g + l*256, blk_ln1_b + l*256, tmp, 0);
        gemm_mfma<float><<<dim3(12,49), 256, 0, stream>>>(tmp, blk_qkv_w + (size_t)l*768*256, nullptr, nullptr, big, 3136,768,256, 0);
        rope_kernel<<<3136, 256, 0, stream>>>(big);
        blk_attn_fused<<<25088, 64, 0, stream>>>(big, qbuf);
        gemm_mfma<float><<<dim3(4,49), 256, 0, stream>>>(qbuf, blk_proj_w + (size_t)l*256*256, blk_proj_b + l*256, xout, xout, 3136,256,256, 0);
        ln256_kernel<<<3136, 256, 0, stream>>>(xout, blk_ln2_g + l*256, blk_ln2_b + l*256, tmp, 0);
        gemm_mfma<float><<<dim3(12,49), 256, 0, stream>>>(tmp, blk_mlp_w1 + (size_t)l*768*256, blk_mlp_b1 + l*768, nullptr, big, 3136,768,256, 1);
        gemm_mfma<float><<<dim3(4,49), 256, 0, stream>>>(big, blk_mlp_w2 + (size_t)l*256*768, blk_mlp_b2 + l*256, xout, xout, 3136,256,768, 0);
    }

    copy_out_kernel<<<(802816+255)/256, 256, 0, stream>>>(xout, (float*)d_out, 802816);
}

// Round 6
// 854.125 us; speedup vs baseline: 5.8498x; 1.0256x over previous
//
#include <hip/hip_runtime.h>
#include <hip/hip_bf16.h>
#include <math.h>

typedef __hip_bfloat16 bf16;

#define LN_EPS 1e-5f

__device__ __forceinline__ float b2f(bf16 x){ return __bfloat162float(x); }
__device__ __forceinline__ float sanit(float s){ return fminf(fmaxf(s, -80.f), 80.f); }

__device__ __forceinline__ void stc(float* p, float v){ *p = v; }
__device__ __forceinline__ void stc(bf16* p, float v){ *p = __float2bfloat16(v); }

__device__ __forceinline__ short f2s(float f){
    union { __hip_bfloat16 h; short s; } u; u.h = __float2bfloat16(f); return u.s;
}

using short8  = __attribute__((ext_vector_type(8))) short;
using floatx4 = __attribute__((ext_vector_type(4))) float;

// ---------------- LayerNorm over D=256, one token per 256-thread block ----
__global__ void ln256_kernel(const float* __restrict__ in, const float* __restrict__ g,
                             const float* __restrict__ bb, float* __restrict__ out, int addTo)
{
    int token = blockIdx.x; int d = threadIdx.x;
    __shared__ float red[256];
    float v = in[(size_t)token*256 + d];
    red[d] = v; __syncthreads();
    for (int s=128; s>0; s>>=1){ if (d<s) red[d]+=red[d+s]; __syncthreads(); }
    float mean = red[0]*(1.f/256.f);
    __syncthreads();
    float dev = v - mean;
    red[d] = dev*dev; __syncthreads();
    for (int s=128; s>0; s>>=1){ if (d<s) red[d]+=red[d+s]; __syncthreads(); }
    float var = red[0]*(1.f/256.f);
    float r = dev*rsqrtf(var+LN_EPS)*g[d] + bb[d];
    size_t o = (size_t)token*256+d;
    if (addTo) out[o] += r; else out[o] = r;
}

// ---------------- MFMA GEMM: C = act(A[M,K] @ W[N,K]^T + bias) + resid ----
// TM x 64 block tile, TM/16 waves (wave w = rows w*16..+15 x 64 cols),
// BK=32 via LDS with fp32->bf16 conversion. LDS rows padded to 40 shorts
// (20 banks) -> worst 2-way bank conflict (free, m136).
// Requires: M%TM==0, N%64==0, K%32==0 (true at all call sites).
template<typename TC, int TM>
__global__ __launch_bounds__(TM*4) void gemm_mfma(const float* __restrict__ A,
                       const float* __restrict__ W,
                       const float* __restrict__ bias, const float* __restrict__ resid,
                       TC* __restrict__ C, int M, int N, int K, int do_gelu)
{
    __shared__ __align__(16) short As[TM*40];
    __shared__ __align__(16) short Ws[64*40];
    int t = threadIdx.x;
    int n0 = blockIdx.x*64, m0 = blockIdx.y*TM;
    int lane = t & 63, w = t >> 6;
    int quad = lane >> 4, mrow = lane & 15;
    floatx4 acc[4] = {{0,0,0,0},{0,0,0,0},{0,0,0,0},{0,0,0,0}};
    int r  = t >> 2;          // 0..TM-1: staging row
    int kq = (t & 3) * 8;     // 0,8,16,24: k-offset within BK
    const float* Arow  = A + (size_t)(m0 + r)*K + kq;
    const float* Wrow0 = W + (size_t)(n0 + r)*K + kq;
    for (int k0 = 0; k0 < K; k0 += 32){
        float4 a1 = *(const float4*)(Arow + k0);
        float4 a2 = *(const float4*)(Arow + k0 + 4);
        float4 w1 = *(const float4*)(Wrow0 + k0);
        float4 w2 = *(const float4*)(Wrow0 + k0 + 4);
        short8 av = { f2s(a1.x), f2s(a1.y), f2s(a1.z), f2s(a1.w),
                      f2s(a2.x), f2s(a2.y), f2s(a2.z), f2s(a2.w) };
        short8 wv0 = { f2s(w1.x), f2s(w1.y), f2s(w1.z), f2s(w1.w),
                       f2s(w2.x), f2s(w2.y), f2s(w2.z), f2s(w2.w) };
        short8 wv1;
        if (TM == 32){
            const float* Wrow1 = W + (size_t)(n0 + r + 32)*K + kq;
            float4 u1 = *(const float4*)(Wrow1 + k0);
            float4 u2 = *(const float4*)(Wrow1 + k0 + 4);
            wv1 = (short8){ f2s(u1.x), f2s(u1.y), f2s(u1.z), f2s(u1.w),
                            f2s(u2.x), f2s(u2.y), f2s(u2.z), f2s(u2.w) };
        }
        __syncthreads();
        *(short8*)&As[r*40 + kq] = av;
        *(short8*)&Ws[r*40 + kq] = wv0;
        if (TM == 32) *(short8*)&Ws[(r+32)*40 + kq] = wv1;
        __syncthreads();
        short8 af = *(short8*)&As[(w*16 + mrow)*40 + quad*8];
        #pragma unroll
        for (int nt=0; nt<4; nt++){
            short8 bfv = *(short8*)&Ws[(nt*16 + mrow)*40 + quad*8];
            acc[nt] = __builtin_amdgcn_mfma_f32_16x16x32_bf16(af, bfv, acc[nt], 0, 0, 0);
        }
    }
    #pragma unroll
    for (int nt=0; nt<4; nt++){
        int col = n0 + nt*16 + mrow;
        float bv = bias ? bias[col] : 0.f;
        #pragma unroll
        for (int rr=0; rr<4; rr++){
            int row = m0 + w*16 + quad*4 + rr;
            float v = acc[nt][rr] + bv;
            if (do_gelu) v = 0.5f*v*(1.0f+erff(v*0.70710678118654752f));
            size_t o = (size_t)row*N + col;
            if (resid) v += resid[o];
            stc(&C[o], v);
        }
    }
}

// -------- seed-weight transpose: w[o][ci][kh][kw] -> wt[o][pos][ci] -------
__global__ void transpose_seedw(const float* __restrict__ w, float* __restrict__ wt)
{
    int idx = blockIdx.x*256 + threadIdx.x;   // 256*2304
    if (idx >= 256*2304) return;
    int o = idx/2304; int rem = idx - o*2304; int pos = rem>>8; int ci = rem&255;
    wt[idx] = w[(size_t)o*2304 + ci*9 + pos];
}

// -------- 3x3 stride-2 pad-1 conv as MFMA GEMM, k = pos*256+ci ordering ---
// A-stage fully coalesced (contiguous ci within one pos); wt rows contiguous.
// M=3136, N=256, K=2304. TM=32, 128 threads.
__global__ __launch_bounds__(128) void conv_mfma(const float* __restrict__ x,
                       const float* __restrict__ wt, float* __restrict__ C)
{
    const int K = 2304, N = 256;
    __shared__ __align__(16) short As[32*40];
    __shared__ __align__(16) short Ws[64*40];
    int t = threadIdx.x;
    int n0 = blockIdx.x*64, m0 = blockIdx.y*32;
    int lane = t & 63, w = t >> 6;
    int quad = lane >> 4, mrow = lane & 15;
    floatx4 acc[4] = {{0,0,0,0},{0,0,0,0},{0,0,0,0},{0,0,0,0}};
    int r  = t >> 2;
    int kq = (t & 3) * 8;
    int m = m0 + r;
    int wo = m%28, ho = (m/28)%28, b = m/784;
    const float* Wrow0 = wt + (size_t)(n0 + r)*K + kq;
    const float* Wrow1 = wt + (size_t)(n0 + r + 32)*K + kq;
    for (int k0 = 0; k0 < K; k0 += 32){
        int kk = k0 + kq;
        int pos = kk >> 8, ci = kk & 255;
        int kh = pos/3, kw = pos - kh*3;
        int ih = 2*ho + kh - 1, iw = 2*wo + kw - 1;
        float4 a1 = {0,0,0,0}, a2 = {0,0,0,0};
        if (ih>=0 && ih<56 && iw>=0 && iw<56){
            const float* px = x + (((size_t)b*56 + ih)*56 + iw)*256 + ci;
            a1 = *(const float4*)px;
            a2 = *(const float4*)(px + 4);
        }
        float4 w1 = *(const float4*)(Wrow0 + k0);
        float4 w2 = *(const float4*)(Wrow0 + k0 + 4);
        float4 u1 = *(const float4*)(Wrow1 + k0);
        float4 u2 = *(const float4*)(Wrow1 + k0 + 4);
        short8 av = { f2s(a1.x), f2s(a1.y), f2s(a1.z), f2s(a1.w),
                      f2s(a2.x), f2s(a2.y), f2s(a2.z), f2s(a2.w) };
        short8 wv0 = { f2s(w1.x), f2s(w1.y), f2s(w1.z), f2s(w1.w),
                       f2s(w2.x), f2s(w2.y), f2s(w2.z), f2s(w2.w) };
        short8 wv1 = { f2s(u1.x), f2s(u1.y), f2s(u1.z), f2s(u1.w),
                       f2s(u2.x), f2s(u2.y), f2s(u2.z), f2s(u2.w) };
        __syncthreads();
        *(short8*)&As[r*40 + kq] = av;
        *(short8*)&Ws[r*40 + kq] = wv0;
        *(short8*)&Ws[(r+32)*40 + kq] = wv1;
        __syncthreads();
        short8 af = *(short8*)&As[(w*16 + mrow)*40 + quad*8];
        #pragma unroll
        for (int nt=0; nt<4; nt++){
            short8 bfv = *(short8*)&Ws[(nt*16 + mrow)*40 + quad*8];
            acc[nt] = __builtin_amdgcn_mfma_f32_16x16x32_bf16(af, bfv, acc[nt], 0, 0, 0);
        }
    }
    #pragma unroll
    for (int nt=0; nt<4; nt++){
        int col = n0 + nt*16 + mrow;
        #pragma unroll
        for (int rr=0; rr<4; rr++){
            int row = m0 + w*16 + quad*4 + rr;
            C[(size_t)row*N + col] = acc[nt][rr];
        }
    }
}

// ---------------- Group attention scores: softmax((k . q_nb + rpb)*scale) --
__global__ void grp_attn_kernel(const bf16* __restrict__ kproj, const float* __restrict__ qbuf,
                                const float* __restrict__ rpb, const float* __restrict__ g_tau,
                                float* __restrict__ attn)
{
    int idx = blockIdx.x;   // b*3136 + n*784 + i*28 + j
    int j = idx%28; int i = (idx/28)%28; int n = (idx/784)%4; int b = idx/3136;
    int lane = threadIdx.x; // 64
    int sh = n>>1, sw = n&1;
    const bf16* kv = kproj + ((size_t)b*3136 + (2*i+sh)*56 + (2*j+sw))*256;
    __shared__ float sc[9];
    int i0 = min(max(i-1,0),25), j0 = min(max(j-1,0),25);
    for (int l=0; l<9; l++){
        int qi = i0 + l/3, qj = j0 + l%3;
        const float* qv = qbuf + ((size_t)b*784 + qi*28+qj)*256;
        float p = 0.f;
        for (int d=lane; d<256; d+=64) p += b2f(kv[d])*qv[d];
        for (int off=32; off>0; off>>=1) p += __shfl_down(p, off, 64);
        if (lane==0) sc[l] = p;
    }
    __syncthreads();
    if (lane==0){
        float scale = expf(g_tau[0]);
        float s[9]; float m = -1e30f;
        for (int l=0; l<9; l++){ s[l] = sanit((sc[l] + rpb[n*9+l])*scale); m = fmaxf(m, s[l]); }
        float sum = 0.f;
        for (int l=0; l<9; l++){ s[l] = expf(s[l]-m); sum += s[l]; }
        float inv = 1.f/fmaxf(sum, 1e-30f);
        float* ap = attn + (size_t)idx*9;
        for (int l=0; l<9; l++) ap[l] = s[l]*inv + 1e-6f;
    }
}

__global__ void zero_kernel(float* __restrict__ p, int n)
{
    int t = blockIdx.x*256 + threadIdx.x;
    if (t < n) p[t] = 0.f;
}

__global__ void grp_scatter_kernel(const float* __restrict__ attn, float* __restrict__ col)
{
    int t = blockIdx.x*256 + threadIdx.x;   // 4*4*784*9
    if (t >= 4*4*784*9) return;
    int l = t%9; int rest = t/9;
    int j = rest%28; int i = (rest/28)%28; int b = rest/3136;
    int i0 = min(max(i-1,0),25), j0 = min(max(j-1,0),25);
    int qp = (i0 + l/3)*28 + (j0 + l%3);
    atomicAdd(&col[b*784+qp], attn[t]);
}

__global__ void grp_av_kernel(const float* __restrict__ attn, const float* __restrict__ col,
                              const bf16* __restrict__ vproj, float* __restrict__ xout)
{
    int idx = blockIdx.x;   // b*784 + i*28 + j
    int j = idx%28; int i = (idx/28)%28; int b = idx/784;
    int d = threadIdx.x;
    int i0 = min(max(i-1,0),25), j0 = min(max(j-1,0),25);
    float acc = 0.f;
    for (int n=0; n<4; n++){
        int sh = n>>1, sw = n&1;
        const float* ap = attn + ((size_t)(b*4+n)*784 + i*28+j)*9;
        for (int l=0; l<9; l++){
            int qi = i0 + l/3, qj = j0 + l%3;
            float dv = col[b*784 + qi*28+qj] + 1e-8f;
            acc += (ap[l]/dv) * b2f(vproj[((size_t)b*3136 + (2*qi+sh)*56 + (2*qj+sw))*256 + d]);
        }
    }
    xout[(size_t)idx*256 + d] += acc;
}

// ---------------- RoPE in place on q,k sections of qkv (B,784,3,8,32) -----
__global__ void rope_kernel(float* __restrict__ qkv)
{
    int idx = blockIdx.x*256 + threadIdx.x;   // B*784*2*8*16 = 802816
    int u = idx%16; int h = (idx/16)%8; int s = (idx/128)%2;
    int t = (idx/256)%784; int b = idx/(256*784);
    float f = expf(-((float)(2*u)/32.f)*logf(10000.f));
    float ang = (float)t * f;
    float c = cosf(ang), sn = sinf(ang);
    float* p = qkv + ((size_t)(b*784+t))*768 + s*256 + h*32 + 2*u;
    float x0 = p[0], x1 = p[1];
    p[0] = x0*c - x1*sn;
    p[1] = x1*c + x0*sn;
}

// ---------------- Block attention (KB=7): fused scores+softmax+AV ---------
__global__ void blk_attn_fused(const float* __restrict__ qkv, float* __restrict__ obuf)
{
    int idx = blockIdx.x;   // (b*8+h)*784 + t
    int t = idx%784; int h = (idx/784)%8; int b = idx/6272;
    int i = t/28, j = t%28;
    int lane = threadIdx.x; // 64
    __shared__ float qs[32];
    __shared__ float red[64];
    __shared__ float a[49];
    if (lane < 32) qs[lane] = qkv[((size_t)(b*784+t))*768 + h*32 + lane];
    __syncthreads();
    int i0 = min(max(i-3,0),21), j0 = min(max(j-3,0),21);
    float score = -1e30f;
    if (lane < 49){
        int ki = i0 + lane/7, kj = j0 + lane%7;
        const float* kp = qkv + ((size_t)(b*784 + ki*28+kj))*768 + 256 + h*32;
        float p = 0.f;
        #pragma unroll
        for (int d=0; d<32; d++) p += qs[d]*kp[d];
        score = sanit(p * 0.17677669529663687f);
    }
    red[lane] = score;
    __syncthreads();
    if (lane==0){
        float m = -1e30f;
        for (int l=0; l<49; l++) m = fmaxf(m, red[l]);
        float s = 0.f;
        for (int l=0; l<49; l++){ float e = expf(red[l]-m); a[l] = e; s += e; }
        float inv = 1.f/fmaxf(s, 1e-30f);
        for (int l=0; l<49; l++) a[l] *= inv;
    }
    __syncthreads();
    if (lane < 32){
        float acc = 0.f;
        for (int l=0; l<49; l++){
            int ki = i0 + l/7, kj = j0 + l%7;
            acc += a[l] * qkv[((size_t)(b*784 + ki*28+kj))*768 + 512 + h*32 + lane];
        }
        obuf[((size_t)(b*784+t))*256 + h*32 + lane] = acc;
    }
}

// ==========================================================================
extern "C" void kernel_launch(void* const* d_in, const int* in_sizes, int n_in,
                              void* d_out, int out_size, void* d_ws, size_t ws_size,
                              hipStream_t stream) {
    const float* x         = (const float*)d_in[0];
    const float* g_seed_w  = (const float*)d_in[1];
    const float* g_q_w     = (const float*)d_in[2];
    const float* g_k_w     = (const float*)d_in[3];
    const float* g_v_w     = (const float*)d_in[4];
    const float* g_mlp_w1  = (const float*)d_in[5];
    const float* g_mlp_b1  = (const float*)d_in[6];
    const float* g_mlp_w2  = (const float*)d_in[7];
    const float* g_mlp_b2  = (const float*)d_in[8];
    const float* g_ln_in_g = (const float*)d_in[9];
    const float* g_ln_in_b = (const float*)d_in[10];
    const float* g_ln_out_g= (const float*)d_in[11];
    const float* g_ln_out_b= (const float*)d_in[12];
    const float* g_tau     = (const float*)d_in[13];
    const float* g_rpb     = (const float*)d_in[14];
    const float* blk_ln1_g = (const float*)d_in[15];
    const float* blk_ln1_b = (const float*)d_in[16];
    const float* blk_qkv_w = (const float*)d_in[17];
    const float* blk_proj_w= (const float*)d_in[18];
    const float* blk_proj_b= (const float*)d_in[19];
    const float* blk_ln2_g = (const float*)d_in[20];
    const float* blk_ln2_b = (const float*)d_in[21];
    const float* blk_mlp_w1= (const float*)d_in[22];
    const float* blk_mlp_b1= (const float*)d_in[23];
    const float* blk_mlp_w2= (const float*)d_in[24];
    const float* blk_mlp_b2= (const float*)d_in[25];

    // workspace layout — 8,144,192 floats-equivalent = 32.6 MB
    float* f     = (float*)d_ws;
    bf16*  kproj = (bf16*)d_ws;          // 3211264 bf16 (= 1605632 floats)
    bf16*  vproj = kproj + 3211264;      // 3211264 bf16
    float* xout  = f + 3211264;          // 802816
    float* tmp   = xout  + 802816;       // 802816
    float* qbuf  = tmp   + 802816;       // 802816
    float* big   = qbuf  + 802816;       // 2408448 (3136x768)
    float* attng = big   + 2408448;      // 112896  (4*4*784*9)
    float* col   = attng + 112896;       // 3136
    // xln aliases qbuf+big (exactly 3211264 floats); both dead at setup time
    float* xln   = qbuf;
    // transposed seed weights alias big (589824 floats); dead before iter-0 MLP
    float* seedwt = big;

    // ---- setup ----
    ln256_kernel<<<12544, 256, 0, stream>>>(x, g_ln_in_g, g_ln_in_b, xln, 0);
    gemm_mfma<bf16,32><<<dim3(4,392), 128, 0, stream>>>(xln, g_k_w, nullptr, nullptr, kproj, 12544,256,256, 0);
    gemm_mfma<bf16,32><<<dim3(4,392), 128, 0, stream>>>(x,   g_v_w, nullptr, nullptr, vproj, 12544,256,256, 0);
    transpose_seedw<<<2304, 256, 0, stream>>>(g_seed_w, seedwt);
    conv_mfma<<<dim3(4,98), 128, 0, stream>>>(x, seedwt, tmp);
    ln256_kernel<<<3136, 256, 0, stream>>>(tmp, g_ln_out_g, g_ln_out_b, xout, 0);

    // ---- NUM_ITERS group-attention iterations ----
    for (int it=0; it<3; it++){
        ln256_kernel<<<3136, 256, 0, stream>>>(xout, g_ln_out_g, g_ln_out_b, tmp, 0);
        gemm_mfma<float,32><<<dim3(4,98), 128, 0, stream>>>(tmp, g_q_w, nullptr, nullptr, qbuf, 3136,256,256, 0);
        grp_attn_kernel<<<12544, 64, 0, stream>>>(kproj, qbuf, g_rpb, g_tau, attng);
        zero_kernel<<<(3136+255)/256, 256, 0, stream>>>(col, 3136);
        grp_scatter_kernel<<<(112896+255)/256, 256, 0, stream>>>(attng, col);
        grp_av_kernel<<<3136, 256, 0, stream>>>(attng, col, vproj, xout);
        gemm_mfma<float,32><<<dim3(8,98), 128, 0, stream>>>(xout, g_mlp_w1, g_mlp_b1, nullptr, big, 3136,512,256, 1);
        gemm_mfma<float,32><<<dim3(4,98), 128, 0, stream>>>(big, g_mlp_w2, g_mlp_b2, nullptr, tmp, 3136,256,512, 0);
        ln256_kernel<<<3136, 256, 0, stream>>>(tmp, g_ln_out_g, g_ln_out_b, xout, 1);
    }

    // ---- DEPTH transformer blocks ----
    for (int l=0; l<2; l++){
        ln256_kernel<<<3136, 256, 0, stream>>>(xout, blk_ln1_g + l*256, blk_ln1_b + l*256, tmp, 0);
        gemm_mfma<float,32><<<dim3(12,98), 128, 0, stream>>>(tmp, blk_qkv_w + (size_t)l*768*256, nullptr, nullptr, big, 3136,768,256, 0);
        rope_kernel<<<3136, 256, 0, stream>>>(big);
        blk_attn_fused<<<25088, 64, 0, stream>>>(big, qbuf);
        gemm_mfma<float,32><<<dim3(4,98), 128, 0, stream>>>(qbuf, blk_proj_w + (size_t)l*256*256, blk_proj_b + l*256, xout, xout, 3136,256,256, 0);
        ln256_kernel<<<3136, 256, 0, stream>>>(xout, blk_ln2_g + l*256, blk_ln2_b + l*256, tmp, 0);
        gemm_mfma<float,32><<<dim3(12,98), 128, 0, stream>>>(tmp, blk_mlp_w1 + (size_t)l*768*256, blk_mlp_b1 + l*768, nullptr, big, 3136,768,256, 1);
        // final layer writes d_out directly (xout dead afterwards)
        float* Cout = (l==1) ? (float*)d_out : xout;
        gemm_mfma<float,32><<<dim3(4,98), 128, 0, stream>>>(big, blk_mlp_w2 + (size_t)l*256*768, blk_mlp_b2 + l*256, xout, Cout, 3136,256,768, 0);
    }
}

// Round 7
// 721.420 us; speedup vs baseline: 6.9259x; 1.1840x over previous
//
#include <hip/hip_runtime.h>
#include <hip/hip_bf16.h>
#include <math.h>

typedef __hip_bfloat16 bf16;

#define LN_EPS 1e-5f

__device__ __forceinline__ float b2f(bf16 x){ return __bfloat162float(x); }
__device__ __forceinline__ float sanit(float s){ return fminf(fmaxf(s, -80.f), 80.f); }

__device__ __forceinline__ void stc(float* p, float v){ *p = v; }
__device__ __forceinline__ void stc(bf16* p, float v){ *p = __float2bfloat16(v); }

__device__ __forceinline__ short f2s(float f){
    union { __hip_bfloat16 h; short s; } u; u.h = __float2bfloat16(f); return u.s;
}

using short8  = __attribute__((ext_vector_type(8))) short;
using floatx4 = __attribute__((ext_vector_type(4))) float;

// ---------------- LayerNorm over D=256: wave-shuffle reduction ------------
__global__ void ln256_kernel(const float* __restrict__ in, const float* __restrict__ g,
                             const float* __restrict__ bb, float* __restrict__ out, int addTo)
{
    int token = blockIdx.x; int d = threadIdx.x;
    int w = d >> 6, lane = d & 63;
    __shared__ float part[8];
    float v = in[(size_t)token*256 + d];
    float s = v;
    #pragma unroll
    for (int off=32; off>0; off>>=1) s += __shfl_down(s, off);
    if (lane==0) part[w] = s;
    __syncthreads();
    float mean = (part[0]+part[1]+part[2]+part[3]) * (1.f/256.f);
    float dev = v - mean;
    float q = dev*dev;
    __syncthreads();
    #pragma unroll
    for (int off=32; off>0; off>>=1) q += __shfl_down(q, off);
    if (lane==0) part[w+4] = q;
    __syncthreads();
    float var = (part[4]+part[5]+part[6]+part[7]) * (1.f/256.f);
    float r = dev*rsqrtf(var+LN_EPS)*g[d] + bb[d];
    size_t o = (size_t)token*256+d;
    if (addTo) out[o] += r; else out[o] = r;
}

// ---------------- MFMA GEMM: C = act(A[M,K] @ W[N,K]^T + bias) + resid ----
// TM x 64 block tile, TM/16 waves, BK=32 via LDS (fp32->bf16). Rows padded
// to 40 shorts (20 banks) -> worst 2-way bank conflict (free).
// Requires: M%TM==0, N%64==0, K%32==0.
template<typename TC, int TM>
__global__ __launch_bounds__(TM*4) void gemm_mfma(const float* __restrict__ A,
                       const float* __restrict__ W,
                       const float* __restrict__ bias, const float* __restrict__ resid,
                       TC* __restrict__ C, int M, int N, int K, int do_gelu)
{
    __shared__ __align__(16) short As[TM*40];
    __shared__ __align__(16) short Ws[64*40];
    int t = threadIdx.x;
    int n0 = blockIdx.x*64, m0 = blockIdx.y*TM;
    int lane = t & 63, w = t >> 6;
    int quad = lane >> 4, mrow = lane & 15;
    floatx4 acc[4] = {{0,0,0,0},{0,0,0,0},{0,0,0,0},{0,0,0,0}};
    int r  = t >> 2;
    int kq = (t & 3) * 8;
    const float* Arow  = A + (size_t)(m0 + r)*K + kq;
    const float* Wrow0 = W + (size_t)(n0 + r)*K + kq;
    for (int k0 = 0; k0 < K; k0 += 32){
        float4 a1 = *(const float4*)(Arow + k0);
        float4 a2 = *(const float4*)(Arow + k0 + 4);
        float4 w1 = *(const float4*)(Wrow0 + k0);
        float4 w2 = *(const float4*)(Wrow0 + k0 + 4);
        short8 av = { f2s(a1.x), f2s(a1.y), f2s(a1.z), f2s(a1.w),
                      f2s(a2.x), f2s(a2.y), f2s(a2.z), f2s(a2.w) };
        short8 wv0 = { f2s(w1.x), f2s(w1.y), f2s(w1.z), f2s(w1.w),
                       f2s(w2.x), f2s(w2.y), f2s(w2.z), f2s(w2.w) };
        short8 wv1;
        if (TM == 32){
            const float* Wrow1 = W + (size_t)(n0 + r + 32)*K + kq;
            float4 u1 = *(const float4*)(Wrow1 + k0);
            float4 u2 = *(const float4*)(Wrow1 + k0 + 4);
            wv1 = (short8){ f2s(u1.x), f2s(u1.y), f2s(u1.z), f2s(u1.w),
                            f2s(u2.x), f2s(u2.y), f2s(u2.z), f2s(u2.w) };
        }
        __syncthreads();
        *(short8*)&As[r*40 + kq] = av;
        *(short8*)&Ws[r*40 + kq] = wv0;
        if (TM == 32) *(short8*)&Ws[(r+32)*40 + kq] = wv1;
        __syncthreads();
        short8 af = *(short8*)&As[(w*16 + mrow)*40 + quad*8];
        #pragma unroll
        for (int nt=0; nt<4; nt++){
            short8 bfv = *(short8*)&Ws[(nt*16 + mrow)*40 + quad*8];
            acc[nt] = __builtin_amdgcn_mfma_f32_16x16x32_bf16(af, bfv, acc[nt], 0, 0, 0);
        }
    }
    #pragma unroll
    for (int nt=0; nt<4; nt++){
        int col = n0 + nt*16 + mrow;
        float bv = bias ? bias[col] : 0.f;
        #pragma unroll
        for (int rr=0; rr<4; rr++){
            int row = m0 + w*16 + quad*4 + rr;
            float v = acc[nt][rr] + bv;
            if (do_gelu) v = 0.5f*v*(1.0f+erff(v*0.70710678118654752f));
            size_t o = (size_t)row*N + col;
            if (resid) v += resid[o];
            stc(&C[o], v);
        }
    }
}

// -------- seed-weight transpose: w[o][ci][kh][kw] -> wt[o][pos][ci] -------
__global__ void transpose_seedw(const float* __restrict__ w, float* __restrict__ wt)
{
    int idx = blockIdx.x*256 + threadIdx.x;   // 256*2304
    if (idx >= 256*2304) return;
    int o = idx/2304; int rem = idx - o*2304; int pos = rem>>8; int ci = rem&255;
    wt[idx] = w[(size_t)o*2304 + ci*9 + pos];
}

// -------- 3x3 stride-2 pad-1 conv as MFMA GEMM, k = pos*256+ci ordering ---
__global__ __launch_bounds__(128) void conv_mfma(const float* __restrict__ x,
                       const float* __restrict__ wt, float* __restrict__ C)
{
    const int K = 2304, N = 256;
    __shared__ __align__(16) short As[32*40];
    __shared__ __align__(16) short Ws[64*40];
    int t = threadIdx.x;
    int n0 = blockIdx.x*64, m0 = blockIdx.y*32;
    int lane = t & 63, w = t >> 6;
    int quad = lane >> 4, mrow = lane & 15;
    floatx4 acc[4] = {{0,0,0,0},{0,0,0,0},{0,0,0,0},{0,0,0,0}};
    int r  = t >> 2;
    int kq = (t & 3) * 8;
    int m = m0 + r;
    int wo = m%28, ho = (m/28)%28, b = m/784;
    const float* Wrow0 = wt + (size_t)(n0 + r)*K + kq;
    const float* Wrow1 = wt + (size_t)(n0 + r + 32)*K + kq;
    for (int k0 = 0; k0 < K; k0 += 32){
        int kk = k0 + kq;
        int pos = kk >> 8, ci = kk & 255;
        int kh = pos/3, kw = pos - kh*3;
        int ih = 2*ho + kh - 1, iw = 2*wo + kw - 1;
        float4 a1 = {0,0,0,0}, a2 = {0,0,0,0};
        if (ih>=0 && ih<56 && iw>=0 && iw<56){
            const float* px = x + (((size_t)b*56 + ih)*56 + iw)*256 + ci;
            a1 = *(const float4*)px;
            a2 = *(const float4*)(px + 4);
        }
        float4 w1 = *(const float4*)(Wrow0 + k0);
        float4 w2 = *(const float4*)(Wrow0 + k0 + 4);
        float4 u1 = *(const float4*)(Wrow1 + k0);
        float4 u2 = *(const float4*)(Wrow1 + k0 + 4);
        short8 av = { f2s(a1.x), f2s(a1.y), f2s(a1.z), f2s(a1.w),
                      f2s(a2.x), f2s(a2.y), f2s(a2.z), f2s(a2.w) };
        short8 wv0 = { f2s(w1.x), f2s(w1.y), f2s(w1.z), f2s(w1.w),
                       f2s(w2.x), f2s(w2.y), f2s(w2.z), f2s(w2.w) };
        short8 wv1 = { f2s(u1.x), f2s(u1.y), f2s(u1.z), f2s(u1.w),
                       f2s(u2.x), f2s(u2.y), f2s(u2.z), f2s(u2.w) };
        __syncthreads();
        *(short8*)&As[r*40 + kq] = av;
        *(short8*)&Ws[r*40 + kq] = wv0;
        *(short8*)&Ws[(r+32)*40 + kq] = wv1;
        __syncthreads();
        short8 af = *(short8*)&As[(w*16 + mrow)*40 + quad*8];
        #pragma unroll
        for (int nt=0; nt<4; nt++){
            short8 bfv = *(short8*)&Ws[(nt*16 + mrow)*40 + quad*8];
            acc[nt] = __builtin_amdgcn_mfma_f32_16x16x32_bf16(af, bfv, acc[nt], 0, 0, 0);
        }
    }
    #pragma unroll
    for (int nt=0; nt<4; nt++){
        int col = n0 + nt*16 + mrow;
        #pragma unroll
        for (int rr=0; rr<4; rr++){
            int row = m0 + w*16 + quad*4 + rr;
            C[(size_t)row*N + col] = acc[nt][rr];
        }
    }
}

// ---------------- Group attention scores: softmax((k . q_nb + rpb)*scale) --
__global__ void grp_attn_kernel(const bf16* __restrict__ kproj, const float* __restrict__ qbuf,
                                const float* __restrict__ rpb, const float* __restrict__ g_tau,
                                float* __restrict__ attn)
{
    int idx = blockIdx.x;   // b*3136 + n*784 + i*28 + j
    int j = idx%28; int i = (idx/28)%28; int n = (idx/784)%4; int b = idx/3136;
    int lane = threadIdx.x; // 64
    int sh = n>>1, sw = n&1;
    const bf16* kv = kproj + ((size_t)b*3136 + (2*i+sh)*56 + (2*j+sw))*256;
    __shared__ float sc[9];
    int i0 = min(max(i-1,0),25), j0 = min(max(j-1,0),25);
    for (int l=0; l<9; l++){
        int qi = i0 + l/3, qj = j0 + l%3;
        const float* qv = qbuf + ((size_t)b*784 + qi*28+qj)*256;
        float p = 0.f;
        for (int d=lane; d<256; d+=64) p += b2f(kv[d])*qv[d];
        for (int off=32; off>0; off>>=1) p += __shfl_down(p, off, 64);
        if (lane==0) sc[l] = p;
    }
    __syncthreads();
    if (lane==0){
        float scale = expf(g_tau[0]);
        float s[9]; float m = -1e30f;
        for (int l=0; l<9; l++){ s[l] = sanit((sc[l] + rpb[n*9+l])*scale); m = fmaxf(m, s[l]); }
        float sum = 0.f;
        for (int l=0; l<9; l++){ s[l] = expf(s[l]-m); sum += s[l]; }
        float inv = 1.f/fmaxf(sum, 1e-30f);
        float* ap = attn + (size_t)idx*9;
        for (int l=0; l<9; l++) ap[l] = s[l]*inv + 1e-6f;
    }
}

__global__ void zero_kernel(float* __restrict__ p, int n)
{
    int t = blockIdx.x*256 + threadIdx.x;
    if (t < n) p[t] = 0.f;
}

__global__ void grp_scatter_kernel(const float* __restrict__ attn, float* __restrict__ col)
{
    int t = blockIdx.x*256 + threadIdx.x;   // 4*4*784*9
    if (t >= 4*4*784*9) return;
    int l = t%9; int rest = t/9;
    int j = rest%28; int i = (rest/28)%28; int b = rest/3136;
    int i0 = min(max(i-1,0),25), j0 = min(max(j-1,0),25);
    int qp = (i0 + l/3)*28 + (j0 + l%3);
    atomicAdd(&col[b*784+qp], attn[t]);
}

__global__ void grp_av_kernel(const float* __restrict__ attn, const float* __restrict__ col,
                              const bf16* __restrict__ vproj, float* __restrict__ xout)
{
    int idx = blockIdx.x;   // b*784 + i*28 + j
    int j = idx%28; int i = (idx/28)%28; int b = idx/784;
    int d = threadIdx.x;
    int i0 = min(max(i-1,0),25), j0 = min(max(j-1,0),25);
    float acc = 0.f;
    for (int n=0; n<4; n++){
        int sh = n>>1, sw = n&1;
        const float* ap = attn + ((size_t)(b*4+n)*784 + i*28+j)*9;
        for (int l=0; l<9; l++){
            int qi = i0 + l/3, qj = j0 + l%3;
            float dv = col[b*784 + qi*28+qj] + 1e-8f;
            acc += (ap[l]/dv) * b2f(vproj[((size_t)b*3136 + (2*qi+sh)*56 + (2*qj+sw))*256 + d]);
        }
    }
    xout[(size_t)idx*256 + d] += acc;
}

// ---------------- RoPE in place on q,k sections of qkv (B,784,3,8,32) -----
__global__ void rope_kernel(float* __restrict__ qkv)
{
    int idx = blockIdx.x*256 + threadIdx.x;   // B*784*2*8*16 = 802816
    int u = idx%16; int h = (idx/16)%8; int s = (idx/128)%2;
    int t = (idx/256)%784; int b = idx/(256*784);
    float f = expf(-((float)(2*u)/32.f)*logf(10000.f));
    float ang = (float)t * f;
    float c = cosf(ang), sn = sinf(ang);
    float* p = qkv + ((size_t)(b*784+t))*768 + s*256 + h*32 + 2*u;
    float x0 = p[0], x1 = p[1];
    p[0] = x0*c - x1*sn;
    p[1] = x1*c + x0*sn;
}

// ------- Block attention (KB=7), row-tiled: one block per (b,i,h) ---------
// Stages the 7x28 K/V window + 28 Q rows in LDS; 8 threads per token for
// scores+softmax (width-8 shfl reductions); AV bank-aligned. 896 blocks.
__global__ __launch_bounds__(256) void blk_attn_row(const float* __restrict__ qkv,
                                                    float* __restrict__ obuf)
{
    int blk = blockIdx.x;             // (b*28 + i)*8 + h
    int h = blk & 7; int rest = blk >> 3;
    int i = rest % 28; int b = rest / 28;
    int tid = threadIdx.x;
    int i0 = min(max(i-3,0),21);

    __shared__ float Ks[7*28*32];     // 25088 B
    __shared__ float Vs[7*28*32];     // 25088 B
    __shared__ float Qs[28*32];       //  3584 B
    __shared__ float Ps[28*52];       //  5824 B

    // stage K,V: 196 positions x 8 float4
    for (int idx = tid; idx < 196*8; idx += 256){
        int pos = idx >> 3, q = idx & 7;
        int ki = i0 + pos/28, kj = pos - (pos/28)*28;
        const float* base = qkv + ((size_t)(b*784 + ki*28 + kj))*768 + h*32 + q*4;
        *(float4*)&Ks[pos*32 + q*4] = *(const float4*)(base + 256);
        *(float4*)&Vs[pos*32 + q*4] = *(const float4*)(base + 512);
    }
    // stage Q: 28 tokens x 8 float4
    for (int idx = tid; idx < 28*8; idx += 256){
        int tt = idx >> 3, q = idx & 7;
        *(float4*)&Qs[tt*32 + q*4] =
            *(const float4*)(qkv + ((size_t)(b*784 + i*28 + tt))*768 + h*32 + q*4);
    }
    __syncthreads();

    // scores: token tt = tid/8, sublane s = tid%8 (tokens 0..27 -> tids 0..223)
    int tt = tid >> 3, s = tid & 7;
    float sc[7];
    float mx = -1e30f;
    int j0 = min(max(tt-3,0),21);
    if (tt < 28){
        int c = 0;
        for (int l = s; l < 49; l += 8, c++){
            int ki = l/7, kj = j0 + l - (l/7)*7;
            const float4* kp = (const float4*)&Ks[(ki*28+kj)*32];
            const float4* qp = (const float4*)&Qs[tt*32];
            float p = 0.f;
            #pragma unroll
            for (int d=0; d<8; d++){
                float4 kv4 = kp[d], qv4 = qp[d];
                p += qv4.x*kv4.x + qv4.y*kv4.y + qv4.z*kv4.z + qv4.w*kv4.w;
            }
            sc[c] = sanit(p * 0.17677669529663687f);
            mx = fmaxf(mx, sc[c]);
        }
    }
    #pragma unroll
    for (int off=1; off<8; off<<=1) mx = fmaxf(mx, __shfl_xor(mx, off, 8));
    float sm = 0.f;
    if (tt < 28){
        int c = 0;
        for (int l = s; l < 49; l += 8, c++){ sc[c] = expf(sc[c]-mx); sm += sc[c]; }
    }
    #pragma unroll
    for (int off=1; off<8; off<<=1) sm += __shfl_xor(sm, off, 8);
    if (tt < 28){
        float inv = 1.f/fmaxf(sm, 1e-30f);
        int c = 0;
        for (int l = s; l < 49; l += 8, c++) Ps[tt*52 + l] = sc[c]*inv;
    }
    __syncthreads();

    // AV: 28 tokens x 32 dims
    for (int o = tid; o < 28*32; o += 256){
        int t2 = o >> 5, d = o & 31;
        int jj0 = min(max(t2-3,0),21);
        float acc = 0.f;
        #pragma unroll 7
        for (int l=0; l<49; l++){
            int ki = l/7, kj = jj0 + l - (l/7)*7;
            acc += Ps[t2*52 + l] * Vs[(ki*28+kj)*32 + d];
        }
        obuf[((size_t)(b*784 + i*28 + t2))*256 + h*32 + d] = acc;
    }
}

// ==========================================================================
extern "C" void kernel_launch(void* const* d_in, const int* in_sizes, int n_in,
                              void* d_out, int out_size, void* d_ws, size_t ws_size,
                              hipStream_t stream) {
    const float* x         = (const float*)d_in[0];
    const float* g_seed_w  = (const float*)d_in[1];
    const float* g_q_w     = (const float*)d_in[2];
    const float* g_k_w     = (const float*)d_in[3];
    const float* g_v_w     = (const float*)d_in[4];
    const float* g_mlp_w1  = (const float*)d_in[5];
    const float* g_mlp_b1  = (const float*)d_in[6];
    const float* g_mlp_w2  = (const float*)d_in[7];
    const float* g_mlp_b2  = (const float*)d_in[8];
    const float* g_ln_in_g = (const float*)d_in[9];
    const float* g_ln_in_b = (const float*)d_in[10];
    const float* g_ln_out_g= (const float*)d_in[11];
    const float* g_ln_out_b= (const float*)d_in[12];
    const float* g_tau     = (const float*)d_in[13];
    const float* g_rpb     = (const float*)d_in[14];
    const float* blk_ln1_g = (const float*)d_in[15];
    const float* blk_ln1_b = (const float*)d_in[16];
    const float* blk_qkv_w = (const float*)d_in[17];
    const float* blk_proj_w= (const float*)d_in[18];
    const float* blk_proj_b= (const float*)d_in[19];
    const float* blk_ln2_g = (const float*)d_in[20];
    const float* blk_ln2_b = (const float*)d_in[21];
    const float* blk_mlp_w1= (const float*)d_in[22];
    const float* blk_mlp_b1= (const float*)d_in[23];
    const float* blk_mlp_w2= (const float*)d_in[24];
    const float* blk_mlp_b2= (const float*)d_in[25];

    // workspace layout — 8,144,192 floats-equivalent = 32.6 MB
    float* f     = (float*)d_ws;
    bf16*  kproj = (bf16*)d_ws;          // 3211264 bf16 (= 1605632 floats)
    bf16*  vproj = kproj + 3211264;      // 3211264 bf16
    float* xout  = f + 3211264;          // 802816
    float* tmp   = xout  + 802816;       // 802816
    float* qbuf  = tmp   + 802816;       // 802816
    float* big   = qbuf  + 802816;       // 2408448 (3136x768)
    float* attng = big   + 2408448;      // 112896  (4*4*784*9)
    float* col   = attng + 112896;       // 3136
    float* xln   = qbuf;                 // aliases qbuf+big, dead at setup
    float* seedwt = big;                 // aliases big, dead before iter-0 MLP

    // ---- setup ----
    ln256_kernel<<<12544, 256, 0, stream>>>(x, g_ln_in_g, g_ln_in_b, xln, 0);
    gemm_mfma<bf16,32><<<dim3(4,392), 128, 0, stream>>>(xln, g_k_w, nullptr, nullptr, kproj, 12544,256,256, 0);
    gemm_mfma<bf16,32><<<dim3(4,392), 128, 0, stream>>>(x,   g_v_w, nullptr, nullptr, vproj, 12544,256,256, 0);
    transpose_seedw<<<2304, 256, 0, stream>>>(g_seed_w, seedwt);
    conv_mfma<<<dim3(4,98), 128, 0, stream>>>(x, seedwt, tmp);
    ln256_kernel<<<3136, 256, 0, stream>>>(tmp, g_ln_out_g, g_ln_out_b, xout, 0);

    // ---- NUM_ITERS group-attention iterations ----
    for (int it=0; it<3; it++){
        ln256_kernel<<<3136, 256, 0, stream>>>(xout, g_ln_out_g, g_ln_out_b, tmp, 0);
        gemm_mfma<float,32><<<dim3(4,98), 128, 0, stream>>>(tmp, g_q_w, nullptr, nullptr, qbuf, 3136,256,256, 0);
        grp_attn_kernel<<<12544, 64, 0, stream>>>(kproj, qbuf, g_rpb, g_tau, attng);
        zero_kernel<<<(3136+255)/256, 256, 0, stream>>>(col, 3136);
        grp_scatter_kernel<<<(112896+255)/256, 256, 0, stream>>>(attng, col);
        grp_av_kernel<<<3136, 256, 0, stream>>>(attng, col, vproj, xout);
        gemm_mfma<float,32><<<dim3(8,98), 128, 0, stream>>>(xout, g_mlp_w1, g_mlp_b1, nullptr, big, 3136,512,256, 1);
        gemm_mfma<float,32><<<dim3(4,98), 128, 0, stream>>>(big, g_mlp_w2, g_mlp_b2, nullptr, tmp, 3136,256,512, 0);
        ln256_kernel<<<3136, 256, 0, stream>>>(tmp, g_ln_out_g, g_ln_out_b, xout, 1);
    }

    // ---- DEPTH transformer blocks ----
    for (int l=0; l<2; l++){
        ln256_kernel<<<3136, 256, 0, stream>>>(xout, blk_ln1_g + l*256, blk_ln1_b + l*256, tmp, 0);
        gemm_mfma<float,32><<<dim3(12,98), 128, 0, stream>>>(tmp, blk_qkv_w + (size_t)l*768*256, nullptr, nullptr, big, 3136,768,256, 0);
        rope_kernel<<<3136, 256, 0, stream>>>(big);
        blk_attn_row<<<896, 256, 0, stream>>>(big, qbuf);
        gemm_mfma<float,32><<<dim3(4,98), 128, 0, stream>>>(qbuf, blk_proj_w + (size_t)l*256*256, blk_proj_b + l*256, xout, xout, 3136,256,256, 0);
        ln256_kernel<<<3136, 256, 0, stream>>>(xout, blk_ln2_g + l*256, blk_ln2_b + l*256, tmp, 0);
        gemm_mfma<float,32><<<dim3(12,98), 128, 0, stream>>>(tmp, blk_mlp_w1 + (size_t)l*768*256, blk_mlp_b1 + l*768, nullptr, big, 3136,768,256, 1);
        float* Cout = (l==1) ? (float*)d_out : xout;
        gemm_mfma<float,32><<<dim3(4,98), 128, 0, stream>>>(big, blk_mlp_w2 + (size_t)l*256*768, blk_mlp_b2 + l*256, xout, Cout, 3136,256,768, 0);
    }
}

// Round 8
// 632.914 us; speedup vs baseline: 7.8944x; 1.1398x over previous
//
#include <hip/hip_runtime.h>
#include <hip/hip_bf16.h>
#include <math.h>

typedef __hip_bfloat16 bf16;

#define LN_EPS 1e-5f

__device__ __forceinline__ float b2f(bf16 x){ return __bfloat162float(x); }
__device__ __forceinline__ float sanit(float s){ return fminf(fmaxf(s, -80.f), 80.f); }

__device__ __forceinline__ void stc(float* p, float v){ *p = v; }
__device__ __forceinline__ void stc(bf16* p, float v){ *p = __float2bfloat16(v); }
__device__ __forceinline__ void stadd(float* p, float v){ *p += v; }
__device__ __forceinline__ void stadd(bf16* p, float v){ *p = __float2bfloat16(b2f(*p)+v); }

__device__ __forceinline__ short f2s(float f){
    union { __hip_bfloat16 h; short s; } u; u.h = __float2bfloat16(f); return u.s;
}
__device__ __forceinline__ float s2f(short s){
    union { short s; __hip_bfloat16 h; } u; u.s = s; return b2f(u.h);
}

using short8  = __attribute__((ext_vector_type(8))) short;
using floatx4 = __attribute__((ext_vector_type(4))) float;

__device__ __forceinline__ short8 load8(const float* p){
    float4 a1 = *(const float4*)p; float4 a2 = *(const float4*)(p+4);
    return (short8){ f2s(a1.x),f2s(a1.y),f2s(a1.z),f2s(a1.w),
                     f2s(a2.x),f2s(a2.y),f2s(a2.z),f2s(a2.w) };
}
__device__ __forceinline__ short8 load8(const bf16* p){ return *(const short8*)p; }

// ---------------- weight pre-conversion fp32 -> bf16 (one pass) -----------
__global__ void convert_weights(const float* __restrict__ q, const float* __restrict__ k,
                                const float* __restrict__ v, const float* __restrict__ m1,
                                const float* __restrict__ m2, const float* __restrict__ qkv,
                                const float* __restrict__ proj, const float* __restrict__ bm1,
                                const float* __restrict__ bm2, bf16* __restrict__ dst)
{
    int i = blockIdx.x*256 + threadIdx.x;
    if (i >= 1769472) return;
    const float* src; int off;
    if      (i <   65536){ src=q;    off=i; }
    else if (i <  131072){ src=k;    off=i-65536; }
    else if (i <  196608){ src=v;    off=i-131072; }
    else if (i <  327680){ src=m1;   off=i-196608; }
    else if (i <  458752){ src=m2;   off=i-327680; }
    else if (i <  851968){ src=qkv;  off=i-458752; }
    else if (i <  983040){ src=proj; off=i-851968; }
    else if (i < 1376256){ src=bm1;  off=i-983040; }
    else                 { src=bm2;  off=i-1376256; }
    dst[i] = __float2bfloat16(src[off]);
}

// ---------------- LayerNorm over D=256: wave-shuffle reduction ------------
template<typename TO>
__global__ void ln256_kernel(const float* __restrict__ in, const float* __restrict__ g,
                             const float* __restrict__ bb, TO* __restrict__ out, int addTo)
{
    int token = blockIdx.x; int d = threadIdx.x;
    int w = d >> 6, lane = d & 63;
    __shared__ float part[8];
    float v = in[(size_t)token*256 + d];
    float s = v;
    #pragma unroll
    for (int off=32; off>0; off>>=1) s += __shfl_down(s, off);
    if (lane==0) part[w] = s;
    __syncthreads();
    float mean = (part[0]+part[1]+part[2]+part[3]) * (1.f/256.f);
    float dev = v - mean;
    float q = dev*dev;
    __syncthreads();
    #pragma unroll
    for (int off=32; off>0; off>>=1) q += __shfl_down(q, off);
    if (lane==0) part[w+4] = q;
    __syncthreads();
    float var = (part[4]+part[5]+part[6]+part[7]) * (1.f/256.f);
    float r = dev*rsqrtf(var+LN_EPS)*g[d] + bb[d];
    size_t o = (size_t)token*256+d;
    if (addTo) stadd(&out[o], r); else stc(&out[o], r);
}

// ---------------- MFMA GEMM: C = act(A[M,K] @ W[N,K]^T + bias) + resid ----
// TA in {float,bf16}; W always bf16 (preconverted). TM x 64 tile, BK=32 via
// LDS. Rows padded to 40 shorts -> worst 2-way bank conflict (free).
template<typename TA, typename TC, int TM>
__global__ __launch_bounds__(TM*4) void gemm_mfma(const TA* __restrict__ A,
                       const bf16* __restrict__ W,
                       const float* __restrict__ bias, const float* __restrict__ resid,
                       TC* __restrict__ C, int M, int N, int K, int do_gelu)
{
    __shared__ __align__(16) short As[TM*40];
    __shared__ __align__(16) short Ws[64*40];
    int t = threadIdx.x;
    int n0 = blockIdx.x*64, m0 = blockIdx.y*TM;
    int lane = t & 63, w = t >> 6;
    int quad = lane >> 4, mrow = lane & 15;
    floatx4 acc[4] = {{0,0,0,0},{0,0,0,0},{0,0,0,0},{0,0,0,0}};
    int r  = t >> 2;
    int kq = (t & 3) * 8;
    const TA*   Arow  = A + (size_t)(m0 + r)*K + kq;
    const bf16* Wrow0 = W + (size_t)(n0 + r)*K + kq;
    const bf16* Wrow1 = W + (size_t)(n0 + r + 32)*K + kq;
    for (int k0 = 0; k0 < K; k0 += 32){
        short8 av  = load8(Arow + k0);
        short8 wv0 = load8(Wrow0 + k0);
        short8 wv1;
        if (TM == 32) wv1 = load8(Wrow1 + k0);
        __syncthreads();
        *(short8*)&As[r*40 + kq] = av;
        *(short8*)&Ws[r*40 + kq] = wv0;
        if (TM == 32) *(short8*)&Ws[(r+32)*40 + kq] = wv1;
        __syncthreads();
        short8 af = *(short8*)&As[(w*16 + mrow)*40 + quad*8];
        #pragma unroll
        for (int nt=0; nt<4; nt++){
            short8 bfv = *(short8*)&Ws[(nt*16 + mrow)*40 + quad*8];
            acc[nt] = __builtin_amdgcn_mfma_f32_16x16x32_bf16(af, bfv, acc[nt], 0, 0, 0);
        }
    }
    #pragma unroll
    for (int nt=0; nt<4; nt++){
        int col = n0 + nt*16 + mrow;
        float bv = bias ? bias[col] : 0.f;
        #pragma unroll
        for (int rr=0; rr<4; rr++){
            int row = m0 + w*16 + quad*4 + rr;
            float v = acc[nt][rr] + bv;
            if (do_gelu) v = 0.5f*v*(1.0f+erff(v*0.70710678118654752f));
            size_t o = (size_t)row*N + col;
            if (resid) v += resid[o];
            stc(&C[o], v);
        }
    }
}

// -------- seed-weight transpose+convert: w[o][ci][kh][kw] -> wt[o][pos][ci]
__global__ void transpose_seedw(const float* __restrict__ w, bf16* __restrict__ wt)
{
    int idx = blockIdx.x*256 + threadIdx.x;   // 256*2304
    if (idx >= 256*2304) return;
    int o = idx/2304; int rem = idx - o*2304; int pos = rem>>8; int ci = rem&255;
    wt[idx] = __float2bfloat16(w[(size_t)o*2304 + ci*9 + pos]);
}

// -------- 3x3 stride-2 pad-1 conv as MFMA GEMM, k = pos*256+ci ordering ---
__global__ __launch_bounds__(128) void conv_mfma(const float* __restrict__ x,
                       const bf16* __restrict__ wt, float* __restrict__ C)
{
    const int K = 2304, N = 256;
    __shared__ __align__(16) short As[32*40];
    __shared__ __align__(16) short Ws[64*40];
    int t = threadIdx.x;
    int n0 = blockIdx.x*64, m0 = blockIdx.y*32;
    int lane = t & 63, w = t >> 6;
    int quad = lane >> 4, mrow = lane & 15;
    floatx4 acc[4] = {{0,0,0,0},{0,0,0,0},{0,0,0,0},{0,0,0,0}};
    int r  = t >> 2;
    int kq = (t & 3) * 8;
    int m = m0 + r;
    int wo = m%28, ho = (m/28)%28, b = m/784;
    const bf16* Wrow0 = wt + (size_t)(n0 + r)*K + kq;
    const bf16* Wrow1 = wt + (size_t)(n0 + r + 32)*K + kq;
    for (int k0 = 0; k0 < K; k0 += 32){
        int kk = k0 + kq;
        int pos = kk >> 8, ci = kk & 255;
        int kh = pos/3, kw = pos - kh*3;
        int ih = 2*ho + kh - 1, iw = 2*wo + kw - 1;
        short8 av = {0,0,0,0,0,0,0,0};
        if (ih>=0 && ih<56 && iw>=0 && iw<56)
            av = load8(x + (((size_t)b*56 + ih)*56 + iw)*256 + ci);
        short8 wv0 = load8(Wrow0 + k0);
        short8 wv1 = load8(Wrow1 + k0);
        __syncthreads();
        *(short8*)&As[r*40 + kq] = av;
        *(short8*)&Ws[r*40 + kq] = wv0;
        *(short8*)&Ws[(r+32)*40 + kq] = wv1;
        __syncthreads();
        short8 af = *(short8*)&As[(w*16 + mrow)*40 + quad*8];
        #pragma unroll
        for (int nt=0; nt<4; nt++){
            short8 bfv = *(short8*)&Ws[(nt*16 + mrow)*40 + quad*8];
            acc[nt] = __builtin_amdgcn_mfma_f32_16x16x32_bf16(af, bfv, acc[nt], 0, 0, 0);
        }
    }
    #pragma unroll
    for (int nt=0; nt<4; nt++){
        int col = n0 + nt*16 + mrow;
        #pragma unroll
        for (int rr=0; rr<4; rr++){
            int row = m0 + w*16 + quad*4 + rr;
            C[(size_t)row*N + col] = acc[nt][rr];
        }
    }
}

// -------- Group attention + fused column scatter --------------------------
__global__ void grp_attn_kernel(const bf16* __restrict__ kproj, const bf16* __restrict__ qbuf,
                                const float* __restrict__ rpb, const float* __restrict__ g_tau,
                                float* __restrict__ attn, float* __restrict__ col)
{
    int idx = blockIdx.x;   // b*3136 + n*784 + i*28 + j
    int j = idx%28; int i = (idx/28)%28; int n = (idx/784)%4; int b = idx/3136;
    int lane = threadIdx.x; // 64
    int sh = n>>1, sw = n&1;
    const bf16* kv = kproj + ((size_t)b*3136 + (2*i+sh)*56 + (2*j+sw))*256;
    __shared__ float sc[9];
    __shared__ float sc2[9];
    int i0 = min(max(i-1,0),25), j0 = min(max(j-1,0),25);
    for (int l=0; l<9; l++){
        int qi = i0 + l/3, qj = j0 + l%3;
        const bf16* qv = qbuf + ((size_t)b*784 + qi*28+qj)*256;
        float p = 0.f;
        for (int d=lane; d<256; d+=64) p += b2f(kv[d])*b2f(qv[d]);
        for (int off=32; off>0; off>>=1) p += __shfl_down(p, off, 64);
        if (lane==0) sc[l] = p;
    }
    __syncthreads();
    if (lane==0){
        float scale = expf(g_tau[0]);
        float s[9]; float m = -1e30f;
        for (int l=0; l<9; l++){ s[l] = sanit((sc[l] + rpb[n*9+l])*scale); m = fmaxf(m, s[l]); }
        float sum = 0.f;
        for (int l=0; l<9; l++){ s[l] = expf(s[l]-m); sum += s[l]; }
        float inv = 1.f/fmaxf(sum, 1e-30f);
        for (int l=0; l<9; l++) sc2[l] = s[l]*inv + 1e-6f;
    }
    __syncthreads();
    if (lane < 9){
        float a = sc2[lane];
        attn[(size_t)idx*9 + lane] = a;
        int qi = i0 + lane/3, qj = j0 + lane%3;
        atomicAdd(&col[b*784 + qi*28 + qj], a);
    }
}

__global__ void grp_av_kernel(const float* __restrict__ attn, const float* __restrict__ col,
                              const bf16* __restrict__ vproj, float* __restrict__ xout)
{
    int idx = blockIdx.x;   // b*784 + i*28 + j
    int j = idx%28; int i = (idx/28)%28; int b = idx/784;
    int d = threadIdx.x;
    int i0 = min(max(i-1,0),25), j0 = min(max(j-1,0),25);
    float acc = 0.f;
    for (int n=0; n<4; n++){
        int sh = n>>1, sw = n&1;
        const float* ap = attn + ((size_t)(b*4+n)*784 + i*28+j)*9;
        for (int l=0; l<9; l++){
            int qi = i0 + l/3, qj = j0 + l%3;
            float dv = col[b*784 + qi*28+qj] + 1e-8f;
            acc += (ap[l]/dv) * b2f(vproj[((size_t)b*3136 + (2*qi+sh)*56 + (2*qj+sw))*256 + d]);
        }
    }
    xout[(size_t)idx*256 + d] += acc;
}

// ------- Block attention (KB=7), row-tiled, RoPE fused in staging ---------
// One block per (b,i,h); K/V/Q windows staged in LDS from bf16 qkv.
__global__ __launch_bounds__(256) void blk_attn_row(const bf16* __restrict__ qkv,
                                                    bf16* __restrict__ obuf)
{
    int blk = blockIdx.x;             // (b*28 + i)*8 + h
    int h = blk & 7; int rest = blk >> 3;
    int i = rest % 28; int b = rest / 28;
    int tid = threadIdx.x;
    int i0 = min(max(i-3,0),21);

    __shared__ float Ks[7*28*32];
    __shared__ float Vs[7*28*32];
    __shared__ float Qs[28*32];
    __shared__ float Ps[28*52];

    const float LOG1E4_16 = 0.5756462732485115f;   // ln(10000)/16

    // stage K (rope) and V: 196 positions x 4 chunks of 8 dims
    for (int idx = tid; idx < 196*4; idx += 256){
        int pos = idx >> 2, u8 = idx & 3;
        int ki = i0 + pos/28, kj = pos - (pos/28)*28;
        int ttok = ki*28 + kj;
        const bf16* base = qkv + ((size_t)(b*784 + ttok))*768 + h*32 + u8*8;
        short8 k8 = *(const short8*)(base + 256);
        short8 v8 = *(const short8*)(base + 512);
        float f[8];
        #pragma unroll
        for (int d=0; d<8; d++) f[d] = s2f(k8[d]);
        #pragma unroll
        for (int m2=0; m2<4; m2++){
            int u = u8*4 + m2;
            float ang = (float)ttok * expf(-(float)u * LOG1E4_16);
            float c = cosf(ang), s = sinf(ang);
            float x0 = f[2*m2], x1 = f[2*m2+1];
            f[2*m2]   = x0*c - x1*s;
            f[2*m2+1] = x1*c + x0*s;
        }
        #pragma unroll
        for (int d=0; d<8; d++){
            Ks[pos*32 + u8*8 + d] = f[d];
            Vs[pos*32 + u8*8 + d] = s2f(v8[d]);
        }
    }
    // stage Q (rope): 28 tokens x 4 chunks
    for (int idx = tid; idx < 28*4; idx += 256){
        int tt = idx >> 2, u8 = idx & 3;
        int ttok = i*28 + tt;
        const bf16* base = qkv + ((size_t)(b*784 + ttok))*768 + h*32 + u8*8;
        short8 q8 = *(const short8*)base;
        float f[8];
        #pragma unroll
        for (int d=0; d<8; d++) f[d] = s2f(q8[d]);
        #pragma unroll
        for (int m2=0; m2<4; m2++){
            int u = u8*4 + m2;
            float ang = (float)ttok * expf(-(float)u * LOG1E4_16);
            float c = cosf(ang), s = sinf(ang);
            float x0 = f[2*m2], x1 = f[2*m2+1];
            f[2*m2]   = x0*c - x1*s;
            f[2*m2+1] = x1*c + x0*s;
        }
        #pragma unroll
        for (int d=0; d<8; d++) Qs[tt*32 + u8*8 + d] = f[d];
    }
    __syncthreads();

    // scores: token tt = tid/8, sublane s = tid%8
    int tt = tid >> 3, s = tid & 7;
    float sc[7];
    float mx = -1e30f;
    int j0 = min(max(tt-3,0),21);
    if (tt < 28){
        int c = 0;
        for (int l = s; l < 49; l += 8, c++){
            int ki = l/7, kj = j0 + l - (l/7)*7;
            const float4* kp = (const float4*)&Ks[(ki*28+kj)*32];
            const float4* qp = (const float4*)&Qs[tt*32];
            float p = 0.f;
            #pragma unroll
            for (int d=0; d<8; d++){
                float4 kv4 = kp[d], qv4 = qp[d];
                p += qv4.x*kv4.x + qv4.y*kv4.y + qv4.z*kv4.z + qv4.w*kv4.w;
            }
            sc[c] = sanit(p * 0.17677669529663687f);
            mx = fmaxf(mx, sc[c]);
        }
    }
    #pragma unroll
    for (int off=1; off<8; off<<=1) mx = fmaxf(mx, __shfl_xor(mx, off, 8));
    float sm = 0.f;
    if (tt < 28){
        int c = 0;
        for (int l = s; l < 49; l += 8, c++){ sc[c] = expf(sc[c]-mx); sm += sc[c]; }
    }
    #pragma unroll
    for (int off=1; off<8; off<<=1) sm += __shfl_xor(sm, off, 8);
    if (tt < 28){
        float inv = 1.f/fmaxf(sm, 1e-30f);
        int c = 0;
        for (int l = s; l < 49; l += 8, c++) Ps[tt*52 + l] = sc[c]*inv;
    }
    __syncthreads();

    // AV: 28 tokens x 32 dims
    for (int o = tid; o < 28*32; o += 256){
        int t2 = o >> 5, d = o & 31;
        int jj0 = min(max(t2-3,0),21);
        float acc = 0.f;
        #pragma unroll 7
        for (int l=0; l<49; l++){
            int ki = l/7, kj = jj0 + l - (l/7)*7;
            acc += Ps[t2*52 + l] * Vs[(ki*28+kj)*32 + d];
        }
        obuf[((size_t)(b*784 + i*28 + t2))*256 + h*32 + d] = __float2bfloat16(acc);
    }
}

// ==========================================================================
extern "C" void kernel_launch(void* const* d_in, const int* in_sizes, int n_in,
                              void* d_out, int out_size, void* d_ws, size_t ws_size,
                              hipStream_t stream) {
    const float* x         = (const float*)d_in[0];
    const float* g_seed_w  = (const float*)d_in[1];
    const float* g_q_w     = (const float*)d_in[2];
    const float* g_k_w     = (const float*)d_in[3];
    const float* g_v_w     = (const float*)d_in[4];
    const float* g_mlp_w1  = (const float*)d_in[5];
    const float* g_mlp_b1  = (const float*)d_in[6];
    const float* g_mlp_w2  = (const float*)d_in[7];
    const float* g_mlp_b2  = (const float*)d_in[8];
    const float* g_ln_in_g = (const float*)d_in[9];
    const float* g_ln_in_b = (const float*)d_in[10];
    const float* g_ln_out_g= (const float*)d_in[11];
    const float* g_ln_out_b= (const float*)d_in[12];
    const float* g_tau     = (const float*)d_in[13];
    const float* g_rpb     = (const float*)d_in[14];
    const float* blk_ln1_g = (const float*)d_in[15];
    const float* blk_ln1_b = (const float*)d_in[16];
    const float* blk_qkv_w = (const float*)d_in[17];
    const float* blk_proj_w= (const float*)d_in[18];
    const float* blk_proj_b= (const float*)d_in[19];
    const float* blk_ln2_g = (const float*)d_in[20];
    const float* blk_ln2_b = (const float*)d_in[21];
    const float* blk_mlp_w1= (const float*)d_in[22];
    const float* blk_mlp_b1= (const float*)d_in[23];
    const float* blk_mlp_w2= (const float*)d_in[24];
    const float* blk_mlp_b2= (const float*)d_in[25];

    // workspace layout — 8,119,616 floats-equivalent = 32.5 MB
    float* f      = (float*)d_ws;
    bf16*  wbuf   = (bf16*)d_ws;                 // 2359296 bf16 = 1179648 f
    bf16*  kproj  = (bf16*)(f + 1179648);        // 3211264 bf16
    bf16*  vproj  = (bf16*)(f + 2785280);        // 3211264 bf16
    float* xout   = f + 4390912;                 // 802816
    float* tmp    = f + 5193728;                 // 802816
    bf16*  tmph   = (bf16*)(f + 5996544);        // 802816 bf16
    bf16*  qbufh  = (bf16*)(f + 6397952);        // 802816 bf16
    bf16*  bigh   = (bf16*)(f + 6799360);        // 2408448 bf16
    float* attng  = f + 8003584;                 // 112896
    float* col    = f + 8116480;                 // 3136
    // xln: bf16 LN(x), aliases tmph+qbufh+bigh (2007040 f >= 1605632 f) — setup only
    bf16*  xln    = (bf16*)(f + 5996544);

    // weight sub-buffers (bf16 offsets in wbuf)
    bf16* w_q    = wbuf;
    bf16* w_k    = wbuf + 65536;
    bf16* w_v    = wbuf + 131072;
    bf16* w_m1   = wbuf + 196608;
    bf16* w_m2   = wbuf + 327680;
    bf16* w_qkv  = wbuf + 458752;   // 2 layers x 196608
    bf16* w_proj = wbuf + 851968;   // 2 x 65536
    bf16* w_bm1  = wbuf + 983040;   // 2 x 196608
    bf16* w_bm2  = wbuf + 1376256;  // 2 x 196608
    bf16* w_seed = wbuf + 1769472;  // 589824

    // ---- setup ----
    convert_weights<<<6912, 256, 0, stream>>>(g_q_w, g_k_w, g_v_w, g_mlp_w1, g_mlp_w2,
                                              blk_qkv_w, blk_proj_w, blk_mlp_w1, blk_mlp_w2, wbuf);
    transpose_seedw<<<2304, 256, 0, stream>>>(g_seed_w, w_seed);
    ln256_kernel<bf16><<<12544, 256, 0, stream>>>(x, g_ln_in_g, g_ln_in_b, xln, 0);
    gemm_mfma<bf16,bf16,32><<<dim3(4,392), 128, 0, stream>>>(xln, w_k, nullptr, nullptr, kproj, 12544,256,256, 0);
    gemm_mfma<float,bf16,32><<<dim3(4,392), 128, 0, stream>>>(x, w_v, nullptr, nullptr, vproj, 12544,256,256, 0);
    conv_mfma<<<dim3(4,98), 128, 0, stream>>>(x, w_seed, tmp);
    ln256_kernel<float><<<3136, 256, 0, stream>>>(tmp, g_ln_out_g, g_ln_out_b, xout, 0);

    // ---- NUM_ITERS group-attention iterations ----
    for (int it=0; it<3; it++){
        ln256_kernel<bf16><<<3136, 256, 0, stream>>>(xout, g_ln_out_g, g_ln_out_b, tmph, 0);
        gemm_mfma<bf16,bf16,32><<<dim3(4,98), 128, 0, stream>>>(tmph, w_q, nullptr, nullptr, qbufh, 3136,256,256, 0);
        hipMemsetAsync(col, 0, 3136*sizeof(float), stream);
        grp_attn_kernel<<<12544, 64, 0, stream>>>(kproj, qbufh, g_rpb, g_tau, attng, col);
        grp_av_kernel<<<3136, 256, 0, stream>>>(attng, col, vproj, xout);
        gemm_mfma<float,bf16,32><<<dim3(8,98), 128, 0, stream>>>(xout, w_m1, g_mlp_b1, nullptr, bigh, 3136,512,256, 1);
        gemm_mfma<bf16,float,32><<<dim3(4,98), 128, 0, stream>>>(bigh, w_m2, g_mlp_b2, nullptr, tmp, 3136,256,512, 0);
        ln256_kernel<float><<<3136, 256, 0, stream>>>(tmp, g_ln_out_g, g_ln_out_b, xout, 1);
    }

    // ---- DEPTH transformer blocks ----
    for (int l=0; l<2; l++){
        ln256_kernel<bf16><<<3136, 256, 0, stream>>>(xout, blk_ln1_g + l*256, blk_ln1_b + l*256, tmph, 0);
        gemm_mfma<bf16,bf16,32><<<dim3(12,98), 128, 0, stream>>>(tmph, w_qkv + (size_t)l*196608, nullptr, nullptr, bigh, 3136,768,256, 0);
        blk_attn_row<<<896, 256, 0, stream>>>(bigh, qbufh);
        gemm_mfma<bf16,float,32><<<dim3(4,98), 128, 0, stream>>>(qbufh, w_proj + (size_t)l*65536, blk_proj_b + l*256, xout, xout, 3136,256,256, 0);
        ln256_kernel<bf16><<<3136, 256, 0, stream>>>(xout, blk_ln2_g + l*256, blk_ln2_b + l*256, tmph, 0);
        gemm_mfma<bf16,bf16,32><<<dim3(12,98), 128, 0, stream>>>(tmph, w_bm1 + (size_t)l*196608, blk_mlp_b1 + l*768, nullptr, bigh, 3136,768,256, 1);
        float* Cout = (l==1) ? (float*)d_out : xout;
        gemm_mfma<bf16,float,32><<<dim3(4,98), 128, 0, stream>>>(bigh, w_bm2 + (size_t)l*196608, blk_mlp_b2 + l*256, xout, Cout, 3136,256,768, 0);
    }
}

// Round 9
// 592.894 us; speedup vs baseline: 8.4273x; 1.0675x over previous
//
#include <hip/hip_runtime.h>
#include <hip/hip_bf16.h>
#include <math.h>

typedef __hip_bfloat16 bf16;

#define LN_EPS 1e-5f

__device__ __forceinline__ float b2f(bf16 x){ return __bfloat162float(x); }
__device__ __forceinline__ float sanit(float s){ return fminf(fmaxf(s, -80.f), 80.f); }

__device__ __forceinline__ void stc(float* p, float v){ *p = v; }
__device__ __forceinline__ void stc(bf16* p, float v){ *p = __float2bfloat16(v); }
__device__ __forceinline__ void stadd(float* p, float v){ *p += v; }
__device__ __forceinline__ void stadd(bf16* p, float v){ *p = __float2bfloat16(b2f(*p)+v); }

__device__ __forceinline__ short f2s(float f){
    union { __hip_bfloat16 h; short s; } u; u.h = __float2bfloat16(f); return u.s;
}
__device__ __forceinline__ float s2f(short s){
    union { short s; __hip_bfloat16 h; } u; u.s = s; return b2f(u.h);
}

using short8  = __attribute__((ext_vector_type(8))) short;
using floatx4 = __attribute__((ext_vector_type(4))) float;

__device__ __forceinline__ short8 load8(const float* p){
    float4 a1 = *(const float4*)p; float4 a2 = *(const float4*)(p+4);
    return (short8){ f2s(a1.x),f2s(a1.y),f2s(a1.z),f2s(a1.w),
                     f2s(a2.x),f2s(a2.y),f2s(a2.z),f2s(a2.w) };
}
__device__ __forceinline__ short8 load8(const bf16* p){ return *(const short8*)p; }

// ---------------- weight pre-conversion fp32 -> bf16 (one pass) -----------
__global__ void convert_weights(const float* __restrict__ q, const float* __restrict__ k,
                                const float* __restrict__ v, const float* __restrict__ m1,
                                const float* __restrict__ m2, const float* __restrict__ qkv,
                                const float* __restrict__ proj, const float* __restrict__ bm1,
                                const float* __restrict__ bm2, bf16* __restrict__ dst)
{
    int i = blockIdx.x*256 + threadIdx.x;
    if (i >= 1769472) return;
    const float* src; int off;
    if      (i <   65536){ src=q;    off=i; }
    else if (i <  131072){ src=k;    off=i-65536; }
    else if (i <  196608){ src=v;    off=i-131072; }
    else if (i <  327680){ src=m1;   off=i-196608; }
    else if (i <  458752){ src=m2;   off=i-327680; }
    else if (i <  851968){ src=qkv;  off=i-458752; }
    else if (i <  983040){ src=proj; off=i-851968; }
    else if (i < 1376256){ src=bm1;  off=i-983040; }
    else                 { src=bm2;  off=i-1376256; }
    dst[i] = __float2bfloat16(src[off]);
}

// ---------------- LayerNorm over D=256: wave-shuffle reduction ------------
template<typename TO>
__global__ void ln256_kernel(const float* __restrict__ in, const float* __restrict__ g,
                             const float* __restrict__ bb, TO* __restrict__ out, int addTo)
{
    int token = blockIdx.x; int d = threadIdx.x;
    int w = d >> 6, lane = d & 63;
    __shared__ float part[8];
    float v = in[(size_t)token*256 + d];
    float s = v;
    #pragma unroll
    for (int off=32; off>0; off>>=1) s += __shfl_down(s, off);
    if (lane==0) part[w] = s;
    __syncthreads();
    float mean = (part[0]+part[1]+part[2]+part[3]) * (1.f/256.f);
    float dev = v - mean;
    float q = dev*dev;
    __syncthreads();
    #pragma unroll
    for (int off=32; off>0; off>>=1) q += __shfl_down(q, off);
    if (lane==0) part[w+4] = q;
    __syncthreads();
    float var = (part[4]+part[5]+part[6]+part[7]) * (1.f/256.f);
    float r = dev*rsqrtf(var+LN_EPS)*g[d] + bb[d];
    size_t o = (size_t)token*256+d;
    if (addTo) stadd(&out[o], r); else stc(&out[o], r);
}

// ---------------- MFMA GEMM, ping-pong double-buffered LDS ----------------
// 32x64 tile, 128 threads (2 waves). BK=32. Each iter: issue next chunk's
// global loads, MFMA from LDS[cur], write regs to LDS[cur^1], ONE barrier.
// Rows padded to 40 shorts -> worst 2-way bank conflict (free).
// Requires: M%32==0, N%64==0, K%32==0.
template<typename TA, typename TC>
__global__ __launch_bounds__(128) void gemm_mfma(const TA* __restrict__ A,
                       const bf16* __restrict__ W,
                       const float* __restrict__ bias, const float* __restrict__ resid,
                       TC* __restrict__ C, int M, int N, int K, int do_gelu)
{
    __shared__ __align__(16) short As[2][32*40];
    __shared__ __align__(16) short Ws[2][64*40];
    int t = threadIdx.x;
    int n0 = blockIdx.x*64, m0 = blockIdx.y*32;
    int lane = t & 63, w = t >> 6;
    int quad = lane >> 4, mrow = lane & 15;
    floatx4 acc[4] = {{0,0,0,0},{0,0,0,0},{0,0,0,0},{0,0,0,0}};
    int r  = t >> 2;
    int kq = (t & 3) * 8;
    const TA*   Arow  = A + (size_t)(m0 + r)*K + kq;
    const bf16* Wrow0 = W + (size_t)(n0 + r)*K + kq;
    const bf16* Wrow1 = W + (size_t)(n0 + r + 32)*K + kq;

    short8 av  = load8(Arow);
    short8 wv0 = load8(Wrow0);
    short8 wv1 = load8(Wrow1);
    *(short8*)&As[0][r*40 + kq] = av;
    *(short8*)&Ws[0][r*40 + kq] = wv0;
    *(short8*)&Ws[0][(r+32)*40 + kq] = wv1;
    __syncthreads();

    int nb = K >> 5;
    int cur = 0;
    for (int i = 0; i < nb; i++){
        if (i+1 < nb){
            int k0 = (i+1) << 5;
            av  = load8(Arow + k0);
            wv0 = load8(Wrow0 + k0);
            wv1 = load8(Wrow1 + k0);
        }
        short8 af = *(short8*)&As[cur][(w*16 + mrow)*40 + quad*8];
        #pragma unroll
        for (int nt=0; nt<4; nt++){
            short8 bfv = *(short8*)&Ws[cur][(nt*16 + mrow)*40 + quad*8];
            acc[nt] = __builtin_amdgcn_mfma_f32_16x16x32_bf16(af, bfv, acc[nt], 0, 0, 0);
        }
        if (i+1 < nb){
            int nxt = cur ^ 1;
            *(short8*)&As[nxt][r*40 + kq] = av;
            *(short8*)&Ws[nxt][r*40 + kq] = wv0;
            *(short8*)&Ws[nxt][(r+32)*40 + kq] = wv1;
            __syncthreads();
            cur = nxt;
        }
    }
    #pragma unroll
    for (int nt=0; nt<4; nt++){
        int col = n0 + nt*16 + mrow;
        float bv = bias ? bias[col] : 0.f;
        #pragma unroll
        for (int rr=0; rr<4; rr++){
            int row = m0 + w*16 + quad*4 + rr;
            float v = acc[nt][rr] + bv;
            if (do_gelu) v = 0.5f*v*(1.0f+erff(v*0.70710678118654752f));
            size_t o = (size_t)row*N + col;
            if (resid) v += resid[o];
            stc(&C[o], v);
        }
    }
}

// -------- seed-weight transpose+convert: w[o][ci][kh][kw] -> wt[o][pos][ci]
__global__ void transpose_seedw(const float* __restrict__ w, bf16* __restrict__ wt)
{
    int idx = blockIdx.x*256 + threadIdx.x;   // 256*2304
    if (idx >= 256*2304) return;
    int o = idx/2304; int rem = idx - o*2304; int pos = rem>>8; int ci = rem&255;
    wt[idx] = __float2bfloat16(w[(size_t)o*2304 + ci*9 + pos]);
}

// -------- 3x3 s2 p1 conv as MFMA GEMM, K-split x3 (one kh per z-block) ----
// k = pos*256+ci; chunk z covers pos 3z..3z+2 (contiguous K range of 768).
// Partials accumulated into pre-zeroed C via fp32 atomicAdd.
__global__ __launch_bounds__(128) void conv_mfma(const float* __restrict__ x,
                       const bf16* __restrict__ wt, float* __restrict__ C)
{
    const int K = 2304, N = 256, KC = 768;
    __shared__ __align__(16) short As[2][32*40];
    __shared__ __align__(16) short Ws[2][64*40];
    int t = threadIdx.x;
    int n0 = blockIdx.x*64, m0 = blockIdx.y*32, z = blockIdx.z;
    int lane = t & 63, w = t >> 6;
    int quad = lane >> 4, mrow = lane & 15;
    floatx4 acc[4] = {{0,0,0,0},{0,0,0,0},{0,0,0,0},{0,0,0,0}};
    int r  = t >> 2;
    int kq = (t & 3) * 8;
    int m = m0 + r;
    int wo = m%28, ho = (m/28)%28, b = m/784;
    const bf16* Wrow0 = wt + (size_t)(n0 + r)*K + z*KC + kq;
    const bf16* Wrow1 = wt + (size_t)(n0 + r + 32)*K + z*KC + kq;

    int kh = z;                       // chunk z == kernel row kh
    int ih = 2*ho + kh - 1;
    bool rowok = (ih>=0 && ih<56);

    auto loadA = [&](int k0)->short8{
        int kk = k0 + kq;             // 0..767 within chunk
        int pos3 = kk >> 8;           // 0..2  (kw)
        int ci = kk & 255;
        int iw = 2*wo + pos3 - 1;
        short8 a = {0,0,0,0,0,0,0,0};
        if (rowok && iw>=0 && iw<56)
            a = load8(x + (((size_t)b*56 + ih)*56 + iw)*256 + ci);
        return a;
    };

    short8 av  = loadA(0);
    short8 wv0 = load8(Wrow0);
    short8 wv1 = load8(Wrow1);
    *(short8*)&As[0][r*40 + kq] = av;
    *(short8*)&Ws[0][r*40 + kq] = wv0;
    *(short8*)&Ws[0][(r+32)*40 + kq] = wv1;
    __syncthreads();

    const int nb = KC >> 5;           // 24
    int cur = 0;
    for (int i = 0; i < nb; i++){
        if (i+1 < nb){
            int k0 = (i+1) << 5;
            av  = loadA(k0);
            wv0 = load8(Wrow0 + k0);
            wv1 = load8(Wrow1 + k0);
        }
        short8 af = *(short8*)&As[cur][(w*16 + mrow)*40 + quad*8];
        #pragma unroll
        for (int nt=0; nt<4; nt++){
            short8 bfv = *(short8*)&Ws[cur][(nt*16 + mrow)*40 + quad*8];
            acc[nt] = __builtin_amdgcn_mfma_f32_16x16x32_bf16(af, bfv, acc[nt], 0, 0, 0);
        }
        if (i+1 < nb){
            int nxt = cur ^ 1;
            *(short8*)&As[nxt][r*40 + kq] = av;
            *(short8*)&Ws[nxt][r*40 + kq] = wv0;
            *(short8*)&Ws[nxt][(r+32)*40 + kq] = wv1;
            __syncthreads();
            cur = nxt;
        }
    }
    #pragma unroll
    for (int nt=0; nt<4; nt++){
        int col = n0 + nt*16 + mrow;
        #pragma unroll
        for (int rr=0; rr<4; rr++){
            int row = m0 + w*16 + quad*4 + rr;
            atomicAdd(&C[(size_t)row*N + col], acc[nt][rr]);
        }
    }
}

// -------- Group attention + fused column scatter --------------------------
__global__ void grp_attn_kernel(const bf16* __restrict__ kproj, const bf16* __restrict__ qbuf,
                                const float* __restrict__ rpb, const float* __restrict__ g_tau,
                                float* __restrict__ attn, float* __restrict__ col)
{
    int idx = blockIdx.x;   // b*3136 + n*784 + i*28 + j
    int j = idx%28; int i = (idx/28)%28; int n = (idx/784)%4; int b = idx/3136;
    int lane = threadIdx.x; // 64
    int sh = n>>1, sw = n&1;
    const bf16* kv = kproj + ((size_t)b*3136 + (2*i+sh)*56 + (2*j+sw))*256;
    __shared__ float sc[9];
    __shared__ float sc2[9];
    int i0 = min(max(i-1,0),25), j0 = min(max(j-1,0),25);
    for (int l=0; l<9; l++){
        int qi = i0 + l/3, qj = j0 + l%3;
        const bf16* qv = qbuf + ((size_t)b*784 + qi*28+qj)*256;
        float p = 0.f;
        for (int d=lane; d<256; d+=64) p += b2f(kv[d])*b2f(qv[d]);
        for (int off=32; off>0; off>>=1) p += __shfl_down(p, off, 64);
        if (lane==0) sc[l] = p;
    }
    __syncthreads();
    if (lane==0){
        float scale = expf(g_tau[0]);
        float s[9]; float m = -1e30f;
        for (int l=0; l<9; l++){ s[l] = sanit((sc[l] + rpb[n*9+l])*scale); m = fmaxf(m, s[l]); }
        float sum = 0.f;
        for (int l=0; l<9; l++){ s[l] = expf(s[l]-m); sum += s[l]; }
        float inv = 1.f/fmaxf(sum, 1e-30f);
        for (int l=0; l<9; l++) sc2[l] = s[l]*inv + 1e-6f;
    }
    __syncthreads();
    if (lane < 9){
        float a = sc2[lane];
        attn[(size_t)idx*9 + lane] = a;
        int qi = i0 + lane/3, qj = j0 + lane%3;
        atomicAdd(&col[b*784 + qi*28 + qj], a);
    }
}

__global__ void grp_av_kernel(const float* __restrict__ attn, const float* __restrict__ col,
                              const bf16* __restrict__ vproj, float* __restrict__ xout)
{
    int idx = blockIdx.x;   // b*784 + i*28 + j
    int j = idx%28; int i = (idx/28)%28; int b = idx/784;
    int d = threadIdx.x;
    int i0 = min(max(i-1,0),25), j0 = min(max(j-1,0),25);
    float acc = 0.f;
    for (int n=0; n<4; n++){
        int sh = n>>1, sw = n&1;
        const float* ap = attn + ((size_t)(b*4+n)*784 + i*28+j)*9;
        for (int l=0; l<9; l++){
            int qi = i0 + l/3, qj = j0 + l%3;
            float dv = col[b*784 + qi*28+qj] + 1e-8f;
            acc += (ap[l]/dv) * b2f(vproj[((size_t)b*3136 + (2*qi+sh)*56 + (2*qj+sw))*256 + d]);
        }
    }
    xout[(size_t)idx*256 + d] += acc;
}

// ------- Block attention (KB=7), row-tiled, RoPE fused in staging ---------
__global__ __launch_bounds__(256) void blk_attn_row(const bf16* __restrict__ qkv,
                                                    bf16* __restrict__ obuf)
{
    int blk = blockIdx.x;             // (b*28 + i)*8 + h
    int h = blk & 7; int rest = blk >> 3;
    int i = rest % 28; int b = rest / 28;
    int tid = threadIdx.x;
    int i0 = min(max(i-3,0),21);

    __shared__ float Ks[7*28*32];
    __shared__ float Vs[7*28*32];
    __shared__ float Qs[28*32];
    __shared__ float Ps[28*52];

    const float LOG1E4_16 = 0.5756462732485115f;   // ln(10000)/16

    for (int idx = tid; idx < 196*4; idx += 256){
        int pos = idx >> 2, u8 = idx & 3;
        int ki = i0 + pos/28, kj = pos - (pos/28)*28;
        int ttok = ki*28 + kj;
        const bf16* base = qkv + ((size_t)(b*784 + ttok))*768 + h*32 + u8*8;
        short8 k8 = *(const short8*)(base + 256);
        short8 v8 = *(const short8*)(base + 512);
        float f[8];
        #pragma unroll
        for (int d=0; d<8; d++) f[d] = s2f(k8[d]);
        #pragma unroll
        for (int m2=0; m2<4; m2++){
            int u = u8*4 + m2;
            float ang = (float)ttok * expf(-(float)u * LOG1E4_16);
            float c = cosf(ang), s = sinf(ang);
            float x0 = f[2*m2], x1 = f[2*m2+1];
            f[2*m2]   = x0*c - x1*s;
            f[2*m2+1] = x1*c + x0*s;
        }
        #pragma unroll
        for (int d=0; d<8; d++){
            Ks[pos*32 + u8*8 + d] = f[d];
            Vs[pos*32 + u8*8 + d] = s2f(v8[d]);
        }
    }
    for (int idx = tid; idx < 28*4; idx += 256){
        int tt = idx >> 2, u8 = idx & 3;
        int ttok = i*28 + tt;
        const bf16* base = qkv + ((size_t)(b*784 + ttok))*768 + h*32 + u8*8;
        short8 q8 = *(const short8*)base;
        float f[8];
        #pragma unroll
        for (int d=0; d<8; d++) f[d] = s2f(q8[d]);
        #pragma unroll
        for (int m2=0; m2<4; m2++){
            int u = u8*4 + m2;
            float ang = (float)ttok * expf(-(float)u * LOG1E4_16);
            float c = cosf(ang), s = sinf(ang);
            float x0 = f[2*m2], x1 = f[2*m2+1];
            f[2*m2]   = x0*c - x1*s;
            f[2*m2+1] = x1*c + x0*s;
        }
        #pragma unroll
        for (int d=0; d<8; d++) Qs[tt*32 + u8*8 + d] = f[d];
    }
    __syncthreads();

    int tt = tid >> 3, s = tid & 7;
    float sc[7];
    float mx = -1e30f;
    int j0 = min(max(tt-3,0),21);
    if (tt < 28){
        int c = 0;
        for (int l = s; l < 49; l += 8, c++){
            int ki = l/7, kj = j0 + l - (l/7)*7;
            const float4* kp = (const float4*)&Ks[(ki*28+kj)*32];
            const float4* qp = (const float4*)&Qs[tt*32];
            float p = 0.f;
            #pragma unroll
            for (int d=0; d<8; d++){
                float4 kv4 = kp[d], qv4 = qp[d];
                p += qv4.x*kv4.x + qv4.y*kv4.y + qv4.z*kv4.z + qv4.w*kv4.w;
            }
            sc[c] = sanit(p * 0.17677669529663687f);
            mx = fmaxf(mx, sc[c]);
        }
    }
    #pragma unroll
    for (int off=1; off<8; off<<=1) mx = fmaxf(mx, __shfl_xor(mx, off, 8));
    float sm = 0.f;
    if (tt < 28){
        int c = 0;
        for (int l = s; l < 49; l += 8, c++){ sc[c] = expf(sc[c]-mx); sm += sc[c]; }
    }
    #pragma unroll
    for (int off=1; off<8; off<<=1) sm += __shfl_xor(sm, off, 8);
    if (tt < 28){
        float inv = 1.f/fmaxf(sm, 1e-30f);
        int c = 0;
        for (int l = s; l < 49; l += 8, c++) Ps[tt*52 + l] = sc[c]*inv;
    }
    __syncthreads();

    for (int o = tid; o < 28*32; o += 256){
        int t2 = o >> 5, d = o & 31;
        int jj0 = min(max(t2-3,0),21);
        float acc = 0.f;
        #pragma unroll 7
        for (int l=0; l<49; l++){
            int ki = l/7, kj = jj0 + l - (l/7)*7;
            acc += Ps[t2*52 + l] * Vs[(ki*28+kj)*32 + d];
        }
        obuf[((size_t)(b*784 + i*28 + t2))*256 + h*32 + d] = __float2bfloat16(acc);
    }
}

// ==========================================================================
extern "C" void kernel_launch(void* const* d_in, const int* in_sizes, int n_in,
                              void* d_out, int out_size, void* d_ws, size_t ws_size,
                              hipStream_t stream) {
    const float* x         = (const float*)d_in[0];
    const float* g_seed_w  = (const float*)d_in[1];
    const float* g_q_w     = (const float*)d_in[2];
    const float* g_k_w     = (const float*)d_in[3];
    const float* g_v_w     = (const float*)d_in[4];
    const float* g_mlp_w1  = (const float*)d_in[5];
    const float* g_mlp_b1  = (const float*)d_in[6];
    const float* g_mlp_w2  = (const float*)d_in[7];
    const float* g_mlp_b2  = (const float*)d_in[8];
    const float* g_ln_in_g = (const float*)d_in[9];
    const float* g_ln_in_b = (const float*)d_in[10];
    const float* g_ln_out_g= (const float*)d_in[11];
    const float* g_ln_out_b= (const float*)d_in[12];
    const float* g_tau     = (const float*)d_in[13];
    const float* g_rpb     = (const float*)d_in[14];
    const float* blk_ln1_g = (const float*)d_in[15];
    const float* blk_ln1_b = (const float*)d_in[16];
    const float* blk_qkv_w = (const float*)d_in[17];
    const float* blk_proj_w= (const float*)d_in[18];
    const float* blk_proj_b= (const float*)d_in[19];
    const float* blk_ln2_g = (const float*)d_in[20];
    const float* blk_ln2_b = (const float*)d_in[21];
    const float* blk_mlp_w1= (const float*)d_in[22];
    const float* blk_mlp_b1= (const float*)d_in[23];
    const float* blk_mlp_w2= (const float*)d_in[24];
    const float* blk_mlp_b2= (const float*)d_in[25];

    // workspace layout — 8,119,616 floats-equivalent = 32.5 MB
    float* f      = (float*)d_ws;
    bf16*  wbuf   = (bf16*)d_ws;                 // 2359296 bf16 = 1179648 f
    bf16*  kproj  = (bf16*)(f + 1179648);        // 3211264 bf16
    bf16*  vproj  = (bf16*)(f + 2785280);        // 3211264 bf16
    float* xout   = f + 4390912;                 // 802816
    float* tmp    = f + 5193728;                 // 802816
    bf16*  tmph   = (bf16*)(f + 5996544);        // 802816 bf16
    bf16*  qbufh  = (bf16*)(f + 6397952);        // 802816 bf16
    bf16*  bigh   = (bf16*)(f + 6799360);        // 2408448 bf16
    float* attng  = f + 8003584;                 // 112896
    float* col    = f + 8116480;                 // 3136
    bf16*  xln    = (bf16*)(f + 5996544);        // aliases tmph..bigh, setup only

    bf16* w_q    = wbuf;
    bf16* w_k    = wbuf + 65536;
    bf16* w_v    = wbuf + 131072;
    bf16* w_m1   = wbuf + 196608;
    bf16* w_m2   = wbuf + 327680;
    bf16* w_qkv  = wbuf + 458752;   // 2 layers x 196608
    bf16* w_proj = wbuf + 851968;   // 2 x 65536
    bf16* w_bm1  = wbuf + 983040;   // 2 x 196608
    bf16* w_bm2  = wbuf + 1376256;  // 2 x 196608
    bf16* w_seed = wbuf + 1769472;  // 589824

    // ---- setup ----
    convert_weights<<<6912, 256, 0, stream>>>(g_q_w, g_k_w, g_v_w, g_mlp_w1, g_mlp_w2,
                                              blk_qkv_w, blk_proj_w, blk_mlp_w1, blk_mlp_w2, wbuf);
    transpose_seedw<<<2304, 256, 0, stream>>>(g_seed_w, w_seed);
    ln256_kernel<bf16><<<12544, 256, 0, stream>>>(x, g_ln_in_g, g_ln_in_b, xln, 0);
    gemm_mfma<bf16,bf16><<<dim3(4,392), 128, 0, stream>>>(xln, w_k, nullptr, nullptr, kproj, 12544,256,256, 0);
    gemm_mfma<float,bf16><<<dim3(4,392), 128, 0, stream>>>(x, w_v, nullptr, nullptr, vproj, 12544,256,256, 0);
    hipMemsetAsync(tmp, 0, 3136*256*sizeof(float), stream);
    conv_mfma<<<dim3(4,98,3), 128, 0, stream>>>(x, w_seed, tmp);
    ln256_kernel<float><<<3136, 256, 0, stream>>>(tmp, g_ln_out_g, g_ln_out_b, xout, 0);

    // ---- NUM_ITERS group-attention iterations ----
    for (int it=0; it<3; it++){
        ln256_kernel<bf16><<<3136, 256, 0, stream>>>(xout, g_ln_out_g, g_ln_out_b, tmph, 0);
        gemm_mfma<bf16,bf16><<<dim3(4,98), 128, 0, stream>>>(tmph, w_q, nullptr, nullptr, qbufh, 3136,256,256, 0);
        hipMemsetAsync(col, 0, 3136*sizeof(float), stream);
        grp_attn_kernel<<<12544, 64, 0, stream>>>(kproj, qbufh, g_rpb, g_tau, attng, col);
        grp_av_kernel<<<3136, 256, 0, stream>>>(attng, col, vproj, xout);
        gemm_mfma<float,bf16><<<dim3(8,98), 128, 0, stream>>>(xout, w_m1, g_mlp_b1, nullptr, bigh, 3136,512,256, 1);
        gemm_mfma<bf16,float><<<dim3(4,98), 128, 0, stream>>>(bigh, w_m2, g_mlp_b2, nullptr, tmp, 3136,256,512, 0);
        ln256_kernel<float><<<3136, 256, 0, stream>>>(tmp, g_ln_out_g, g_ln_out_b, xout, 1);
    }

    // ---- DEPTH transformer blocks ----
    for (int l=0; l<2; l++){
        ln256_kernel<bf16><<<3136, 256, 0, stream>>>(xout, blk_ln1_g + l*256, blk_ln1_b + l*256, tmph, 0);
        gemm_mfma<bf16,bf16><<<dim3(12,98), 128, 0, stream>>>(tmph, w_qkv + (size_t)l*196608, nullptr, nullptr, bigh, 3136,768,256, 0);
        blk_attn_row<<<896, 256, 0, stream>>>(bigh, qbufh);
        gemm_mfma<bf16,float><<<dim3(4,98), 128, 0, stream>>>(qbufh, w_proj + (size_t)l*65536, blk_proj_b + l*256, xout, xout, 3136,256,256, 0);
        ln256_kernel<bf16><<<3136, 256, 0, stream>>>(xout, blk_ln2_g + l*256, blk_ln2_b + l*256, tmph, 0);
        gemm_mfma<bf16,bf16><<<dim3(12,98), 128, 0, stream>>>(tmph, w_bm1 + (size_t)l*196608, blk_mlp_b1 + l*768, nullptr, bigh, 3136,768,256, 1);
        float* Cout = (l==1) ? (float*)d_out : xout;
        gemm_mfma<bf16,float><<<dim3(4,98), 128, 0, stream>>>(bigh, w_bm2 + (size_t)l*196608, blk_mlp_b2 + l*256, xout, Cout, 3136,256,768, 0);
    }
}

// Round 10
// 573.501 us; speedup vs baseline: 8.7122x; 1.0338x over previous
//
#include <hip/hip_runtime.h>
#include <hip/hip_bf16.h>
#include <math.h>

typedef __hip_bfloat16 bf16;

#define LN_EPS 1e-5f

__device__ __forceinline__ float b2f(bf16 x){ return __bfloat162float(x); }
__device__ __forceinline__ float sanit(float s){ return fminf(fmaxf(s, -80.f), 80.f); }

__device__ __forceinline__ void stc(float* p, float v){ *p = v; }
__device__ __forceinline__ void stc(bf16* p, float v){ *p = __float2bfloat16(v); }
__device__ __forceinline__ void stadd(float* p, float v){ *p += v; }
__device__ __forceinline__ void stadd(bf16* p, float v){ *p = __float2bfloat16(b2f(*p)+v); }

__device__ __forceinline__ short f2s(float f){
    union { __hip_bfloat16 h; short s; } u; u.h = __float2bfloat16(f); return u.s;
}
__device__ __forceinline__ float s2f(short s){
    union { short s; __hip_bfloat16 h; } u; u.s = s; return b2f(u.h);
}

using short8  = __attribute__((ext_vector_type(8))) short;
using floatx4 = __attribute__((ext_vector_type(4))) float;

__device__ __forceinline__ short8 load8(const float* p){
    float4 a1 = *(const float4*)p; float4 a2 = *(const float4*)(p+4);
    return (short8){ f2s(a1.x),f2s(a1.y),f2s(a1.z),f2s(a1.w),
                     f2s(a2.x),f2s(a2.y),f2s(a2.z),f2s(a2.w) };
}
__device__ __forceinline__ short8 load8(const bf16* p){ return *(const short8*)p; }

// ---------------- weight pre-conversion fp32 -> bf16 (one pass) -----------
__global__ void convert_weights(const float* __restrict__ q, const float* __restrict__ k,
                                const float* __restrict__ v, const float* __restrict__ m1,
                                const float* __restrict__ m2, const float* __restrict__ qkv,
                                const float* __restrict__ proj, const float* __restrict__ bm1,
                                const float* __restrict__ bm2, bf16* __restrict__ dst)
{
    int i = blockIdx.x*256 + threadIdx.x;
    if (i >= 1769472) return;
    const float* src; int off;
    if      (i <   65536){ src=q;    off=i; }
    else if (i <  131072){ src=k;    off=i-65536; }
    else if (i <  196608){ src=v;    off=i-131072; }
    else if (i <  327680){ src=m1;   off=i-196608; }
    else if (i <  458752){ src=m2;   off=i-327680; }
    else if (i <  851968){ src=qkv;  off=i-458752; }
    else if (i <  983040){ src=proj; off=i-851968; }
    else if (i < 1376256){ src=bm1;  off=i-983040; }
    else                 { src=bm2;  off=i-1376256; }
    dst[i] = __float2bfloat16(src[off]);
}

// ---------------- LayerNorm over D=256: wave-shuffle reduction ------------
template<typename TO>
__global__ void ln256_kernel(const float* __restrict__ in, const float* __restrict__ g,
                             const float* __restrict__ bb, TO* __restrict__ out, int addTo)
{
    int token = blockIdx.x; int d = threadIdx.x;
    int w = d >> 6, lane = d & 63;
    __shared__ float part[8];
    float v = in[(size_t)token*256 + d];
    float s = v;
    #pragma unroll
    for (int off=32; off>0; off>>=1) s += __shfl_down(s, off);
    if (lane==0) part[w] = s;
    __syncthreads();
    float mean = (part[0]+part[1]+part[2]+part[3]) * (1.f/256.f);
    float dev = v - mean;
    float q = dev*dev;
    __syncthreads();
    #pragma unroll
    for (int off=32; off>0; off>>=1) q += __shfl_down(q, off);
    if (lane==0) part[w+4] = q;
    __syncthreads();
    float var = (part[4]+part[5]+part[6]+part[7]) * (1.f/256.f);
    float r = dev*rsqrtf(var+LN_EPS)*g[d] + bb[d];
    size_t o = (size_t)token*256+d;
    if (addTo) stadd(&out[o], r); else stc(&out[o], r);
}

// ------- setup LN: xln = bf16(LN(x)); xh = bf16(x) ------------------------
__global__ void ln_cast_kernel(const float* __restrict__ in, const float* __restrict__ g,
                               const float* __restrict__ bb, bf16* __restrict__ xln,
                               bf16* __restrict__ xh)
{
    int token = blockIdx.x; int d = threadIdx.x;
    int w = d >> 6, lane = d & 63;
    __shared__ float part[8];
    float v = in[(size_t)token*256 + d];
    float s = v;
    #pragma unroll
    for (int off=32; off>0; off>>=1) s += __shfl_down(s, off);
    if (lane==0) part[w] = s;
    __syncthreads();
    float mean = (part[0]+part[1]+part[2]+part[3]) * (1.f/256.f);
    float dev = v - mean;
    float q = dev*dev;
    __syncthreads();
    #pragma unroll
    for (int off=32; off>0; off>>=1) q += __shfl_down(q, off);
    if (lane==0) part[w+4] = q;
    __syncthreads();
    float var = (part[4]+part[5]+part[6]+part[7]) * (1.f/256.f);
    float r = dev*rsqrtf(var+LN_EPS)*g[d] + bb[d];
    size_t o = (size_t)token*256+d;
    xln[o] = __float2bfloat16(r);
    xh[o]  = __float2bfloat16(v);
}

// ------- fused: xout = (resid?) + LN1(in);  tmph = bf16(LN2(xout)) --------
__global__ void ln_add_ln(const float* __restrict__ in, const float* __restrict__ resid,
                          const float* __restrict__ g1, const float* __restrict__ b1,
                          const float* __restrict__ g2, const float* __restrict__ b2,
                          float* __restrict__ xout, bf16* __restrict__ tmph)
{
    int token = blockIdx.x; int d = threadIdx.x;
    int w = d >> 6, lane = d & 63;
    __shared__ float part[8];
    size_t o = (size_t)token*256 + d;
    float v = in[o];
    float s = v;
    #pragma unroll
    for (int off=32; off>0; off>>=1) s += __shfl_down(s, off);
    if (lane==0) part[w] = s;
    __syncthreads();
    float mean = (part[0]+part[1]+part[2]+part[3]) * (1.f/256.f);
    float dev = v - mean;
    float q = dev*dev;
    __syncthreads();
    #pragma unroll
    for (int off=32; off>0; off>>=1) q += __shfl_down(q, off);
    if (lane==0) part[w+4] = q;
    __syncthreads();
    float var = (part[4]+part[5]+part[6]+part[7]) * (1.f/256.f);
    float r = dev*rsqrtf(var+LN_EPS)*g1[d] + b1[d];
    float sx = (resid ? resid[o] : 0.f) + r;
    xout[o] = sx;
    __syncthreads();
    float s2 = sx;
    #pragma unroll
    for (int off=32; off>0; off>>=1) s2 += __shfl_down(s2, off);
    if (lane==0) part[w] = s2;
    __syncthreads();
    float mean2 = (part[0]+part[1]+part[2]+part[3]) * (1.f/256.f);
    float dev2 = sx - mean2;
    float q2 = dev2*dev2;
    __syncthreads();
    #pragma unroll
    for (int off=32; off>0; off>>=1) q2 += __shfl_down(q2, off);
    if (lane==0) part[w+4] = q2;
    __syncthreads();
    float var2 = (part[4]+part[5]+part[6]+part[7]) * (1.f/256.f);
    tmph[o] = __float2bfloat16(dev2*rsqrtf(var2+LN_EPS)*g2[d] + b2[d]);
}

// ---------------- MFMA GEMM, ping-pong double-buffered LDS ----------------
template<typename TA, typename TC>
__global__ __launch_bounds__(128) void gemm_mfma(const TA* __restrict__ A,
                       const bf16* __restrict__ W,
                       const float* __restrict__ bias, const float* __restrict__ resid,
                       TC* __restrict__ C, int M, int N, int K, int do_gelu)
{
    __shared__ __align__(16) short As[2][32*40];
    __shared__ __align__(16) short Ws[2][64*40];
    int t = threadIdx.x;
    int n0 = blockIdx.x*64, m0 = blockIdx.y*32;
    int lane = t & 63, w = t >> 6;
    int quad = lane >> 4, mrow = lane & 15;
    floatx4 acc[4] = {{0,0,0,0},{0,0,0,0},{0,0,0,0},{0,0,0,0}};
    int r  = t >> 2;
    int kq = (t & 3) * 8;
    const TA*   Arow  = A + (size_t)(m0 + r)*K + kq;
    const bf16* Wrow0 = W + (size_t)(n0 + r)*K + kq;
    const bf16* Wrow1 = W + (size_t)(n0 + r + 32)*K + kq;

    short8 av  = load8(Arow);
    short8 wv0 = load8(Wrow0);
    short8 wv1 = load8(Wrow1);
    *(short8*)&As[0][r*40 + kq] = av;
    *(short8*)&Ws[0][r*40 + kq] = wv0;
    *(short8*)&Ws[0][(r+32)*40 + kq] = wv1;
    __syncthreads();

    int nb = K >> 5;
    int cur = 0;
    for (int i = 0; i < nb; i++){
        if (i+1 < nb){
            int k0 = (i+1) << 5;
            av  = load8(Arow + k0);
            wv0 = load8(Wrow0 + k0);
            wv1 = load8(Wrow1 + k0);
        }
        short8 af = *(short8*)&As[cur][(w*16 + mrow)*40 + quad*8];
        #pragma unroll
        for (int nt=0; nt<4; nt++){
            short8 bfv = *(short8*)&Ws[cur][(nt*16 + mrow)*40 + quad*8];
            acc[nt] = __builtin_amdgcn_mfma_f32_16x16x32_bf16(af, bfv, acc[nt], 0, 0, 0);
        }
        if (i+1 < nb){
            int nxt = cur ^ 1;
            *(short8*)&As[nxt][r*40 + kq] = av;
            *(short8*)&Ws[nxt][r*40 + kq] = wv0;
            *(short8*)&Ws[nxt][(r+32)*40 + kq] = wv1;
            __syncthreads();
            cur = nxt;
        }
    }
    #pragma unroll
    for (int nt=0; nt<4; nt++){
        int col = n0 + nt*16 + mrow;
        float bv = bias ? bias[col] : 0.f;
        #pragma unroll
        for (int rr=0; rr<4; rr++){
            int row = m0 + w*16 + quad*4 + rr;
            float v = acc[nt][rr] + bv;
            if (do_gelu) v = 0.5f*v*(1.0f+erff(v*0.70710678118654752f));
            size_t o = (size_t)row*N + col;
            if (resid) v += resid[o];
            stc(&C[o], v);
        }
    }
}

// ------- merged K/V projection: z=0: kproj=xln@Wk^T; z=1: vproj=xh@Wv^T ---
__global__ __launch_bounds__(128) void gemm_kv(const bf16* __restrict__ xln,
                       const bf16* __restrict__ xh, const bf16* __restrict__ wk,
                       const bf16* __restrict__ wv, bf16* __restrict__ kp,
                       bf16* __restrict__ vp)
{
    const int N = 256, K = 256;
    const bf16* A = blockIdx.z ? xh : xln;
    const bf16* W = blockIdx.z ? wv : wk;
    bf16*       C = blockIdx.z ? vp : kp;
    __shared__ __align__(16) short As[2][32*40];
    __shared__ __align__(16) short Ws[2][64*40];
    int t = threadIdx.x;
    int n0 = blockIdx.x*64, m0 = blockIdx.y*32;
    int lane = t & 63, w = t >> 6;
    int quad = lane >> 4, mrow = lane & 15;
    floatx4 acc[4] = {{0,0,0,0},{0,0,0,0},{0,0,0,0},{0,0,0,0}};
    int r  = t >> 2;
    int kq = (t & 3) * 8;
    const bf16* Arow  = A + (size_t)(m0 + r)*K + kq;
    const bf16* Wrow0 = W + (size_t)(n0 + r)*K + kq;
    const bf16* Wrow1 = W + (size_t)(n0 + r + 32)*K + kq;
    short8 av  = load8(Arow);
    short8 wv0 = load8(Wrow0);
    short8 wv1 = load8(Wrow1);
    *(short8*)&As[0][r*40 + kq] = av;
    *(short8*)&Ws[0][r*40 + kq] = wv0;
    *(short8*)&Ws[0][(r+32)*40 + kq] = wv1;
    __syncthreads();
    const int nb = K >> 5;
    int cur = 0;
    for (int i = 0; i < nb; i++){
        if (i+1 < nb){
            int k0 = (i+1) << 5;
            av  = load8(Arow + k0);
            wv0 = load8(Wrow0 + k0);
            wv1 = load8(Wrow1 + k0);
        }
        short8 af = *(short8*)&As[cur][(w*16 + mrow)*40 + quad*8];
        #pragma unroll
        for (int nt=0; nt<4; nt++){
            short8 bfv = *(short8*)&Ws[cur][(nt*16 + mrow)*40 + quad*8];
            acc[nt] = __builtin_amdgcn_mfma_f32_16x16x32_bf16(af, bfv, acc[nt], 0, 0, 0);
        }
        if (i+1 < nb){
            int nxt = cur ^ 1;
            *(short8*)&As[nxt][r*40 + kq] = av;
            *(short8*)&Ws[nxt][r*40 + kq] = wv0;
            *(short8*)&Ws[nxt][(r+32)*40 + kq] = wv1;
            __syncthreads();
            cur = nxt;
        }
    }
    #pragma unroll
    for (int nt=0; nt<4; nt++){
        int col = n0 + nt*16 + mrow;
        #pragma unroll
        for (int rr=0; rr<4; rr++){
            int row = m0 + w*16 + quad*4 + rr;
            C[(size_t)row*N + col] = __float2bfloat16(acc[nt][rr]);
        }
    }
}

// -------- seed-weight transpose+convert ----------------------------------
__global__ void transpose_seedw(const float* __restrict__ w, bf16* __restrict__ wt)
{
    int idx = blockIdx.x*256 + threadIdx.x;   // 256*2304
    if (idx >= 256*2304) return;
    int o = idx/2304; int rem = idx - o*2304; int pos = rem>>8; int ci = rem&255;
    wt[idx] = __float2bfloat16(w[(size_t)o*2304 + ci*9 + pos]);
}

// -------- 3x3 s2 p1 conv as MFMA GEMM, K-split x3, bf16 input xh ----------
__global__ __launch_bounds__(128) void conv_mfma(const bf16* __restrict__ xh,
                       const bf16* __restrict__ wt, float* __restrict__ C)
{
    const int K = 2304, N = 256, KC = 768;
    __shared__ __align__(16) short As[2][32*40];
    __shared__ __align__(16) short Ws[2][64*40];
    int t = threadIdx.x;
    int n0 = blockIdx.x*64, m0 = blockIdx.y*32, z = blockIdx.z;
    int lane = t & 63, w = t >> 6;
    int quad = lane >> 4, mrow = lane & 15;
    floatx4 acc[4] = {{0,0,0,0},{0,0,0,0},{0,0,0,0},{0,0,0,0}};
    int r  = t >> 2;
    int kq = (t & 3) * 8;
    int m = m0 + r;
    int wo = m%28, ho = (m/28)%28, b = m/784;
    const bf16* Wrow0 = wt + (size_t)(n0 + r)*K + z*KC + kq;
    const bf16* Wrow1 = wt + (size_t)(n0 + r + 32)*K + z*KC + kq;

    int kh = z;
    int ih = 2*ho + kh - 1;
    bool rowok = (ih>=0 && ih<56);

    auto loadA = [&](int k0)->short8{
        int kk = k0 + kq;
        int pos3 = kk >> 8;
        int ci = kk & 255;
        int iw = 2*wo + pos3 - 1;
        short8 a = {0,0,0,0,0,0,0,0};
        if (rowok && iw>=0 && iw<56)
            a = load8(xh + (((size_t)b*56 + ih)*56 + iw)*256 + ci);
        return a;
    };

    short8 av  = loadA(0);
    short8 wv0 = load8(Wrow0);
    short8 wv1 = load8(Wrow1);
    *(short8*)&As[0][r*40 + kq] = av;
    *(short8*)&Ws[0][r*40 + kq] = wv0;
    *(short8*)&Ws[0][(r+32)*40 + kq] = wv1;
    __syncthreads();

    const int nb = KC >> 5;
    int cur = 0;
    for (int i = 0; i < nb; i++){
        if (i+1 < nb){
            int k0 = (i+1) << 5;
            av  = loadA(k0);
            wv0 = load8(Wrow0 + k0);
            wv1 = load8(Wrow1 + k0);
        }
        short8 af = *(short8*)&As[cur][(w*16 + mrow)*40 + quad*8];
        #pragma unroll
        for (int nt=0; nt<4; nt++){
            short8 bfv = *(short8*)&Ws[cur][(nt*16 + mrow)*40 + quad*8];
            acc[nt] = __builtin_amdgcn_mfma_f32_16x16x32_bf16(af, bfv, acc[nt], 0, 0, 0);
        }
        if (i+1 < nb){
            int nxt = cur ^ 1;
            *(short8*)&As[nxt][r*40 + kq] = av;
            *(short8*)&Ws[nxt][r*40 + kq] = wv0;
            *(short8*)&Ws[nxt][(r+32)*40 + kq] = wv1;
            __syncthreads();
            cur = nxt;
        }
    }
    #pragma unroll
    for (int nt=0; nt<4; nt++){
        int col = n0 + nt*16 + mrow;
        #pragma unroll
        for (int rr=0; rr<4; rr++){
            int row = m0 + w*16 + quad*4 + rr;
            atomicAdd(&C[(size_t)row*N + col], acc[nt][rr]);
        }
    }
}

// -------- Group attention + fused column scatter --------------------------
__global__ void grp_attn_kernel(const bf16* __restrict__ kproj, const bf16* __restrict__ qbuf,
                                const float* __restrict__ rpb, const float* __restrict__ g_tau,
                                float* __restrict__ attn, float* __restrict__ col)
{
    int idx = blockIdx.x;   // b*3136 + n*784 + i*28 + j
    int j = idx%28; int i = (idx/28)%28; int n = (idx/784)%4; int b = idx/3136;
    int lane = threadIdx.x; // 64
    int sh = n>>1, sw = n&1;
    const bf16* kv = kproj + ((size_t)b*3136 + (2*i+sh)*56 + (2*j+sw))*256;
    __shared__ float sc[9];
    __shared__ float sc2[9];
    int i0 = min(max(i-1,0),25), j0 = min(max(j-1,0),25);
    for (int l=0; l<9; l++){
        int qi = i0 + l/3, qj = j0 + l%3;
        const bf16* qv = qbuf + ((size_t)b*784 + qi*28+qj)*256;
        float p = 0.f;
        for (int d=lane; d<256; d+=64) p += b2f(kv[d])*b2f(qv[d]);
        for (int off=32; off>0; off>>=1) p += __shfl_down(p, off, 64);
        if (lane==0) sc[l] = p;
    }
    __syncthreads();
    if (lane==0){
        float scale = expf(g_tau[0]);
        float s[9]; float m = -1e30f;
        for (int l=0; l<9; l++){ s[l] = sanit((sc[l] + rpb[n*9+l])*scale); m = fmaxf(m, s[l]); }
        float sum = 0.f;
        for (int l=0; l<9; l++){ s[l] = expf(s[l]-m); sum += s[l]; }
        float inv = 1.f/fmaxf(sum, 1e-30f);
        for (int l=0; l<9; l++) sc2[l] = s[l]*inv + 1e-6f;
    }
    __syncthreads();
    if (lane < 9){
        float a = sc2[lane];
        attn[(size_t)idx*9 + lane] = a;
        int qi = i0 + lane/3, qj = j0 + lane%3;
        atomicAdd(&col[b*784 + qi*28 + qj], a);
    }
}

__global__ void grp_av_kernel(const float* __restrict__ attn, const float* __restrict__ col,
                              const bf16* __restrict__ vproj, float* __restrict__ xout)
{
    int idx = blockIdx.x;   // b*784 + i*28 + j
    int j = idx%28; int i = (idx/28)%28; int b = idx/784;
    int d = threadIdx.x;
    int i0 = min(max(i-1,0),25), j0 = min(max(j-1,0),25);
    float acc = 0.f;
    for (int n=0; n<4; n++){
        int sh = n>>1, sw = n&1;
        const float* ap = attn + ((size_t)(b*4+n)*784 + i*28+j)*9;
        for (int l=0; l<9; l++){
            int qi = i0 + l/3, qj = j0 + l%3;
            float dv = col[b*784 + qi*28+qj] + 1e-8f;
            acc += (ap[l]/dv) * b2f(vproj[((size_t)b*3136 + (2*qi+sh)*56 + (2*qj+sw))*256 + d]);
        }
    }
    xout[(size_t)idx*256 + d] += acc;
}

// ------- Block attention (KB=7), row-tiled, RoPE fused in staging ---------
__global__ __launch_bounds__(256) void blk_attn_row(const bf16* __restrict__ qkv,
                                                    bf16* __restrict__ obuf)
{
    int blk = blockIdx.x;             // (b*28 + i)*8 + h
    int h = blk & 7; int rest = blk >> 3;
    int i = rest % 28; int b = rest / 28;
    int tid = threadIdx.x;
    int i0 = min(max(i-3,0),21);

    __shared__ float Ks[7*28*32];
    __shared__ float Vs[7*28*32];
    __shared__ float Qs[28*32];
    __shared__ float Ps[28*52];

    const float LOG1E4_16 = 0.5756462732485115f;   // ln(10000)/16

    for (int idx = tid; idx < 196*4; idx += 256){
        int pos = idx >> 2, u8 = idx & 3;
        int ki = i0 + pos/28, kj = pos - (pos/28)*28;
        int ttok = ki*28 + kj;
        const bf16* base = qkv + ((size_t)(b*784 + ttok))*768 + h*32 + u8*8;
        short8 k8 = *(const short8*)(base + 256);
        short8 v8 = *(const short8*)(base + 512);
        float f[8];
        #pragma unroll
        for (int d=0; d<8; d++) f[d] = s2f(k8[d]);
        #pragma unroll
        for (int m2=0; m2<4; m2++){
            int u = u8*4 + m2;
            float ang = (float)ttok * expf(-(float)u * LOG1E4_16);
            float c = cosf(ang), s = sinf(ang);
            float x0 = f[2*m2], x1 = f[2*m2+1];
            f[2*m2]   = x0*c - x1*s;
            f[2*m2+1] = x1*c + x0*s;
        }
        #pragma unroll
        for (int d=0; d<8; d++){
            Ks[pos*32 + u8*8 + d] = f[d];
            Vs[pos*32 + u8*8 + d] = s2f(v8[d]);
        }
    }
    for (int idx = tid; idx < 28*4; idx += 256){
        int tt = idx >> 2, u8 = idx & 3;
        int ttok = i*28 + tt;
        const bf16* base = qkv + ((size_t)(b*784 + ttok))*768 + h*32 + u8*8;
        short8 q8 = *(const short8*)base;
        float f[8];
        #pragma unroll
        for (int d=0; d<8; d++) f[d] = s2f(q8[d]);
        #pragma unroll
        for (int m2=0; m2<4; m2++){
            int u = u8*4 + m2;
            float ang = (float)ttok * expf(-(float)u * LOG1E4_16);
            float c = cosf(ang), s = sinf(ang);
            float x0 = f[2*m2], x1 = f[2*m2+1];
            f[2*m2]   = x0*c - x1*s;
            f[2*m2+1] = x1*c + x0*s;
        }
        #pragma unroll
        for (int d=0; d<8; d++) Qs[tt*32 + u8*8 + d] = f[d];
    }
    __syncthreads();

    int tt = tid >> 3, s = tid & 7;
    float sc[7];
    float mx = -1e30f;
    int j0 = min(max(tt-3,0),21);
    if (tt < 28){
        int c = 0;
        for (int l = s; l < 49; l += 8, c++){
            int ki = l/7, kj = j0 + l - (l/7)*7;
            const float4* kp = (const float4*)&Ks[(ki*28+kj)*32];
            const float4* qp = (const float4*)&Qs[tt*32];
            float p = 0.f;
            #pragma unroll
            for (int d=0; d<8; d++){
                float4 kv4 = kp[d], qv4 = qp[d];
                p += qv4.x*kv4.x + qv4.y*kv4.y + qv4.z*kv4.z + qv4.w*kv4.w;
            }
            sc[c] = sanit(p * 0.17677669529663687f);
            mx = fmaxf(mx, sc[c]);
        }
    }
    #pragma unroll
    for (int off=1; off<8; off<<=1) mx = fmaxf(mx, __shfl_xor(mx, off, 8));
    float sm = 0.f;
    if (tt < 28){
        int c = 0;
        for (int l = s; l < 49; l += 8, c++){ sc[c] = expf(sc[c]-mx); sm += sc[c]; }
    }
    #pragma unroll
    for (int off=1; off<8; off<<=1) sm += __shfl_xor(sm, off, 8);
    if (tt < 28){
        float inv = 1.f/fmaxf(sm, 1e-30f);
        int c = 0;
        for (int l = s; l < 49; l += 8, c++) Ps[tt*52 + l] = sc[c]*inv;
    }
    __syncthreads();

    for (int o = tid; o < 28*32; o += 256){
        int t2 = o >> 5, d = o & 31;
        int jj0 = min(max(t2-3,0),21);
        float acc = 0.f;
        #pragma unroll 7
        for (int l=0; l<49; l++){
            int ki = l/7, kj = jj0 + l - (l/7)*7;
            acc += Ps[t2*52 + l] * Vs[(ki*28+kj)*32 + d];
        }
        obuf[((size_t)(b*784 + i*28 + t2))*256 + h*32 + d] = __float2bfloat16(acc);
    }
}

// ==========================================================================
extern "C" void kernel_launch(void* const* d_in, const int* in_sizes, int n_in,
                              void* d_out, int out_size, void* d_ws, size_t ws_size,
                              hipStream_t stream) {
    const float* x         = (const float*)d_in[0];
    const float* g_seed_w  = (const float*)d_in[1];
    const float* g_q_w     = (const float*)d_in[2];
    const float* g_k_w     = (const float*)d_in[3];
    const float* g_v_w     = (const float*)d_in[4];
    const float* g_mlp_w1  = (const float*)d_in[5];
    const float* g_mlp_b1  = (const float*)d_in[6];
    const float* g_mlp_w2  = (const float*)d_in[7];
    const float* g_mlp_b2  = (const float*)d_in[8];
    const float* g_ln_in_g = (const float*)d_in[9];
    const float* g_ln_in_b = (const float*)d_in[10];
    const float* g_ln_out_g= (const float*)d_in[11];
    const float* g_ln_out_b= (const float*)d_in[12];
    const float* g_tau     = (const float*)d_in[13];
    const float* g_rpb     = (const float*)d_in[14];
    const float* blk_ln1_g = (const float*)d_in[15];
    const float* blk_ln1_b = (const float*)d_in[16];
    const float* blk_qkv_w = (const float*)d_in[17];
    const float* blk_proj_w= (const float*)d_in[18];
    const float* blk_proj_b= (const float*)d_in[19];
    const float* blk_ln2_g = (const float*)d_in[20];
    const float* blk_ln2_b = (const float*)d_in[21];
    const float* blk_mlp_w1= (const float*)d_in[22];
    const float* blk_mlp_b1= (const float*)d_in[23];
    const float* blk_mlp_w2= (const float*)d_in[24];
    const float* blk_mlp_b2= (const float*)d_in[25];

    // workspace layout — 11,330,880 floats = 45.3 MB (ws ≈ 268 MB per profile)
    float* f      = (float*)d_ws;
    bf16*  wbuf   = (bf16*)d_ws;                 // 2359296 bf16 = 1179648 f
    bf16*  kproj  = (bf16*)(f + 1179648);        // 3211264 bf16
    bf16*  vproj  = (bf16*)(f + 2785280);        // 3211264 bf16
    float* xout   = f + 4390912;                 // 802816
    float* tmp    = f + 5193728;                 // 802816
    bf16*  tmph   = (bf16*)(f + 5996544);        // 802816 bf16
    bf16*  qbufh  = (bf16*)(f + 6397952);        // 802816 bf16
    bf16*  bigh   = (bf16*)(f + 6799360);        // 2408448 bf16
    float* attng  = f + 8003584;                 // 112896
    float* col    = f + 8116480;                 // 3136
    bf16*  xln    = (bf16*)(f + 8119616);        // 3211264 bf16
    bf16*  xh     = (bf16*)(f + 9725248);        // 3211264 bf16

    bf16* w_q    = wbuf;
    bf16* w_k    = wbuf + 65536;
    bf16* w_v    = wbuf + 131072;
    bf16* w_m1   = wbuf + 196608;
    bf16* w_m2   = wbuf + 327680;
    bf16* w_qkv  = wbuf + 458752;   // 2 layers x 196608
    bf16* w_proj = wbuf + 851968;   // 2 x 65536
    bf16* w_bm1  = wbuf + 983040;   // 2 x 196608
    bf16* w_bm2  = wbuf + 1376256;  // 2 x 196608
    bf16* w_seed = wbuf + 1769472;  // 589824

    // ---- setup ----
    convert_weights<<<6912, 256, 0, stream>>>(g_q_w, g_k_w, g_v_w, g_mlp_w1, g_mlp_w2,
                                              blk_qkv_w, blk_proj_w, blk_mlp_w1, blk_mlp_w2, wbuf);
    transpose_seedw<<<2304, 256, 0, stream>>>(g_seed_w, w_seed);
    ln_cast_kernel<<<12544, 256, 0, stream>>>(x, g_ln_in_g, g_ln_in_b, xln, xh);
    gemm_kv<<<dim3(4,392,2), 128, 0, stream>>>(xln, xh, w_k, w_v, kproj, vproj);
    hipMemsetAsync(tmp, 0, 3136*256*sizeof(float), stream);
    conv_mfma<<<dim3(4,98,3), 128, 0, stream>>>(xh, w_seed, tmp);
    // xout = LN_out(seed); tmph = LN_out(xout)
    ln_add_ln<<<3136, 256, 0, stream>>>(tmp, nullptr, g_ln_out_g, g_ln_out_b,
                                        g_ln_out_g, g_ln_out_b, xout, tmph);

    // ---- NUM_ITERS group-attention iterations ----
    for (int it=0; it<3; it++){
        gemm_mfma<bf16,bf16><<<dim3(4,98), 128, 0, stream>>>(tmph, w_q, nullptr, nullptr, qbufh, 3136,256,256, 0);
        hipMemsetAsync(col, 0, 3136*sizeof(float), stream);
        grp_attn_kernel<<<12544, 64, 0, stream>>>(kproj, qbufh, g_rpb, g_tau, attng, col);
        grp_av_kernel<<<3136, 256, 0, stream>>>(attng, col, vproj, xout);
        gemm_mfma<float,bf16><<<dim3(8,98), 128, 0, stream>>>(xout, w_m1, g_mlp_b1, nullptr, bigh, 3136,512,256, 1);
        gemm_mfma<bf16,float><<<dim3(4,98), 128, 0, stream>>>(bigh, w_m2, g_mlp_b2, nullptr, tmp, 3136,256,512, 0);
        const float* g2 = (it<2) ? g_ln_out_g : blk_ln1_g;   // it=2 feeds blk layer 0 LN1
        const float* b2 = (it<2) ? g_ln_out_b : blk_ln1_b;
        ln_add_ln<<<3136, 256, 0, stream>>>(tmp, xout, g_ln_out_g, g_ln_out_b,
                                            g2, b2, xout, tmph);
    }

    // ---- DEPTH transformer blocks (tmph holds LN1(xout) at loop entry) ----
    for (int l=0; l<2; l++){
        gemm_mfma<bf16,bf16><<<dim3(12,98), 128, 0, stream>>>(tmph, w_qkv + (size_t)l*196608, nullptr, nullptr, bigh, 3136,768,256, 0);
        blk_attn_row<<<896, 256, 0, stream>>>(bigh, qbufh);
        gemm_mfma<bf16,float><<<dim3(4,98), 128, 0, stream>>>(qbufh, w_proj + (size_t)l*65536, blk_proj_b + l*256, xout, xout, 3136,256,256, 0);
        ln256_kernel<bf16><<<3136, 256, 0, stream>>>(xout, blk_ln2_g + l*256, blk_ln2_b + l*256, tmph, 0);
        gemm_mfma<bf16,bf16><<<dim3(12,98), 128, 0, stream>>>(tmph, w_bm1 + (size_t)l*196608, blk_mlp_b1 + l*768, nullptr, bigh, 3136,768,256, 1);
        if (l==0){
            gemm_mfma<bf16,float><<<dim3(4,98), 128, 0, stream>>>(bigh, w_bm2, blk_mlp_b2, xout, xout, 3136,256,768, 0);
            ln256_kernel<bf16><<<3136, 256, 0, stream>>>(xout, blk_ln1_g + 256, blk_ln1_b + 256, tmph, 0);
        } else {
            gemm_mfma<bf16,float><<<dim3(4,98), 128, 0, stream>>>(bigh, w_bm2 + 196608, blk_mlp_b2 + 256, xout, (float*)d_out, 3136,256,768, 0);
        }
    }
}

// Round 11
// 517.181 us; speedup vs baseline: 9.6610x; 1.1089x over previous
//
#include <hip/hip_runtime.h>
#include <hip/hip_bf16.h>
#include <math.h>

typedef __hip_bfloat16 bf16;

#define LN_EPS 1e-5f

__device__ __forceinline__ float b2f(bf16 x){ return __bfloat162float(x); }
__device__ __forceinline__ float sanit(float s){ return fminf(fmaxf(s, -80.f), 80.f); }

__device__ __forceinline__ void stc(float* p, float v){ *p = v; }
__device__ __forceinline__ void stc(bf16* p, float v){ *p = __float2bfloat16(v); }

__device__ __forceinline__ short f2s(float f){
    union { __hip_bfloat16 h; short s; } u; u.h = __float2bfloat16(f); return u.s;
}
__device__ __forceinline__ float s2f(short s){
    union { short s; __hip_bfloat16 h; } u; u.s = s; return b2f(u.h);
}

using short8  = __attribute__((ext_vector_type(8))) short;
using floatx4 = __attribute__((ext_vector_type(4))) float;

__device__ __forceinline__ short8 load8(const float* p){
    float4 a1 = *(const float4*)p; float4 a2 = *(const float4*)(p+4);
    return (short8){ f2s(a1.x),f2s(a1.y),f2s(a1.z),f2s(a1.w),
                     f2s(a2.x),f2s(a2.y),f2s(a2.z),f2s(a2.w) };
}
__device__ __forceinline__ short8 load8(const bf16* p){ return *(const short8*)p; }

// ---------------- weight pre-conversion fp32 -> bf16 (one pass) -----------
__global__ void convert_weights(const float* __restrict__ q, const float* __restrict__ k,
                                const float* __restrict__ v, const float* __restrict__ m1,
                                const float* __restrict__ m2, const float* __restrict__ qkv,
                                const float* __restrict__ proj, const float* __restrict__ bm1,
                                const float* __restrict__ bm2, bf16* __restrict__ dst)
{
    int i = blockIdx.x*256 + threadIdx.x;
    if (i >= 1769472) return;
    const float* src; int off;
    if      (i <   65536){ src=q;    off=i; }
    else if (i <  131072){ src=k;    off=i-65536; }
    else if (i <  196608){ src=v;    off=i-131072; }
    else if (i <  327680){ src=m1;   off=i-196608; }
    else if (i <  458752){ src=m2;   off=i-327680; }
    else if (i <  851968){ src=qkv;  off=i-458752; }
    else if (i <  983040){ src=proj; off=i-851968; }
    else if (i < 1376256){ src=bm1;  off=i-983040; }
    else                 { src=bm2;  off=i-1376256; }
    dst[i] = __float2bfloat16(src[off]);
}

// ---------------- LayerNorm over D=256: wave-shuffle reduction ------------
template<typename TO>
__global__ void ln256_kernel(const float* __restrict__ in, const float* __restrict__ g,
                             const float* __restrict__ bb, TO* __restrict__ out, int addTo)
{
    int token = blockIdx.x; int d = threadIdx.x;
    int w = d >> 6, lane = d & 63;
    __shared__ float part[8];
    float v = in[(size_t)token*256 + d];
    float s = v;
    #pragma unroll
    for (int off=32; off>0; off>>=1) s += __shfl_down(s, off);
    if (lane==0) part[w] = s;
    __syncthreads();
    float mean = (part[0]+part[1]+part[2]+part[3]) * (1.f/256.f);
    float dev = v - mean;
    float q = dev*dev;
    __syncthreads();
    #pragma unroll
    for (int off=32; off>0; off>>=1) q += __shfl_down(q, off);
    if (lane==0) part[w+4] = q;
    __syncthreads();
    float var = (part[4]+part[5]+part[6]+part[7]) * (1.f/256.f);
    float r = dev*rsqrtf(var+LN_EPS)*g[d] + bb[d];
    size_t o = (size_t)token*256+d;
    if (addTo) out[o] += r; else stc(&out[o], r);
}

// ------- setup LN: xln = bf16(LN(x)); xh = bf16(x); zero tmp (conv acc) ---
__global__ void ln_cast_kernel(const float* __restrict__ in, const float* __restrict__ g,
                               const float* __restrict__ bb, bf16* __restrict__ xln,
                               bf16* __restrict__ xh, float* __restrict__ tmpz)
{
    int token = blockIdx.x; int d = threadIdx.x;
    int w = d >> 6, lane = d & 63;
    __shared__ float part[8];
    float v = in[(size_t)token*256 + d];
    float s = v;
    #pragma unroll
    for (int off=32; off>0; off>>=1) s += __shfl_down(s, off);
    if (lane==0) part[w] = s;
    __syncthreads();
    float mean = (part[0]+part[1]+part[2]+part[3]) * (1.f/256.f);
    float dev = v - mean;
    float q = dev*dev;
    __syncthreads();
    #pragma unroll
    for (int off=32; off>0; off>>=1) q += __shfl_down(q, off);
    if (lane==0) part[w+4] = q;
    __syncthreads();
    float var = (part[4]+part[5]+part[6]+part[7]) * (1.f/256.f);
    float r = dev*rsqrtf(var+LN_EPS)*g[d] + bb[d];
    size_t o = (size_t)token*256+d;
    xln[o] = __float2bfloat16(r);
    xh[o]  = __float2bfloat16(v);
    if (token < 3136) tmpz[(size_t)token*256 + d] = 0.f;
}

// ------- fused: xout = (resid?) + LN1(in); tmph = bf16(LN2(xout)); col=0 --
__global__ void ln_add_ln(const float* __restrict__ in, const float* __restrict__ resid,
                          const float* __restrict__ g1, const float* __restrict__ b1,
                          const float* __restrict__ g2, const float* __restrict__ b2,
                          float* __restrict__ xout, bf16* __restrict__ tmph,
                          float* __restrict__ colz)
{
    int token = blockIdx.x; int d = threadIdx.x;
    int w = d >> 6, lane = d & 63;
    __shared__ float part[8];
    size_t o = (size_t)token*256 + d;
    if (d == 0) colz[token] = 0.f;
    float v = in[o];
    float s = v;
    #pragma unroll
    for (int off=32; off>0; off>>=1) s += __shfl_down(s, off);
    if (lane==0) part[w] = s;
    __syncthreads();
    float mean = (part[0]+part[1]+part[2]+part[3]) * (1.f/256.f);
    float dev = v - mean;
    float q = dev*dev;
    __syncthreads();
    #pragma unroll
    for (int off=32; off>0; off>>=1) q += __shfl_down(q, off);
    if (lane==0) part[w+4] = q;
    __syncthreads();
    float var = (part[4]+part[5]+part[6]+part[7]) * (1.f/256.f);
    float r = dev*rsqrtf(var+LN_EPS)*g1[d] + b1[d];
    float sx = (resid ? resid[o] : 0.f) + r;
    xout[o] = sx;
    __syncthreads();
    float s2 = sx;
    #pragma unroll
    for (int off=32; off>0; off>>=1) s2 += __shfl_down(s2, off);
    if (lane==0) part[w] = s2;
    __syncthreads();
    float mean2 = (part[0]+part[1]+part[2]+part[3]) * (1.f/256.f);
    float dev2 = sx - mean2;
    float q2 = dev2*dev2;
    __syncthreads();
    #pragma unroll
    for (int off=32; off>0; off>>=1) q2 += __shfl_down(q2, off);
    if (lane==0) part[w+4] = q2;
    __syncthreads();
    float var2 = (part[4]+part[5]+part[6]+part[7]) * (1.f/256.f);
    tmph[o] = __float2bfloat16(dev2*rsqrtf(var2+LN_EPS)*g2[d] + b2[d]);
}

// ---------------- MFMA GEMM, ping-pong double-buffered LDS ----------------
template<typename TA, typename TC>
__global__ __launch_bounds__(128) void gemm_mfma(const TA* __restrict__ A,
                       const bf16* __restrict__ W,
                       const float* __restrict__ bias, const float* __restrict__ resid,
                       TC* __restrict__ C, int M, int N, int K, int do_gelu)
{
    __shared__ __align__(16) short As[2][32*40];
    __shared__ __align__(16) short Ws[2][64*40];
    int t = threadIdx.x;
    int n0 = blockIdx.x*64, m0 = blockIdx.y*32;
    int lane = t & 63, w = t >> 6;
    int quad = lane >> 4, mrow = lane & 15;
    floatx4 acc[4] = {{0,0,0,0},{0,0,0,0},{0,0,0,0},{0,0,0,0}};
    int r  = t >> 2;
    int kq = (t & 3) * 8;
    const TA*   Arow  = A + (size_t)(m0 + r)*K + kq;
    const bf16* Wrow0 = W + (size_t)(n0 + r)*K + kq;
    const bf16* Wrow1 = W + (size_t)(n0 + r + 32)*K + kq;

    short8 av  = load8(Arow);
    short8 wv0 = load8(Wrow0);
    short8 wv1 = load8(Wrow1);
    *(short8*)&As[0][r*40 + kq] = av;
    *(short8*)&Ws[0][r*40 + kq] = wv0;
    *(short8*)&Ws[0][(r+32)*40 + kq] = wv1;
    __syncthreads();

    int nb = K >> 5;
    int cur = 0;
    for (int i = 0; i < nb; i++){
        if (i+1 < nb){
            int k0 = (i+1) << 5;
            av  = load8(Arow + k0);
            wv0 = load8(Wrow0 + k0);
            wv1 = load8(Wrow1 + k0);
        }
        short8 af = *(short8*)&As[cur][(w*16 + mrow)*40 + quad*8];
        #pragma unroll
        for (int nt=0; nt<4; nt++){
            short8 bfv = *(short8*)&Ws[cur][(nt*16 + mrow)*40 + quad*8];
            acc[nt] = __builtin_amdgcn_mfma_f32_16x16x32_bf16(af, bfv, acc[nt], 0, 0, 0);
        }
        if (i+1 < nb){
            int nxt = cur ^ 1;
            *(short8*)&As[nxt][r*40 + kq] = av;
            *(short8*)&Ws[nxt][r*40 + kq] = wv0;
            *(short8*)&Ws[nxt][(r+32)*40 + kq] = wv1;
            __syncthreads();
            cur = nxt;
        }
    }
    #pragma unroll
    for (int nt=0; nt<4; nt++){
        int col = n0 + nt*16 + mrow;
        float bv = bias ? bias[col] : 0.f;
        #pragma unroll
        for (int rr=0; rr<4; rr++){
            int row = m0 + w*16 + quad*4 + rr;
            float v = acc[nt][rr] + bv;
            if (do_gelu) v = 0.5f*v*(1.0f+erff(v*0.70710678118654752f));
            size_t o = (size_t)row*N + col;
            if (resid) v += resid[o];
            stc(&C[o], v);
        }
    }
}

// ------- merged K/V projection: z=0: kproj=xln@Wk^T; z=1: vproj=xh@Wv^T ---
__global__ __launch_bounds__(128) void gemm_kv(const bf16* __restrict__ xln,
                       const bf16* __restrict__ xh, const bf16* __restrict__ wk,
                       const bf16* __restrict__ wv, bf16* __restrict__ kp,
                       bf16* __restrict__ vp)
{
    const int N = 256, K = 256;
    const bf16* A = blockIdx.z ? xh : xln;
    const bf16* W = blockIdx.z ? wv : wk;
    bf16*       C = blockIdx.z ? vp : kp;
    __shared__ __align__(16) short As[2][32*40];
    __shared__ __align__(16) short Ws[2][64*40];
    int t = threadIdx.x;
    int n0 = blockIdx.x*64, m0 = blockIdx.y*32;
    int lane = t & 63, w = t >> 6;
    int quad = lane >> 4, mrow = lane & 15;
    floatx4 acc[4] = {{0,0,0,0},{0,0,0,0},{0,0,0,0},{0,0,0,0}};
    int r  = t >> 2;
    int kq = (t & 3) * 8;
    const bf16* Arow  = A + (size_t)(m0 + r)*K + kq;
    const bf16* Wrow0 = W + (size_t)(n0 + r)*K + kq;
    const bf16* Wrow1 = W + (size_t)(n0 + r + 32)*K + kq;
    short8 av  = load8(Arow);
    short8 wv0 = load8(Wrow0);
    short8 wv1 = load8(Wrow1);
    *(short8*)&As[0][r*40 + kq] = av;
    *(short8*)&Ws[0][r*40 + kq] = wv0;
    *(short8*)&Ws[0][(r+32)*40 + kq] = wv1;
    __syncthreads();
    const int nb = K >> 5;
    int cur = 0;
    for (int i = 0; i < nb; i++){
        if (i+1 < nb){
            int k0 = (i+1) << 5;
            av  = load8(Arow + k0);
            wv0 = load8(Wrow0 + k0);
            wv1 = load8(Wrow1 + k0);
        }
        short8 af = *(short8*)&As[cur][(w*16 + mrow)*40 + quad*8];
        #pragma unroll
        for (int nt=0; nt<4; nt++){
            short8 bfv = *(short8*)&Ws[cur][(nt*16 + mrow)*40 + quad*8];
            acc[nt] = __builtin_amdgcn_mfma_f32_16x16x32_bf16(af, bfv, acc[nt], 0, 0, 0);
        }
        if (i+1 < nb){
            int nxt = cur ^ 1;
            *(short8*)&As[nxt][r*40 + kq] = av;
            *(short8*)&Ws[nxt][r*40 + kq] = wv0;
            *(short8*)&Ws[nxt][(r+32)*40 + kq] = wv1;
            __syncthreads();
            cur = nxt;
        }
    }
    #pragma unroll
    for (int nt=0; nt<4; nt++){
        int col = n0 + nt*16 + mrow;
        #pragma unroll
        for (int rr=0; rr<4; rr++){
            int row = m0 + w*16 + quad*4 + rr;
            C[(size_t)row*N + col] = __float2bfloat16(acc[nt][rr]);
        }
    }
}

// -------- seed-weight transpose+convert ----------------------------------
__global__ void transpose_seedw(const float* __restrict__ w, bf16* __restrict__ wt)
{
    int idx = blockIdx.x*256 + threadIdx.x;   // 256*2304
    if (idx >= 256*2304) return;
    int o = idx/2304; int rem = idx - o*2304; int pos = rem>>8; int ci = rem&255;
    wt[idx] = __float2bfloat16(w[(size_t)o*2304 + ci*9 + pos]);
}

// -------- 3x3 s2 p1 conv as MFMA GEMM, K-split x3, bf16 input xh ----------
__global__ __launch_bounds__(128) void conv_mfma(const bf16* __restrict__ xh,
                       const bf16* __restrict__ wt, float* __restrict__ C)
{
    const int K = 2304, N = 256, KC = 768;
    __shared__ __align__(16) short As[2][32*40];
    __shared__ __align__(16) short Ws[2][64*40];
    int t = threadIdx.x;
    int n0 = blockIdx.x*64, m0 = blockIdx.y*32, z = blockIdx.z;
    int lane = t & 63, w = t >> 6;
    int quad = lane >> 4, mrow = lane & 15;
    floatx4 acc[4] = {{0,0,0,0},{0,0,0,0},{0,0,0,0},{0,0,0,0}};
    int r  = t >> 2;
    int kq = (t & 3) * 8;
    int m = m0 + r;
    int wo = m%28, ho = (m/28)%28, b = m/784;
    const bf16* Wrow0 = wt + (size_t)(n0 + r)*K + z*KC + kq;
    const bf16* Wrow1 = wt + (size_t)(n0 + r + 32)*K + z*KC + kq;

    int kh = z;
    int ih = 2*ho + kh - 1;
    bool rowok = (ih>=0 && ih<56);

    auto loadA = [&](int k0)->short8{
        int kk = k0 + kq;
        int pos3 = kk >> 8;
        int ci = kk & 255;
        int iw = 2*wo + pos3 - 1;
        short8 a = {0,0,0,0,0,0,0,0};
        if (rowok && iw>=0 && iw<56)
            a = load8(xh + (((size_t)b*56 + ih)*56 + iw)*256 + ci);
        return a;
    };

    short8 av  = loadA(0);
    short8 wv0 = load8(Wrow0);
    short8 wv1 = load8(Wrow1);
    *(short8*)&As[0][r*40 + kq] = av;
    *(short8*)&Ws[0][r*40 + kq] = wv0;
    *(short8*)&Ws[0][(r+32)*40 + kq] = wv1;
    __syncthreads();

    const int nb = KC >> 5;
    int cur = 0;
    for (int i = 0; i < nb; i++){
        if (i+1 < nb){
            int k0 = (i+1) << 5;
            av  = loadA(k0);
            wv0 = load8(Wrow0 + k0);
            wv1 = load8(Wrow1 + k0);
        }
        short8 af = *(short8*)&As[cur][(w*16 + mrow)*40 + quad*8];
        #pragma unroll
        for (int nt=0; nt<4; nt++){
            short8 bfv = *(short8*)&Ws[cur][(nt*16 + mrow)*40 + quad*8];
            acc[nt] = __builtin_amdgcn_mfma_f32_16x16x32_bf16(af, bfv, acc[nt], 0, 0, 0);
        }
        if (i+1 < nb){
            int nxt = cur ^ 1;
            *(short8*)&As[nxt][r*40 + kq] = av;
            *(short8*)&Ws[nxt][r*40 + kq] = wv0;
            *(short8*)&Ws[nxt][(r+32)*40 + kq] = wv1;
            __syncthreads();
            cur = nxt;
        }
    }
    #pragma unroll
    for (int nt=0; nt<4; nt++){
        int col = n0 + nt*16 + mrow;
        #pragma unroll
        for (int rr=0; rr<4; rr++){
            int row = m0 + w*16 + quad*4 + rr;
            atomicAdd(&C[(size_t)row*N + col], acc[nt][rr]);
        }
    }
}

// -------- Group attention, row-tiled: one block per (b,n,i) ---------------
// Stages 28-pixel K row + 3x28 Q window in LDS (bf16); 252 threads each own
// one (pixel, neighbor) dot; softmax by 28 threads; fused column scatter.
__global__ __launch_bounds__(256) void grp_attn_row(const bf16* __restrict__ kproj,
                                const bf16* __restrict__ qbuf,
                                const float* __restrict__ rpb, const float* __restrict__ g_tau,
                                float* __restrict__ attn, float* __restrict__ col)
{
    int blk = blockIdx.x;           // (b*4+n)*28 + i
    int i = blk % 28; int bn = blk / 28; int n = bn & 3; int b = bn >> 2;
    int tid = threadIdx.x;
    int sh = n>>1, sw = n&1;
    int i0 = min(max(i-1,0),25);
    __shared__ short Ks[28*256];    // 14336 B
    __shared__ short Qs[3*28*256];  // 43008 B
    __shared__ float sc[28*9];
    __shared__ float pr[28*9];

    for (int u = tid; u < 28*32; u += 256){
        int j = u >> 5, c = u & 31;
        *(short8*)&Ks[j*256 + c*8] =
            *(const short8*)(kproj + ((size_t)b*3136 + (2*i+sh)*56 + (2*j+sw))*256 + c*8);
    }
    for (int u = tid; u < 3*28*32; u += 256){
        int r = u / (28*32); int rem = u - r*(28*32);
        int j = rem >> 5, c = rem & 31;
        *(short8*)&Qs[(r*28 + j)*256 + c*8] =
            *(const short8*)(qbuf + ((size_t)b*784 + (i0+r)*28 + j)*256 + c*8);
    }
    __syncthreads();

    float scale = expf(g_tau[0]);
    if (tid < 252){
        int pix = tid / 9, l = tid - (tid/9)*9;
        int j0 = min(max(pix-1,0),25);
        int qr = l/3, qj = j0 + (l - qr*3);
        const short* kp = &Ks[pix*256];
        const short* qp = &Qs[(qr*28 + qj)*256];
        float p = 0.f;
        for (int c = 0; c < 32; c++){
            short8 k8 = *(const short8*)(kp + c*8);
            short8 q8 = *(const short8*)(qp + c*8);
            #pragma unroll
            for (int d=0; d<8; d++) p += s2f(k8[d])*s2f(q8[d]);
        }
        sc[pix*9 + l] = sanit((p + rpb[n*9+l])*scale);
    }
    __syncthreads();
    if (tid < 28){
        float m = -1e30f;
        for (int l=0;l<9;l++) m = fmaxf(m, sc[tid*9+l]);
        float sum=0.f; float e[9];
        for (int l=0;l<9;l++){ e[l]=expf(sc[tid*9+l]-m); sum+=e[l]; }
        float inv = 1.f/fmaxf(sum,1e-30f);
        for (int l=0;l<9;l++) pr[tid*9+l] = e[l]*inv + 1e-6f;
    }
    __syncthreads();
    if (tid < 252){
        int pix = tid/9, l = tid - (tid/9)*9;
        float a = pr[pix*9+l];
        int idx = (b*4+n)*784 + i*28 + pix;
        attn[(size_t)idx*9 + l] = a;
        int j0 = min(max(pix-1,0),25);
        int qi = i0 + l/3, qj = j0 + l%3;
        atomicAdd(&col[b*784 + qi*28 + qj], a);
    }
}

__global__ void grp_av_kernel(const float* __restrict__ attn, const float* __restrict__ col,
                              const bf16* __restrict__ vproj, float* __restrict__ xout)
{
    int idx = blockIdx.x;   // b*784 + i*28 + j
    int j = idx%28; int i = (idx/28)%28; int b = idx/784;
    int d = threadIdx.x;
    int i0 = min(max(i-1,0),25), j0 = min(max(j-1,0),25);
    float acc = 0.f;
    for (int n=0; n<4; n++){
        int sh = n>>1, sw = n&1;
        const float* ap = attn + ((size_t)(b*4+n)*784 + i*28+j)*9;
        for (int l=0; l<9; l++){
            int qi = i0 + l/3, qj = j0 + l%3;
            float dv = col[b*784 + qi*28+qj] + 1e-8f;
            acc += (ap[l]/dv) * b2f(vproj[((size_t)b*3136 + (2*qi+sh)*56 + (2*qj+sw))*256 + d]);
        }
    }
    xout[(size_t)idx*256 + d] += acc;
}

// ------- Block attention (KB=7), row-tiled, RoPE fused in staging ---------
__global__ __launch_bounds__(256) void blk_attn_row(const bf16* __restrict__ qkv,
                                                    bf16* __restrict__ obuf)
{
    int blk = blockIdx.x;             // (b*28 + i)*8 + h
    int h = blk & 7; int rest = blk >> 3;
    int i = rest % 28; int b = rest / 28;
    int tid = threadIdx.x;
    int i0 = min(max(i-3,0),21);

    __shared__ float Ks[7*28*32];
    __shared__ float Vs[7*28*32];
    __shared__ float Qs[28*32];
    __shared__ float Ps[28*52];

    const float LOG1E4_16 = 0.5756462732485115f;   // ln(10000)/16

    for (int idx = tid; idx < 196*4; idx += 256){
        int pos = idx >> 2, u8 = idx & 3;
        int ki = i0 + pos/28, kj = pos - (pos/28)*28;
        int ttok = ki*28 + kj;
        const bf16* base = qkv + ((size_t)(b*784 + ttok))*768 + h*32 + u8*8;
        short8 k8 = *(const short8*)(base + 256);
        short8 v8 = *(const short8*)(base + 512);
        float f[8];
        #pragma unroll
        for (int d=0; d<8; d++) f[d] = s2f(k8[d]);
        #pragma unroll
        for (int m2=0; m2<4; m2++){
            int u = u8*4 + m2;
            float ang = (float)ttok * expf(-(float)u * LOG1E4_16);
            float c = cosf(ang), s = sinf(ang);
            float x0 = f[2*m2], x1 = f[2*m2+1];
            f[2*m2]   = x0*c - x1*s;
            f[2*m2+1] = x1*c + x0*s;
        }
        #pragma unroll
        for (int d=0; d<8; d++){
            Ks[pos*32 + u8*8 + d] = f[d];
            Vs[pos*32 + u8*8 + d] = s2f(v8[d]);
        }
    }
    for (int idx = tid; idx < 28*4; idx += 256){
        int tt = idx >> 2, u8 = idx & 3;
        int ttok = i*28 + tt;
        const bf16* base = qkv + ((size_t)(b*784 + ttok))*768 + h*32 + u8*8;
        short8 q8 = *(const short8*)base;
        float f[8];
        #pragma unroll
        for (int d=0; d<8; d++) f[d] = s2f(q8[d]);
        #pragma unroll
        for (int m2=0; m2<4; m2++){
            int u = u8*4 + m2;
            float ang = (float)ttok * expf(-(float)u * LOG1E4_16);
            float c = cosf(ang), s = sinf(ang);
            float x0 = f[2*m2], x1 = f[2*m2+1];
            f[2*m2]   = x0*c - x1*s;
            f[2*m2+1] = x1*c + x0*s;
        }
        #pragma unroll
        for (int d=0; d<8; d++) Qs[tt*32 + u8*8 + d] = f[d];
    }
    __syncthreads();

    int tt = tid >> 3, s = tid & 7;
    float sc[7];
    float mx = -1e30f;
    int j0 = min(max(tt-3,0),21);
    if (tt < 28){
        int c = 0;
        for (int l = s; l < 49; l += 8, c++){
            int ki = l/7, kj = j0 + l - (l/7)*7;
            const float4* kp = (const float4*)&Ks[(ki*28+kj)*32];
            const float4* qp = (const float4*)&Qs[tt*32];
            float p = 0.f;
            #pragma unroll
            for (int d=0; d<8; d++){
                float4 kv4 = kp[d], qv4 = qp[d];
                p += qv4.x*kv4.x + qv4.y*kv4.y + qv4.z*kv4.z + qv4.w*kv4.w;
            }
            sc[c] = sanit(p * 0.17677669529663687f);
            mx = fmaxf(mx, sc[c]);
        }
    }
    #pragma unroll
    for (int off=1; off<8; off<<=1) mx = fmaxf(mx, __shfl_xor(mx, off, 8));
    float sm = 0.f;
    if (tt < 28){
        int c = 0;
        for (int l = s; l < 49; l += 8, c++){ sc[c] = expf(sc[c]-mx); sm += sc[c]; }
    }
    #pragma unroll
    for (int off=1; off<8; off<<=1) sm += __shfl_xor(sm, off, 8);
    if (tt < 28){
        float inv = 1.f/fmaxf(sm, 1e-30f);
        int c = 0;
        for (int l = s; l < 49; l += 8, c++) Ps[tt*52 + l] = sc[c]*inv;
    }
    __syncthreads();

    for (int o = tid; o < 28*32; o += 256){
        int t2 = o >> 5, d = o & 31;
        int jj0 = min(max(t2-3,0),21);
        float acc = 0.f;
        #pragma unroll 7
        for (int l=0; l<49; l++){
            int ki = l/7, kj = jj0 + l - (l/7)*7;
            acc += Ps[t2*52 + l] * Vs[(ki*28+kj)*32 + d];
        }
        obuf[((size_t)(b*784 + i*28 + t2))*256 + h*32 + d] = __float2bfloat16(acc);
    }
}

// ==========================================================================
extern "C" void kernel_launch(void* const* d_in, const int* in_sizes, int n_in,
                              void* d_out, int out_size, void* d_ws, size_t ws_size,
                              hipStream_t stream) {
    const float* x         = (const float*)d_in[0];
    const float* g_seed_w  = (const float*)d_in[1];
    const float* g_q_w     = (const float*)d_in[2];
    const float* g_k_w     = (const float*)d_in[3];
    const float* g_v_w     = (const float*)d_in[4];
    const float* g_mlp_w1  = (const float*)d_in[5];
    const float* g_mlp_b1  = (const float*)d_in[6];
    const float* g_mlp_w2  = (const float*)d_in[7];
    const float* g_mlp_b2  = (const float*)d_in[8];
    const float* g_ln_in_g = (const float*)d_in[9];
    const float* g_ln_in_b = (const float*)d_in[10];
    const float* g_ln_out_g= (const float*)d_in[11];
    const float* g_ln_out_b= (const float*)d_in[12];
    const float* g_tau     = (const float*)d_in[13];
    const float* g_rpb     = (const float*)d_in[14];
    const float* blk_ln1_g = (const float*)d_in[15];
    const float* blk_ln1_b = (const float*)d_in[16];
    const float* blk_qkv_w = (const float*)d_in[17];
    const float* blk_proj_w= (const float*)d_in[18];
    const float* blk_proj_b= (const float*)d_in[19];
    const float* blk_ln2_g = (const float*)d_in[20];
    const float* blk_ln2_b = (const float*)d_in[21];
    const float* blk_mlp_w1= (const float*)d_in[22];
    const float* blk_mlp_b1= (const float*)d_in[23];
    const float* blk_mlp_w2= (const float*)d_in[24];
    const float* blk_mlp_b2= (const float*)d_in[25];

    // workspace layout — 11,330,880 floats = 45.3 MB (ws ≈ 268 MB per profile)
    float* f      = (float*)d_ws;
    bf16*  wbuf   = (bf16*)d_ws;                 // 2359296 bf16 = 1179648 f
    bf16*  kproj  = (bf16*)(f + 1179648);        // 3211264 bf16
    bf16*  vproj  = (bf16*)(f + 2785280);        // 3211264 bf16
    float* xout   = f + 4390912;                 // 802816
    float* tmp    = f + 5193728;                 // 802816
    bf16*  tmph   = (bf16*)(f + 5996544);        // 802816 bf16
    bf16*  qbufh  = (bf16*)(f + 6397952);        // 802816 bf16
    bf16*  bigh   = (bf16*)(f + 6799360);        // 2408448 bf16
    float* attng  = f + 8003584;                 // 112896
    float* col    = f + 8116480;                 // 3136
    bf16*  xln    = (bf16*)(f + 8119616);        // 3211264 bf16
    bf16*  xh     = (bf16*)(f + 9725248);        // 3211264 bf16

    bf16* w_q    = wbuf;
    bf16* w_k    = wbuf + 65536;
    bf16* w_v    = wbuf + 131072;
    bf16* w_m1   = wbuf + 196608;
    bf16* w_m2   = wbuf + 327680;
    bf16* w_qkv  = wbuf + 458752;   // 2 layers x 196608
    bf16* w_proj = wbuf + 851968;   // 2 x 65536
    bf16* w_bm1  = wbuf + 983040;   // 2 x 196608
    bf16* w_bm2  = wbuf + 1376256;  // 2 x 196608
    bf16* w_seed = wbuf + 1769472;  // 589824

    // ---- setup ----
    convert_weights<<<6912, 256, 0, stream>>>(g_q_w, g_k_w, g_v_w, g_mlp_w1, g_mlp_w2,
                                              blk_qkv_w, blk_proj_w, blk_mlp_w1, blk_mlp_w2, wbuf);
    transpose_seedw<<<2304, 256, 0, stream>>>(g_seed_w, w_seed);
    ln_cast_kernel<<<12544, 256, 0, stream>>>(x, g_ln_in_g, g_ln_in_b, xln, xh, tmp);
    gemm_kv<<<dim3(4,392,2), 128, 0, stream>>>(xln, xh, w_k, w_v, kproj, vproj);
    conv_mfma<<<dim3(4,98,3), 128, 0, stream>>>(xh, w_seed, tmp);
    // xout = LN_out(seed); tmph = LN_out(xout); col = 0
    ln_add_ln<<<3136, 256, 0, stream>>>(tmp, nullptr, g_ln_out_g, g_ln_out_b,
                                        g_ln_out_g, g_ln_out_b, xout, tmph, col);

    // ---- NUM_ITERS group-attention iterations ----
    for (int it=0; it<3; it++){
        gemm_mfma<bf16,bf16><<<dim3(4,98), 128, 0, stream>>>(tmph, w_q, nullptr, nullptr, qbufh, 3136,256,256, 0);
        grp_attn_row<<<448, 256, 0, stream>>>(kproj, qbufh, g_rpb, g_tau, attng, col);
        grp_av_kernel<<<3136, 256, 0, stream>>>(attng, col, vproj, xout);
        gemm_mfma<float,bf16><<<dim3(8,98), 128, 0, stream>>>(xout, w_m1, g_mlp_b1, nullptr, bigh, 3136,512,256, 1);
        gemm_mfma<bf16,float><<<dim3(4,98), 128, 0, stream>>>(bigh, w_m2, g_mlp_b2, nullptr, tmp, 3136,256,512, 0);
        const float* g2 = (it<2) ? g_ln_out_g : blk_ln1_g;   // it=2 feeds blk layer 0 LN1
        const float* b2 = (it<2) ? g_ln_out_b : blk_ln1_b;
        ln_add_ln<<<3136, 256, 0, stream>>>(tmp, xout, g_ln_out_g, g_ln_out_b,
                                            g2, b2, xout, tmph, col);
    }

    // ---- DEPTH transformer blocks (tmph holds LN1(xout) at loop entry) ----
    for (int l=0; l<2; l++){
        gemm_mfma<bf16,bf16><<<dim3(12,98), 128, 0, stream>>>(tmph, w_qkv + (size_t)l*196608, nullptr, nullptr, bigh, 3136,768,256, 0);
        blk_attn_row<<<896, 256, 0, stream>>>(bigh, qbufh);
        gemm_mfma<bf16,float><<<dim3(4,98), 128, 0, stream>>>(qbufh, w_proj + (size_t)l*65536, blk_proj_b + l*256, xout, xout, 3136,256,256, 0);
        ln256_kernel<bf16><<<3136, 256, 0, stream>>>(xout, blk_ln2_g + l*256, blk_ln2_b + l*256, tmph, 0);
        gemm_mfma<bf16,bf16><<<dim3(12,98), 128, 0, stream>>>(tmph, w_bm1 + (size_t)l*196608, blk_mlp_b1 + l*768, nullptr, bigh, 3136,768,256, 1);
        if (l==0){
            gemm_mfma<bf16,float><<<dim3(4,98), 128, 0, stream>>>(bigh, w_bm2, blk_mlp_b2, xout, xout, 3136,256,768, 0);
            ln256_kernel<bf16><<<3136, 256, 0, stream>>>(xout, blk_ln1_g + 256, blk_ln1_b + 256, tmph, 0);
        } else {
            gemm_mfma<bf16,float><<<dim3(4,98), 128, 0, stream>>>(bigh, w_bm2 + 196608, blk_mlp_b2 + 256, xout, (float*)d_out, 3136,256,768, 0);
        }
    }
}

// Round 12
// 502.987 us; speedup vs baseline: 9.9336x; 1.0282x over previous
//
#include <hip/hip_runtime.h>
#include <hip/hip_bf16.h>
#include <math.h>

typedef __hip_bfloat16 bf16;

#define LN_EPS 1e-5f

__device__ __forceinline__ float b2f(bf16 x){ return __bfloat162float(x); }
__device__ __forceinline__ float sanit(float s){ return fminf(fmaxf(s, -80.f), 80.f); }

__device__ __forceinline__ void stc(float* p, float v){ *p = v; }
__device__ __forceinline__ void stc(bf16* p, float v){ *p = __float2bfloat16(v); }

__device__ __forceinline__ short f2s(float f){
    union { __hip_bfloat16 h; short s; } u; u.h = __float2bfloat16(f); return u.s;
}
__device__ __forceinline__ float s2f(short s){
    union { short s; __hip_bfloat16 h; } u; u.s = s; return b2f(u.h);
}

using short8  = __attribute__((ext_vector_type(8))) short;
using floatx4 = __attribute__((ext_vector_type(4))) float;

__device__ __forceinline__ short8 load8(const float* p){
    float4 a1 = *(const float4*)p; float4 a2 = *(const float4*)(p+4);
    return (short8){ f2s(a1.x),f2s(a1.y),f2s(a1.z),f2s(a1.w),
                     f2s(a2.x),f2s(a2.y),f2s(a2.z),f2s(a2.w) };
}
__device__ __forceinline__ short8 load8(const bf16* p){ return *(const short8*)p; }

// ------- fused setup: blocks [0,12544) ln_cast | [12544,19456) weight cvt |
//         [19456,21760) seed transpose. Independent jobs overlap on CUs.
__global__ void setup_fused(const float* __restrict__ x, const float* __restrict__ g,
                            const float* __restrict__ bb, bf16* __restrict__ xln,
                            bf16* __restrict__ xh, float* __restrict__ tmpz,
                            const float* __restrict__ wq, const float* __restrict__ wk,
                            const float* __restrict__ wv, const float* __restrict__ m1,
                            const float* __restrict__ m2, const float* __restrict__ qkv,
                            const float* __restrict__ proj, const float* __restrict__ bm1,
                            const float* __restrict__ bm2, bf16* __restrict__ wdst,
                            const float* __restrict__ sw, bf16* __restrict__ swt)
{
    int blk = blockIdx.x; int tid = threadIdx.x;
    if (blk < 12544){
        int token = blk; int d = tid;
        int w = d >> 6, lane = d & 63;
        __shared__ float part[8];
        float v = x[(size_t)token*256 + d];
        float s = v;
        #pragma unroll
        for (int off=32; off>0; off>>=1) s += __shfl_down(s, off);
        if (lane==0) part[w] = s;
        __syncthreads();
        float mean = (part[0]+part[1]+part[2]+part[3]) * (1.f/256.f);
        float dev = v - mean;
        float q = dev*dev;
        __syncthreads();
        #pragma unroll
        for (int off=32; off>0; off>>=1) q += __shfl_down(q, off);
        if (lane==0) part[w+4] = q;
        __syncthreads();
        float var = (part[4]+part[5]+part[6]+part[7]) * (1.f/256.f);
        float r = dev*rsqrtf(var+LN_EPS)*g[d] + bb[d];
        size_t o = (size_t)token*256+d;
        xln[o] = __float2bfloat16(r);
        xh[o]  = __float2bfloat16(v);
        if (token < 3136) tmpz[(size_t)token*256 + d] = 0.f;
    } else if (blk < 19456){
        int i = (blk-12544)*256 + tid;
        const float* src; int off;
        if      (i <   65536){ src=wq;   off=i; }
        else if (i <  131072){ src=wk;   off=i-65536; }
        else if (i <  196608){ src=wv;   off=i-131072; }
        else if (i <  327680){ src=m1;   off=i-196608; }
        else if (i <  458752){ src=m2;   off=i-327680; }
        else if (i <  851968){ src=qkv;  off=i-458752; }
        else if (i <  983040){ src=proj; off=i-851968; }
        else if (i < 1376256){ src=bm1;  off=i-983040; }
        else                 { src=bm2;  off=i-1376256; }
        wdst[i] = __float2bfloat16(src[off]);
    } else {
        int idx = (blk-19456)*256 + tid;   // 256*2304
        int o = idx/2304; int rem = idx - o*2304; int pos = rem>>8; int ci = rem&255;
        swt[idx] = __float2bfloat16(sw[(size_t)o*2304 + ci*9 + pos]);
    }
}

// ------- fused: xout = (resid?) + LN1(in); tmph = bf16(LN2(xout)); col=0 --
__global__ void ln_add_ln(const float* __restrict__ in, const float* __restrict__ resid,
                          const float* __restrict__ g1, const float* __restrict__ b1,
                          const float* __restrict__ g2, const float* __restrict__ b2,
                          float* __restrict__ xout, bf16* __restrict__ tmph,
                          float* __restrict__ colz)
{
    int token = blockIdx.x; int d = threadIdx.x;
    int w = d >> 6, lane = d & 63;
    __shared__ float part[8];
    size_t o = (size_t)token*256 + d;
    if (d == 0) colz[token] = 0.f;
    float v = in[o];
    float s = v;
    #pragma unroll
    for (int off=32; off>0; off>>=1) s += __shfl_down(s, off);
    if (lane==0) part[w] = s;
    __syncthreads();
    float mean = (part[0]+part[1]+part[2]+part[3]) * (1.f/256.f);
    float dev = v - mean;
    float q = dev*dev;
    __syncthreads();
    #pragma unroll
    for (int off=32; off>0; off>>=1) q += __shfl_down(q, off);
    if (lane==0) part[w+4] = q;
    __syncthreads();
    float var = (part[4]+part[5]+part[6]+part[7]) * (1.f/256.f);
    float r = dev*rsqrtf(var+LN_EPS)*g1[d] + b1[d];
    float sx = (resid ? resid[o] : 0.f) + r;
    xout[o] = sx;
    __syncthreads();
    float s2 = sx;
    #pragma unroll
    for (int off=32; off>0; off>>=1) s2 += __shfl_down(s2, off);
    if (lane==0) part[w] = s2;
    __syncthreads();
    float mean2 = (part[0]+part[1]+part[2]+part[3]) * (1.f/256.f);
    float dev2 = sx - mean2;
    float q2 = dev2*dev2;
    __syncthreads();
    #pragma unroll
    for (int off=32; off>0; off>>=1) q2 += __shfl_down(q2, off);
    if (lane==0) part[w+4] = q2;
    __syncthreads();
    float var2 = (part[4]+part[5]+part[6]+part[7]) * (1.f/256.f);
    tmph[o] = __float2bfloat16(dev2*rsqrtf(var2+LN_EPS)*g2[d] + b2[d]);
}

// ---------------- LayerNorm over D=256: wave-shuffle reduction ------------
template<typename TO>
__global__ void ln256_kernel(const float* __restrict__ in, const float* __restrict__ g,
                             const float* __restrict__ bb, TO* __restrict__ out, int addTo)
{
    int token = blockIdx.x; int d = threadIdx.x;
    int w = d >> 6, lane = d & 63;
    __shared__ float part[8];
    float v = in[(size_t)token*256 + d];
    float s = v;
    #pragma unroll
    for (int off=32; off>0; off>>=1) s += __shfl_down(s, off);
    if (lane==0) part[w] = s;
    __syncthreads();
    float mean = (part[0]+part[1]+part[2]+part[3]) * (1.f/256.f);
    float dev = v - mean;
    float q = dev*dev;
    __syncthreads();
    #pragma unroll
    for (int off=32; off>0; off>>=1) q += __shfl_down(q, off);
    if (lane==0) part[w+4] = q;
    __syncthreads();
    float var = (part[4]+part[5]+part[6]+part[7]) * (1.f/256.f);
    float r = dev*rsqrtf(var+LN_EPS)*g[d] + bb[d];
    size_t o = (size_t)token*256+d;
    if (addTo) out[o] += r; else stc(&out[o], r);
}

// ---------------- MFMA GEMM, ping-pong double-buffered LDS ----------------
template<typename TA, typename TC>
__global__ __launch_bounds__(128) void gemm_mfma(const TA* __restrict__ A,
                       const bf16* __restrict__ W,
                       const float* __restrict__ bias, const float* __restrict__ resid,
                       TC* __restrict__ C, int M, int N, int K, int do_gelu)
{
    __shared__ __align__(16) short As[2][32*40];
    __shared__ __align__(16) short Ws[2][64*40];
    int t = threadIdx.x;
    int n0 = blockIdx.x*64, m0 = blockIdx.y*32;
    int lane = t & 63, w = t >> 6;
    int quad = lane >> 4, mrow = lane & 15;
    floatx4 acc[4] = {{0,0,0,0},{0,0,0,0},{0,0,0,0},{0,0,0,0}};
    int r  = t >> 2;
    int kq = (t & 3) * 8;
    const TA*   Arow  = A + (size_t)(m0 + r)*K + kq;
    const bf16* Wrow0 = W + (size_t)(n0 + r)*K + kq;
    const bf16* Wrow1 = W + (size_t)(n0 + r + 32)*K + kq;

    short8 av  = load8(Arow);
    short8 wv0 = load8(Wrow0);
    short8 wv1 = load8(Wrow1);
    *(short8*)&As[0][r*40 + kq] = av;
    *(short8*)&Ws[0][r*40 + kq] = wv0;
    *(short8*)&Ws[0][(r+32)*40 + kq] = wv1;
    __syncthreads();

    int nb = K >> 5;
    int cur = 0;
    for (int i = 0; i < nb; i++){
        if (i+1 < nb){
            int k0 = (i+1) << 5;
            av  = load8(Arow + k0);
            wv0 = load8(Wrow0 + k0);
            wv1 = load8(Wrow1 + k0);
        }
        short8 af = *(short8*)&As[cur][(w*16 + mrow)*40 + quad*8];
        #pragma unroll
        for (int nt=0; nt<4; nt++){
            short8 bfv = *(short8*)&Ws[cur][(nt*16 + mrow)*40 + quad*8];
            acc[nt] = __builtin_amdgcn_mfma_f32_16x16x32_bf16(af, bfv, acc[nt], 0, 0, 0);
        }
        if (i+1 < nb){
            int nxt = cur ^ 1;
            *(short8*)&As[nxt][r*40 + kq] = av;
            *(short8*)&Ws[nxt][r*40 + kq] = wv0;
            *(short8*)&Ws[nxt][(r+32)*40 + kq] = wv1;
            __syncthreads();
            cur = nxt;
        }
    }
    #pragma unroll
    for (int nt=0; nt<4; nt++){
        int col = n0 + nt*16 + mrow;
        float bv = bias ? bias[col] : 0.f;
        #pragma unroll
        for (int rr=0; rr<4; rr++){
            int row = m0 + w*16 + quad*4 + rr;
            float v = acc[nt][rr] + bv;
            if (do_gelu) v = 0.5f*v*(1.0f+erff(v*0.70710678118654752f));
            size_t o = (size_t)row*N + col;
            if (resid) v += resid[o];
            stc(&C[o], v);
        }
    }
}

// ------- merged K/V projection + seed conv, one dispatch ------------------
// z=0: kproj = xln@Wk^T   z=1: vproj = xh@Wv^T   (y in [0,392), M=12544)
// z=2: conv chunk = y/98, m0 = (y%98)*32 (y<294; atomicAdd into Cconv)
__global__ __launch_bounds__(128) void kv_conv(const bf16* __restrict__ xln,
                       const bf16* __restrict__ xh, const bf16* __restrict__ wk,
                       const bf16* __restrict__ wv, bf16* __restrict__ kp,
                       bf16* __restrict__ vp, const bf16* __restrict__ wt,
                       float* __restrict__ Cconv)
{
    __shared__ __align__(16) short As[2][32*40];
    __shared__ __align__(16) short Ws[2][64*40];
    int t = threadIdx.x;
    int lane = t & 63, w = t >> 6;
    int quad = lane >> 4, mrow = lane & 15;
    int r  = t >> 2;
    int kq = (t & 3) * 8;
    floatx4 acc[4] = {{0,0,0,0},{0,0,0,0},{0,0,0,0},{0,0,0,0}};
    int z = blockIdx.z;
    int n0 = blockIdx.x*64;

    if (z < 2){
        const int N = 256, K = 256;
        int m0 = blockIdx.y*32;
        const bf16* A = z ? xh : xln;
        const bf16* W = z ? wv : wk;
        bf16*       C = z ? vp : kp;
        const bf16* Arow  = A + (size_t)(m0 + r)*K + kq;
        const bf16* Wrow0 = W + (size_t)(n0 + r)*K + kq;
        const bf16* Wrow1 = W + (size_t)(n0 + r + 32)*K + kq;
        short8 av  = load8(Arow);
        short8 wv0 = load8(Wrow0);
        short8 wv1 = load8(Wrow1);
        *(short8*)&As[0][r*40 + kq] = av;
        *(short8*)&Ws[0][r*40 + kq] = wv0;
        *(short8*)&Ws[0][(r+32)*40 + kq] = wv1;
        __syncthreads();
        const int nb = K >> 5;
        int cur = 0;
        for (int i = 0; i < nb; i++){
            if (i+1 < nb){
                int k0 = (i+1) << 5;
                av  = load8(Arow + k0);
                wv0 = load8(Wrow0 + k0);
                wv1 = load8(Wrow1 + k0);
            }
            short8 af = *(short8*)&As[cur][(w*16 + mrow)*40 + quad*8];
            #pragma unroll
            for (int nt=0; nt<4; nt++){
                short8 bfv = *(short8*)&Ws[cur][(nt*16 + mrow)*40 + quad*8];
                acc[nt] = __builtin_amdgcn_mfma_f32_16x16x32_bf16(af, bfv, acc[nt], 0, 0, 0);
            }
            if (i+1 < nb){
                int nxt = cur ^ 1;
                *(short8*)&As[nxt][r*40 + kq] = av;
                *(short8*)&Ws[nxt][r*40 + kq] = wv0;
                *(short8*)&Ws[nxt][(r+32)*40 + kq] = wv1;
                __syncthreads();
                cur = nxt;
            }
        }
        #pragma unroll
        for (int nt=0; nt<4; nt++){
            int col = n0 + nt*16 + mrow;
            #pragma unroll
            for (int rr=0; rr<4; rr++){
                int row = m0 + w*16 + quad*4 + rr;
                C[(size_t)row*N + col] = __float2bfloat16(acc[nt][rr]);
            }
        }
    } else {
        int yy = blockIdx.y;
        if (yy >= 294) return;
        const int K = 2304, N = 256, KC = 768;
        int zc = yy / 98;
        int m0 = (yy - zc*98)*32;
        int m = m0 + r;
        int wo = m%28, ho = (m/28)%28, b = m/784;
        const bf16* Wrow0 = wt + (size_t)(n0 + r)*K + zc*KC + kq;
        const bf16* Wrow1 = wt + (size_t)(n0 + r + 32)*K + zc*KC + kq;
        int kh = zc;
        int ih = 2*ho + kh - 1;
        bool rowok = (ih>=0 && ih<56);
        auto loadA = [&](int k0)->short8{
            int kk = k0 + kq;
            int pos3 = kk >> 8;
            int ci = kk & 255;
            int iw = 2*wo + pos3 - 1;
            short8 a = {0,0,0,0,0,0,0,0};
            if (rowok && iw>=0 && iw<56)
                a = load8(xh + (((size_t)b*56 + ih)*56 + iw)*256 + ci);
            return a;
        };
        short8 av  = loadA(0);
        short8 wv0 = load8(Wrow0);
        short8 wv1 = load8(Wrow1);
        *(short8*)&As[0][r*40 + kq] = av;
        *(short8*)&Ws[0][r*40 + kq] = wv0;
        *(short8*)&Ws[0][(r+32)*40 + kq] = wv1;
        __syncthreads();
        const int nb = KC >> 5;
        int cur = 0;
        for (int i = 0; i < nb; i++){
            if (i+1 < nb){
                int k0 = (i+1) << 5;
                av  = loadA(k0);
                wv0 = load8(Wrow0 + k0);
                wv1 = load8(Wrow1 + k0);
            }
            short8 af = *(short8*)&As[cur][(w*16 + mrow)*40 + quad*8];
            #pragma unroll
            for (int nt=0; nt<4; nt++){
                short8 bfv = *(short8*)&Ws[cur][(nt*16 + mrow)*40 + quad*8];
                acc[nt] = __builtin_amdgcn_mfma_f32_16x16x32_bf16(af, bfv, acc[nt], 0, 0, 0);
            }
            if (i+1 < nb){
                int nxt = cur ^ 1;
                *(short8*)&As[nxt][r*40 + kq] = av;
                *(short8*)&Ws[nxt][r*40 + kq] = wv0;
                *(short8*)&Ws[nxt][(r+32)*40 + kq] = wv1;
                __syncthreads();
                cur = nxt;
            }
        }
        #pragma unroll
        for (int nt=0; nt<4; nt++){
            int col = n0 + nt*16 + mrow;
            #pragma unroll
            for (int rr=0; rr<4; rr++){
                int row = m0 + w*16 + quad*4 + rr;
                atomicAdd(&Cconv[(size_t)row*N + col], acc[nt][rr]);
            }
        }
    }
}

// -------- Group attention, row-tiled: one block per (b,n,i) ---------------
__global__ __launch_bounds__(256) void grp_attn_row(const bf16* __restrict__ kproj,
                                const bf16* __restrict__ qbuf,
                                const float* __restrict__ rpb, const float* __restrict__ g_tau,
                                float* __restrict__ attn, float* __restrict__ col)
{
    int blk = blockIdx.x;           // (b*4+n)*28 + i
    int i = blk % 28; int bn = blk / 28; int n = bn & 3; int b = bn >> 2;
    int tid = threadIdx.x;
    int sh = n>>1, sw = n&1;
    int i0 = min(max(i-1,0),25);
    __shared__ short Ks[28*256];
    __shared__ short Qs[3*28*256];
    __shared__ float sc[28*9];
    __shared__ float pr[28*9];

    for (int u = tid; u < 28*32; u += 256){
        int j = u >> 5, c = u & 31;
        *(short8*)&Ks[j*256 + c*8] =
            *(const short8*)(kproj + ((size_t)b*3136 + (2*i+sh)*56 + (2*j+sw))*256 + c*8);
    }
    for (int u = tid; u < 3*28*32; u += 256){
        int r = u / (28*32); int rem = u - r*(28*32);
        int j = rem >> 5, c = rem & 31;
        *(short8*)&Qs[(r*28 + j)*256 + c*8] =
            *(const short8*)(qbuf + ((size_t)b*784 + (i0+r)*28 + j)*256 + c*8);
    }
    __syncthreads();

    float scale = expf(g_tau[0]);
    if (tid < 252){
        int pix = tid / 9, l = tid - (tid/9)*9;
        int j0 = min(max(pix-1,0),25);
        int qr = l/3, qj = j0 + (l - qr*3);
        const short* kp = &Ks[pix*256];
        const short* qp = &Qs[(qr*28 + qj)*256];
        float p = 0.f;
        for (int c = 0; c < 32; c++){
            short8 k8 = *(const short8*)(kp + c*8);
            short8 q8 = *(const short8*)(qp + c*8);
            #pragma unroll
            for (int d=0; d<8; d++) p += s2f(k8[d])*s2f(q8[d]);
        }
        sc[pix*9 + l] = sanit((p + rpb[n*9+l])*scale);
    }
    __syncthreads();
    if (tid < 28){
        float m = -1e30f;
        for (int l=0;l<9;l++) m = fmaxf(m, sc[tid*9+l]);
        float sum=0.f; float e[9];
        for (int l=0;l<9;l++){ e[l]=expf(sc[tid*9+l]-m); sum+=e[l]; }
        float inv = 1.f/fmaxf(sum,1e-30f);
        for (int l=0;l<9;l++) pr[tid*9+l] = e[l]*inv + 1e-6f;
    }
    __syncthreads();
    if (tid < 252){
        int pix = tid/9, l = tid - (tid/9)*9;
        float a = pr[pix*9+l];
        int idx = (b*4+n)*784 + i*28 + pix;
        attn[(size_t)idx*9 + l] = a;
        int j0 = min(max(pix-1,0),25);
        int qi = i0 + l/3, qj = j0 + l%3;
        atomicAdd(&col[b*784 + qi*28 + qj], a);
    }
}

__global__ void grp_av_kernel(const float* __restrict__ attn, const float* __restrict__ col,
                              const bf16* __restrict__ vproj, float* __restrict__ xout,
                              bf16* __restrict__ xouth)
{
    int idx = blockIdx.x;   // b*784 + i*28 + j
    int j = idx%28; int i = (idx/28)%28; int b = idx/784;
    int d = threadIdx.x;
    int i0 = min(max(i-1,0),25), j0 = min(max(j-1,0),25);
    float acc = 0.f;
    for (int n=0; n<4; n++){
        int sh = n>>1, sw = n&1;
        const float* ap = attn + ((size_t)(b*4+n)*784 + i*28+j)*9;
        for (int l=0; l<9; l++){
            int qi = i0 + l/3, qj = j0 + l%3;
            float dv = col[b*784 + qi*28+qj] + 1e-8f;
            acc += (ap[l]/dv) * b2f(vproj[((size_t)b*3136 + (2*qi+sh)*56 + (2*qj+sw))*256 + d]);
        }
    }
    size_t o = (size_t)idx*256 + d;
    float nv = xout[o] + acc;
    xout[o] = nv;
    xouth[o] = __float2bfloat16(nv);
}

// ------- Block attention (KB=7), row-tiled, RoPE fused in staging ---------
__global__ __launch_bounds__(256) void blk_attn_row(const bf16* __restrict__ qkv,
                                                    bf16* __restrict__ obuf)
{
    int blk = blockIdx.x;             // (b*28 + i)*8 + h
    int h = blk & 7; int rest = blk >> 3;
    int i = rest % 28; int b = rest / 28;
    int tid = threadIdx.x;
    int i0 = min(max(i-3,0),21);

    __shared__ float Ks[7*28*32];
    __shared__ float Vs[7*28*32];
    __shared__ float Qs[28*32];
    __shared__ float Ps[28*52];

    const float LOG1E4_16 = 0.5756462732485115f;   // ln(10000)/16

    for (int idx = tid; idx < 196*4; idx += 256){
        int pos = idx >> 2, u8 = idx & 3;
        int ki = i0 + pos/28, kj = pos - (pos/28)*28;
        int ttok = ki*28 + kj;
        const bf16* base = qkv + ((size_t)(b*784 + ttok))*768 + h*32 + u8*8;
        short8 k8 = *(const short8*)(base + 256);
        short8 v8 = *(const short8*)(base + 512);
        float f[8];
        #pragma unroll
        for (int d=0; d<8; d++) f[d] = s2f(k8[d]);
        #pragma unroll
        for (int m2=0; m2<4; m2++){
            int u = u8*4 + m2;
            float ang = (float)ttok * expf(-(float)u * LOG1E4_16);
            float c = cosf(ang), s = sinf(ang);
            float x0 = f[2*m2], x1 = f[2*m2+1];
            f[2*m2]   = x0*c - x1*s;
            f[2*m2+1] = x1*c + x0*s;
        }
        #pragma unroll
        for (int d=0; d<8; d++){
            Ks[pos*32 + u8*8 + d] = f[d];
            Vs[pos*32 + u8*8 + d] = s2f(v8[d]);
        }
    }
    for (int idx = tid; idx < 28*4; idx += 256){
        int tt = idx >> 2, u8 = idx & 3;
        int ttok = i*28 + tt;
        const bf16* base = qkv + ((size_t)(b*784 + ttok))*768 + h*32 + u8*8;
        short8 q8 = *(const short8*)base;
        float f[8];
        #pragma unroll
        for (int d=0; d<8; d++) f[d] = s2f(q8[d]);
        #pragma unroll
        for (int m2=0; m2<4; m2++){
            int u = u8*4 + m2;
            float ang = (float)ttok * expf(-(float)u * LOG1E4_16);
            float c = cosf(ang), s = sinf(ang);
            float x0 = f[2*m2], x1 = f[2*m2+1];
            f[2*m2]   = x0*c - x1*s;
            f[2*m2+1] = x1*c + x0*s;
        }
        #pragma unroll
        for (int d=0; d<8; d++) Qs[tt*32 + u8*8 + d] = f[d];
    }
    __syncthreads();

    int tt = tid >> 3, s = tid & 7;
    float sc[7];
    float mx = -1e30f;
    int j0 = min(max(tt-3,0),21);
    if (tt < 28){
        int c = 0;
        for (int l = s; l < 49; l += 8, c++){
            int ki = l/7, kj = j0 + l - (l/7)*7;
            const float4* kp = (const float4*)&Ks[(ki*28+kj)*32];
            const float4* qp = (const float4*)&Qs[tt*32];
            float p = 0.f;
            #pragma unroll
            for (int d=0; d<8; d++){
                float4 kv4 = kp[d], qv4 = qp[d];
                p += qv4.x*kv4.x + qv4.y*kv4.y + qv4.z*kv4.z + qv4.w*kv4.w;
            }
            sc[c] = sanit(p * 0.17677669529663687f);
            mx = fmaxf(mx, sc[c]);
        }
    }
    #pragma unroll
    for (int off=1; off<8; off<<=1) mx = fmaxf(mx, __shfl_xor(mx, off, 8));
    float sm = 0.f;
    if (tt < 28){
        int c = 0;
        for (int l = s; l < 49; l += 8, c++){ sc[c] = expf(sc[c]-mx); sm += sc[c]; }
    }
    #pragma unroll
    for (int off=1; off<8; off<<=1) sm += __shfl_xor(sm, off, 8);
    if (tt < 28){
        float inv = 1.f/fmaxf(sm, 1e-30f);
        int c = 0;
        for (int l = s; l < 49; l += 8, c++) Ps[tt*52 + l] = sc[c]*inv;
    }
    __syncthreads();

    for (int o = tid; o < 28*32; o += 256){
        int t2 = o >> 5, d = o & 31;
        int jj0 = min(max(t2-3,0),21);
        float acc = 0.f;
        #pragma unroll 7
        for (int l=0; l<49; l++){
            int ki = l/7, kj = jj0 + l - (l/7)*7;
            acc += Ps[t2*52 + l] * Vs[(ki*28+kj)*32 + d];
        }
        obuf[((size_t)(b*784 + i*28 + t2))*256 + h*32 + d] = __float2bfloat16(acc);
    }
}

// ==========================================================================
extern "C" void kernel_launch(void* const* d_in, const int* in_sizes, int n_in,
                              void* d_out, int out_size, void* d_ws, size_t ws_size,
                              hipStream_t stream) {
    const float* x         = (const float*)d_in[0];
    const float* g_seed_w  = (const float*)d_in[1];
    const float* g_q_w     = (const float*)d_in[2];
    const float* g_k_w     = (const float*)d_in[3];
    const float* g_v_w     = (const float*)d_in[4];
    const float* g_mlp_w1  = (const float*)d_in[5];
    const float* g_mlp_b1  = (const float*)d_in[6];
    const float* g_mlp_w2  = (const float*)d_in[7];
    const float* g_mlp_b2  = (const float*)d_in[8];
    const float* g_ln_in_g = (const float*)d_in[9];
    const float* g_ln_in_b = (const float*)d_in[10];
    const float* g_ln_out_g= (const float*)d_in[11];
    const float* g_ln_out_b= (const float*)d_in[12];
    const float* g_tau     = (const float*)d_in[13];
    const float* g_rpb     = (const float*)d_in[14];
    const float* blk_ln1_g = (const float*)d_in[15];
    const float* blk_ln1_b = (const float*)d_in[16];
    const float* blk_qkv_w = (const float*)d_in[17];
    const float* blk_proj_w= (const float*)d_in[18];
    const float* blk_proj_b= (const float*)d_in[19];
    const float* blk_ln2_g = (const float*)d_in[20];
    const float* blk_ln2_b = (const float*)d_in[21];
    const float* blk_mlp_w1= (const float*)d_in[22];
    const float* blk_mlp_b1= (const float*)d_in[23];
    const float* blk_mlp_w2= (const float*)d_in[24];
    const float* blk_mlp_b2= (const float*)d_in[25];

    // workspace layout — 11,732,288 floats = 46.9 MB (ws ≈ 268 MB)
    float* f      = (float*)d_ws;
    bf16*  wbuf   = (bf16*)d_ws;                 // 2359296 bf16 = 1179648 f
    bf16*  kproj  = (bf16*)(f + 1179648);        // 3211264 bf16
    bf16*  vproj  = (bf16*)(f + 2785280);        // 3211264 bf16
    float* xout   = f + 4390912;                 // 802816
    float* tmp    = f + 5193728;                 // 802816
    bf16*  tmph   = (bf16*)(f + 5996544);        // 802816 bf16
    bf16*  qbufh  = (bf16*)(f + 6397952);        // 802816 bf16
    bf16*  bigh   = (bf16*)(f + 6799360);        // 2408448 bf16
    float* attng  = f + 8003584;                 // 112896
    float* col    = f + 8116480;                 // 3136
    bf16*  xln    = (bf16*)(f + 8119616);        // 3211264 bf16
    bf16*  xh     = (bf16*)(f + 9725248);        // 3211264 bf16
    bf16*  xouth  = (bf16*)(f + 11330880);       // 802816 bf16

    bf16* w_q    = wbuf;
    bf16* w_k    = wbuf + 65536;
    bf16* w_v    = wbuf + 131072;
    bf16* w_m1   = wbuf + 196608;
    bf16* w_m2   = wbuf + 327680;
    bf16* w_qkv  = wbuf + 458752;   // 2 layers x 196608
    bf16* w_proj = wbuf + 851968;   // 2 x 65536
    bf16* w_bm1  = wbuf + 983040;   // 2 x 196608
    bf16* w_bm2  = wbuf + 1376256;  // 2 x 196608
    bf16* w_seed = wbuf + 1769472;  // 589824

    // ---- setup: 1 fused dispatch, then merged kv+conv dispatch ----
    setup_fused<<<21760, 256, 0, stream>>>(x, g_ln_in_g, g_ln_in_b, xln, xh, tmp,
                                           g_q_w, g_k_w, g_v_w, g_mlp_w1, g_mlp_w2,
                                           blk_qkv_w, blk_proj_w, blk_mlp_w1, blk_mlp_w2,
                                           wbuf, g_seed_w, w_seed);
    kv_conv<<<dim3(4,392,3), 128, 0, stream>>>(xln, xh, w_k, w_v, kproj, vproj, w_seed, tmp);
    // xout = LN_out(seed); tmph = LN_out(xout); col = 0
    ln_add_ln<<<3136, 256, 0, stream>>>(tmp, nullptr, g_ln_out_g, g_ln_out_b,
                                        g_ln_out_g, g_ln_out_b, xout, tmph, col);

    // ---- NUM_ITERS group-attention iterations ----
    for (int it=0; it<3; it++){
        gemm_mfma<bf16,bf16><<<dim3(4,98), 128, 0, stream>>>(tmph, w_q, nullptr, nullptr, qbufh, 3136,256,256, 0);
        grp_attn_row<<<448, 256, 0, stream>>>(kproj, qbufh, g_rpb, g_tau, attng, col);
        grp_av_kernel<<<3136, 256, 0, stream>>>(attng, col, vproj, xout, xouth);
        gemm_mfma<bf16,bf16><<<dim3(8,98), 128, 0, stream>>>(xouth, w_m1, g_mlp_b1, nullptr, bigh, 3136,512,256, 1);
        gemm_mfma<bf16,float><<<dim3(4,98), 128, 0, stream>>>(bigh, w_m2, g_mlp_b2, nullptr, tmp, 3136,256,512, 0);
        const float* g2 = (it<2) ? g_ln_out_g : blk_ln1_g;   // it=2 feeds blk layer 0 LN1
        const float* b2 = (it<2) ? g_ln_out_b : blk_ln1_b;
        ln_add_ln<<<3136, 256, 0, stream>>>(tmp, xout, g_ln_out_g, g_ln_out_b,
                                            g2, b2, xout, tmph, col);
    }

    // ---- DEPTH transformer blocks (tmph holds LN1(xout) at loop entry) ----
    for (int l=0; l<2; l++){
        gemm_mfma<bf16,bf16><<<dim3(12,98), 128, 0, stream>>>(tmph, w_qkv + (size_t)l*196608, nullptr, nullptr, bigh, 3136,768,256, 0);
        blk_attn_row<<<896, 256, 0, stream>>>(bigh, qbufh);
        gemm_mfma<bf16,float><<<dim3(4,98), 128, 0, stream>>>(qbufh, w_proj + (size_t)l*65536, blk_proj_b + l*256, xout, xout, 3136,256,256, 0);
        ln256_kernel<bf16><<<3136, 256, 0, stream>>>(xout, blk_ln2_g + l*256, blk_ln2_b + l*256, tmph, 0);
        gemm_mfma<bf16,bf16><<<dim3(12,98), 128, 0, stream>>>(tmph, w_bm1 + (size_t)l*196608, blk_mlp_b1 + l*768, nullptr, bigh, 3136,768,256, 1);
        if (l==0){
            gemm_mfma<bf16,float><<<dim3(4,98), 128, 0, stream>>>(bigh, w_bm2, blk_mlp_b2, xout, xout, 3136,256,768, 0);
            ln256_kernel<bf16><<<3136, 256, 0, stream>>>(xout, blk_ln1_g + 256, blk_ln1_b + 256, tmph, 0);
        } else {
            gemm_mfma<bf16,float><<<dim3(4,98), 128, 0, stream>>>(bigh, w_bm2 + 196608, blk_mlp_b2 + 256, xout, (float*)d_out, 3136,256,768, 0);
        }
    }
}